// Round 6
// baseline (1045.328 us; speedup 1.0000x reference)
//
#include <hip/hip_runtime.h>
#include <math.h>

// ---------------------------------------------------------------------------
// WaveNet forward. Layers, skip/end1, end2(+fused pool1), FC1 all via
// split-bf16 MFMA (3-term hi*hi+hi*lo+lo*hi, rel err ~2^-16). Flat layout
// (channel, time, batch) => buf[c][t*256+n]; dilate() is a reinterpretation.
// R15: revert R13/R14 (Gt pre-tiling: staging-VALU removal did NOT help ->
// staging was not the limiter; layers regressed). Base = R12 (best, 829.7us).
// skip_end1 was latency-bound at ~2 waves/SIMD (occ 25%, MfmaUtil 22%, no
// pipe saturated). Now 512-thread / 8-wave blocks, COLUMN-split: each wave
// owns 64 rows x 32 cols (acc1[4][2], acc2[2][2]) -> per-CU LDS B-traffic
// unchanged, waves/SIMD doubled, per-wave regs halved. T14 ph=1 reg-prefetch
// kept. Bit-identical accumulation order per output element.
// ---------------------------------------------------------------------------

#define MCAP 327680

typedef short v8s __attribute__((ext_vector_type(8)));
typedef float v4f __attribute__((ext_vector_type(4)));

static inline long lmax_(long a, long b) { return a > b ? a : b; }

__device__ inline unsigned short rnbf(float x) {
    unsigned u = __float_as_uint(x);
    return (unsigned short)((u + 0x7FFFu + ((u >> 16) & 1u)) >> 16);
}
__device__ inline void split2(float v, unsigned short& h, unsigned short& l) {
    h = rnbf(v);
    const float hf = __uint_as_float(((unsigned)h) << 16);
    l = rnbf(v - hf);
}
__device__ inline unsigned packsplit(float v) {
    unsigned short h, l;
    split2(v, h, l);
    return ((unsigned)l << 16) | (unsigned)h;
}
__device__ inline float unpack2f(unsigned v) {
    return __uint_as_float(v << 16) + __uint_as_float(v & 0xffff0000u);
}

__global__ __launch_bounds__(256) void k_zero(float* __restrict__ p, int n) {
    int i = blockIdx.x * 256 + threadIdx.x;
    if (i < n) p[i] = 0.f;
}

// h0[o][t*256+n] = packsplit(sum_i start_w[o,i] * x[n,i,t])
__global__ __launch_bounds__(256) void k_start(const float* __restrict__ x,
                                               const float* __restrict__ sw,
                                               unsigned* __restrict__ h0) {
    int j = blockIdx.x * 256 + threadIdx.x;
    int t = j >> 8, n = j & 255;
    float xv[5];
#pragma unroll
    for (int i = 0; i < 5; ++i) xv[i] = x[n * 6400 + i * 1280 + t];
#pragma unroll
    for (int o = 0; o < 32; ++o) {
        float acc = 0.f;
#pragma unroll
        for (int i = 0; i < 5; ++i) acc = fmaf(sw[o * 5 + i], xv[i], acc);
        h0[o * MCAP + j] = packsplit(acc);
    }
}

// Prepack small weights (split bf16).
// e1t k-dim is PERMUTED for k_skip_end1_m's two-pass st consumption:
//   k_new = h*128 + w*32 + c*16 + r  <->  ch = w*64 + (2h+c)*16 + r
__global__ __launch_bounds__(256) void k_prep(const float* __restrict__ skw,
                                              const float* __restrict__ e1w,
                                              const float* __restrict__ fw,
                                              const float* __restrict__ gw,
                                              const float* __restrict__ rw,
                                              const float* __restrict__ e2w,
                                              unsigned short* __restrict__ swt_hi,
                                              unsigned short* __restrict__ swt_lo,
                                              unsigned short* __restrict__ e1t_hi,
                                              unsigned short* __restrict__ e1t_lo,
                                              unsigned short* __restrict__ wfg_hi,
                                              unsigned short* __restrict__ wfg_lo,
                                              unsigned short* __restrict__ wr_hi,
                                              unsigned short* __restrict__ wr_lo,
                                              unsigned short* __restrict__ e2s_hi,
                                              unsigned short* __restrict__ e2s_lo) {
    int idx = blockIdx.x * 256 + threadIdx.x;
    if (idx < 49152) {
        int ch = idx / 192, k = idx - ch * 192;
        int l = k >> 5, i = k & 31;
        unsigned short h, lo;
        split2(skw[l * 8192 + ch * 32 + i], h, lo);
        swt_hi[idx] = h; swt_lo[idx] = lo;
    }
    if (idx < 32768) {
        int co = idx >> 8, kn = idx & 255;
        int hf = kn >> 7, wv = (kn >> 5) & 3, c = (kn >> 4) & 1, r = kn & 15;
        int ch = wv * 64 + (hf * 2 + c) * 16 + r;
        unsigned short h, lo;
        split2(e1w[co * 256 + ch], h, lo);
        e1t_hi[idx] = h; e1t_lo[idx] = lo;
    }
    if (idx < 24576) {
        int l = idx >> 12, r = idx & 4095;
        int row = r >> 6, k = r & 63;
        int o = row & 31, i = k & 31, tap = k >> 5;
        const float* src = (row < 32) ? fw : gw;
        unsigned short h, lo;
        split2(src[l * 2048 + o * 64 + i * 2 + tap], h, lo);
        wfg_hi[idx] = h; wfg_lo[idx] = lo;
    }
    if (idx < 12288) {
        int l = idx >> 11, r = idx & 2047;
        int o = r >> 6, k = r & 63, i = k & 31;
        unsigned short h, lo;
        split2(rw[l * 1024 + o * 32 + i], h, lo);
        wr_hi[idx] = h; wr_lo[idx] = lo;
    }
    if (idx < 4096) {
        unsigned short h, lo;
        split2(e2w[idx], h, lo);
        e2s_hi[idx] = h; e2s_lo[idx] = lo;
    }
}

// Split fc1 weights (1024 x 10144, row-major, k-contiguous).
__global__ __launch_bounds__(256) void k_prep_w1(const float* __restrict__ w1,
                                                 unsigned short* __restrict__ hi,
                                                 unsigned short* __restrict__ lo) {
    int idx = blockIdx.x * 256 + threadIdx.x;
    if (idx < 10387456) {
        unsigned short h, l;
        split2(w1[idx], h, l);
        hi[idx] = h; lo[idx] = l;
    }
}

// One dilated gated layer via split-bf16 MFMA. 128-col tile, Jcnt % 128 == 0.
// hin/hout/gsl hold packed-split u32 activations. LDS: single 128x136 u16
// buffer; acts (AT) during stage A, gated k-ext (GT) after a barrier.
__global__ __launch_bounds__(256) void k_layer_m(
    const unsigned* __restrict__ hin, const int hinBase, const int hinStride,
    unsigned* __restrict__ hout, const int houtBase, const int houtStride,
    unsigned* __restrict__ gsl, const int gStride,
    const unsigned short* __restrict__ wfg_hi, const unsigned short* __restrict__ wfg_lo,
    const unsigned short* __restrict__ wr_hi, const unsigned short* __restrict__ wr_lo,
    const int Jlo, const int NpmP, const int padN,
    const int so_, const int M0, const int M1, const int doRes)
{
    __shared__ unsigned short U[128 * 136];
    unsigned short* AT = U;          // [col][k]: 0..63 hi, 64..127 lo (stage A)
    unsigned short* GT = U;          // [col][72]: 0..31 ghi, 32..63 glo (stage B)

    const int tid = threadIdx.x;
    const int j0 = Jlo + blockIdx.x * 128;

    {
        const int col = tid & 127;
        const int kg = tid >> 7;
        unsigned short* bh = &AT[col * 136 + kg * 32];
        unsigned short* bl = &AT[col * 136 + 64 + kg * 32];
        if (kg == 0 && j0 < padN) {
            uint4 z; z.x = z.y = z.z = z.w = 0u;
#pragma unroll
            for (int ch = 0; ch < 32; ch += 8) {
                *(uint4*)&bh[ch] = z;
                *(uint4*)&bl[ch] = z;
            }
        } else {
            const int off = (kg == 0) ? (j0 - padN) : (j0 + NpmP);
            const unsigned* p = hin + (off - hinBase) + col;
#pragma unroll
            for (int ch = 0; ch < 32; ch += 8) {
                alignas(16) unsigned short h8[8], l8[8];
#pragma unroll
                for (int u = 0; u < 8; ++u) {
                    const unsigned v = p[(size_t)(ch + u) * hinStride];
                    h8[u] = (unsigned short)(v & 0xffffu);
                    l8[u] = (unsigned short)(v >> 16);
                }
                *(uint4*)&bh[ch] = *(uint4*)h8;
                *(uint4*)&bl[ch] = *(uint4*)l8;
            }
        }
    }
    __syncthreads();

    const int lane = tid & 63;
    const int w    = tid >> 6;
    const int ch2  = w >> 1;
    const int mh   = w & 1;
    const int l15  = lane & 15;
    const int quad = lane >> 4;
    const int q8   = quad * 8;
    const int colb = ch2 * 64;

    v4f accf[4], accg[4];
#pragma unroll
    for (int nt = 0; nt < 4; ++nt) { accf[nt] = (v4f)(0.f); accg[nt] = (v4f)(0.f); }

#pragma unroll
    for (int kt = 0; kt < 2; ++kt) {
        const int frow = (mh * 16 + l15) * 64 + kt * 32 + q8;
        const int grow = (32 + mh * 16 + l15) * 64 + kt * 32 + q8;
        const v8s afh = *(const v8s*)&wfg_hi[frow];
        const v8s afl = *(const v8s*)&wfg_lo[frow];
        const v8s agh = *(const v8s*)&wfg_hi[grow];
        const v8s agl = *(const v8s*)&wfg_lo[grow];
#pragma unroll
        for (int nt = 0; nt < 4; ++nt) {
            const int col = colb + nt * 16 + l15;
            const v8s bh = *(const v8s*)&AT[col * 136 + kt * 32 + q8];
            const v8s bl = *(const v8s*)&AT[col * 136 + 64 + kt * 32 + q8];
            accf[nt] = __builtin_amdgcn_mfma_f32_16x16x32_bf16(afh, bh, accf[nt], 0, 0, 0);
            accf[nt] = __builtin_amdgcn_mfma_f32_16x16x32_bf16(afh, bl, accf[nt], 0, 0, 0);
            accf[nt] = __builtin_amdgcn_mfma_f32_16x16x32_bf16(afl, bh, accf[nt], 0, 0, 0);
            accg[nt] = __builtin_amdgcn_mfma_f32_16x16x32_bf16(agh, bh, accg[nt], 0, 0, 0);
            accg[nt] = __builtin_amdgcn_mfma_f32_16x16x32_bf16(agh, bl, accg[nt], 0, 0, 0);
            accg[nt] = __builtin_amdgcn_mfma_f32_16x16x32_bf16(agl, bh, accg[nt], 0, 0, 0);
        }
    }

    // gate + split (split reused for G store and GT staging)
    unsigned short gh[4][4], gl[4][4];
#pragma unroll
    for (int nt = 0; nt < 4; ++nt)
#pragma unroll
        for (int r = 0; r < 4; ++r) {
            const float f = accf[nt][r];
            const float g = accg[nt][r];
            const float th = 1.f - 2.f / (__expf(2.f * f) + 1.f);
            const float sg = 1.f / (1.f + __expf(-g));
            split2(th * sg, gh[nt][r], gl[nt][r]);
        }

    const int m0c = j0 - so_;
    if (m0c >= M0 && m0c < M1) {
#pragma unroll
        for (int nt = 0; nt < 4; ++nt)
#pragma unroll
            for (int r = 0; r < 4; ++r) {
                const int ch = mh * 16 + quad * 4 + r;
                const int m = (m0c - M0) + colb + nt * 16 + l15;
                gsl[(size_t)ch * gStride + m] =
                    ((unsigned)gl[nt][r] << 16) | (unsigned)gh[nt][r];
            }
    }

    if (doRes) {
        __syncthreads();   // all stage-A AT reads complete before GT overlays U
#pragma unroll
        for (int nt = 0; nt < 4; ++nt)
#pragma unroll
            for (int r = 0; r < 4; ++r) {
                const int ch = mh * 16 + quad * 4 + r;
                const int col = colb + nt * 16 + l15;
                GT[col * 72 + ch] = gh[nt][r];
                GT[col * 72 + 32 + ch] = gl[nt][r];
            }
        __syncthreads();

        v4f accr[4];
#pragma unroll
        for (int nt = 0; nt < 4; ++nt) accr[nt] = (v4f)(0.f);
#pragma unroll
        for (int kt = 0; kt < 2; ++kt) {
            const int row = (mh * 16 + l15) * 64 + kt * 32 + q8;
            const v8s arh = *(const v8s*)&wr_hi[row];
            const v8s arl = *(const v8s*)&wr_lo[row];
#pragma unroll
            for (int nt = 0; nt < 4; ++nt) {
                const int col = colb + nt * 16 + l15;
                const v8s b = *(const v8s*)&GT[col * 72 + kt * 32 + q8];
                accr[nt] = __builtin_amdgcn_mfma_f32_16x16x32_bf16(arh, b, accr[nt], 0, 0, 0);
                accr[nt] = __builtin_amdgcn_mfma_f32_16x16x32_bf16(arl, b, accr[nt], 0, 0, 0);
            }
        }

        // tap1 re-loaded from global (same packed value as the AT copy)
        const unsigned* tp = hin + (j0 + NpmP - hinBase);
#pragma unroll
        for (int nt = 0; nt < 4; ++nt)
#pragma unroll
            for (int r = 0; r < 4; ++r) {
                const int o = mh * 16 + quad * 4 + r;
                const int col = colb + nt * 16 + l15;
                const float tap1 = unpack2f(tp[(size_t)o * hinStride + col]);
                hout[(size_t)o * houtStride + (j0 - houtBase) + col] =
                    packsplit(accr[nt][r] + tap1);
            }
    }
}

// Fused skip -> relu -> end1 + bias -> relu -> y1 (split-bf16 MFMA).
// R15: 512 threads / 8 waves, column-split: wave (wv=w8&3, cg=w8>>2) owns
// rows wv*64..+63 x cols cg*32..+31 in m1 (acc1[4][2]) and rows wv*32..+31
// x same cols in m2 (acc2[2][2]). LDS B-read traffic per CU unchanged vs
// 4-wave version; waves/SIMD doubled. T14 reg-prefetch of ph=1 kept.
// LDS 34.8 KB: gt 64x104, st 64x136 aliased; e1t k-permuted (unchanged).
__global__ __launch_bounds__(512, 2) void k_skip_end1_m(
    const unsigned* __restrict__ g,
    const unsigned short* __restrict__ swt_hi, const unsigned short* __restrict__ swt_lo,
    const unsigned short* __restrict__ e1t_hi, const unsigned short* __restrict__ e1t_lo,
    const float* __restrict__ b1, float* __restrict__ y1, const int gs)
{
    __shared__ unsigned short U[17408];          // 34816 B
    unsigned short* gt_hi = U;                   // 64 x 104
    unsigned short* gt_lo = U + 6656;
    unsigned short* st_hi = U;                   // 64 x 136 (aliases gt)
    unsigned short* st_lo = U + 8704;

    const int tid  = threadIdx.x;
    const int m0   = blockIdx.x * 64;
    const int lane = tid & 63;
    const int w8   = tid >> 6;        // 0..7
    const int wv   = w8 & 3;          // row group
    const int cg   = w8 >> 2;         // col group
    const int l15  = lane & 15;
    const int q8   = (lane >> 4) * 8;
    const int rbase = (lane >> 4) * 4;

    const int scol = tid & 63;
    const int ks0  = ((tid >> 6) & 3) * 8;
    const int kcA  = (tid >> 8) * 32;            // 0 (waves 0-3) or 32 (waves 4-7)

    v4f acc1[4][2];
#pragma unroll
    for (int a = 0; a < 4; ++a)
#pragma unroll
        for (int b = 0; b < 2; ++b) acc1[a][b] = (v4f)(0.f);

    // ---- stage ph=0 (k 0..95): round A all threads, round B waves 0-3 ----
    {
        alignas(16) unsigned short h8[8], l8[8];
#pragma unroll
        for (int j = 0; j < 8; ++j) {
            const int k = kcA + ks0 + j;
            const unsigned v = g[(size_t)(k >> 5) * 32 * gs + (size_t)(k & 31) * gs + m0 + scol];
            h8[j] = (unsigned short)(v & 0xffffu);
            l8[j] = (unsigned short)(v >> 16);
        }
        *(v8s*)&gt_hi[scol * 104 + kcA + ks0] = *(v8s*)h8;
        *(v8s*)&gt_lo[scol * 104 + kcA + ks0] = *(v8s*)l8;
        if (tid < 256) {
#pragma unroll
            for (int j = 0; j < 8; ++j) {
                const int k = 64 + ks0 + j;
                const unsigned v = g[(size_t)(k >> 5) * 32 * gs + (size_t)(k & 31) * gs + m0 + scol];
                h8[j] = (unsigned short)(v & 0xffffu);
                l8[j] = (unsigned short)(v >> 16);
            }
            *(v8s*)&gt_hi[scol * 104 + 64 + ks0] = *(v8s*)h8;
            *(v8s*)&gt_lo[scol * 104 + 64 + ks0] = *(v8s*)l8;
        }
    }
    __syncthreads();

    // ---- T14: issue ph=1 (k 96..191) loads into regs ----
    unsigned pre[16];
#pragma unroll
    for (int j = 0; j < 8; ++j) {
        const int k = 96 + kcA + ks0 + j;
        pre[j] = g[(size_t)(k >> 5) * 32 * gs + (size_t)(k & 31) * gs + m0 + scol];
    }
    if (tid < 256) {
#pragma unroll
        for (int j = 0; j < 8; ++j) {
            const int k = 160 + ks0 + j;
            pre[8 + j] = g[(size_t)(k >> 5) * 32 * gs + (size_t)(k & 31) * gs + m0 + scol];
        }
    }

    // ---- m1 over ph=0 ----
    for (int kc = 0; kc < 96; kc += 32) {
        v8s bh[2], bl[2];
#pragma unroll
        for (int t = 0; t < 2; ++t) {
            const int bo = ((cg * 2 + t) * 16 + l15) * 104 + kc + q8;
            bh[t] = *(const v8s*)&gt_hi[bo];
            bl[t] = *(const v8s*)&gt_lo[bo];
        }
#pragma unroll
        for (int cp = 0; cp < 2; ++cp) {
            v8s ah[2], al[2];
#pragma unroll
            for (int u = 0; u < 2; ++u) {
                const int tt = cp * 2 + u;
                const int row = (wv * 64 + tt * 16 + l15) * 192 + kc + q8;
                ah[u] = *(const v8s*)&swt_hi[row];
                al[u] = *(const v8s*)&swt_lo[row];
            }
#pragma unroll
            for (int u = 0; u < 2; ++u) {
                const int tt = cp * 2 + u;
#pragma unroll
                for (int nt = 0; nt < 2; ++nt) {
                    acc1[tt][nt] = __builtin_amdgcn_mfma_f32_16x16x32_bf16(ah[u], bh[nt], acc1[tt][nt], 0, 0, 0);
                    acc1[tt][nt] = __builtin_amdgcn_mfma_f32_16x16x32_bf16(ah[u], bl[nt], acc1[tt][nt], 0, 0, 0);
                    acc1[tt][nt] = __builtin_amdgcn_mfma_f32_16x16x32_bf16(al[u], bh[nt], acc1[tt][nt], 0, 0, 0);
                }
            }
        }
    }
    __syncthreads();   // gt(ph0) reads done before overwrite

    // ---- write prefetched ph=1 to LDS ----
    {
        alignas(16) unsigned short h8[8], l8[8];
#pragma unroll
        for (int j = 0; j < 8; ++j) {
            const unsigned v = pre[j];
            h8[j] = (unsigned short)(v & 0xffffu);
            l8[j] = (unsigned short)(v >> 16);
        }
        *(v8s*)&gt_hi[scol * 104 + kcA + ks0] = *(v8s*)h8;
        *(v8s*)&gt_lo[scol * 104 + kcA + ks0] = *(v8s*)l8;
        if (tid < 256) {
#pragma unroll
            for (int j = 0; j < 8; ++j) {
                const unsigned v = pre[8 + j];
                h8[j] = (unsigned short)(v & 0xffffu);
                l8[j] = (unsigned short)(v >> 16);
            }
            *(v8s*)&gt_hi[scol * 104 + 64 + ks0] = *(v8s*)h8;
            *(v8s*)&gt_lo[scol * 104 + 64 + ks0] = *(v8s*)l8;
        }
    }
    __syncthreads();

    // ---- m1 over ph=1 ----
    for (int kc = 0; kc < 96; kc += 32) {
        v8s bh[2], bl[2];
#pragma unroll
        for (int t = 0; t < 2; ++t) {
            const int bo = ((cg * 2 + t) * 16 + l15) * 104 + kc + q8;
            bh[t] = *(const v8s*)&gt_hi[bo];
            bl[t] = *(const v8s*)&gt_lo[bo];
        }
#pragma unroll
        for (int cp = 0; cp < 2; ++cp) {
            v8s ah[2], al[2];
#pragma unroll
            for (int u = 0; u < 2; ++u) {
                const int tt = cp * 2 + u;
                const int row = (wv * 64 + tt * 16 + l15) * 192 + 96 + kc + q8;
                ah[u] = *(const v8s*)&swt_hi[row];
                al[u] = *(const v8s*)&swt_lo[row];
            }
#pragma unroll
            for (int u = 0; u < 2; ++u) {
                const int tt = cp * 2 + u;
#pragma unroll
                for (int nt = 0; nt < 2; ++nt) {
                    acc1[tt][nt] = __builtin_amdgcn_mfma_f32_16x16x32_bf16(ah[u], bh[nt], acc1[tt][nt], 0, 0, 0);
                    acc1[tt][nt] = __builtin_amdgcn_mfma_f32_16x16x32_bf16(ah[u], bl[nt], acc1[tt][nt], 0, 0, 0);
                    acc1[tt][nt] = __builtin_amdgcn_mfma_f32_16x16x32_bf16(al[u], bh[nt], acc1[tt][nt], 0, 0, 0);
                }
            }
        }
    }
    __syncthreads();   // gt reads done before st overlays U

    v4f acc2[2][2];
#pragma unroll
    for (int a = 0; a < 2; ++a)
#pragma unroll
        for (int b = 0; b < 2; ++b) acc2[a][b] = (v4f)(0.f);

#pragma unroll
    for (int hh = 0; hh < 2; ++hh) {
        // write st half hh: every wave's tt{2hh, 2hh+1} tiles (its 32 cols)
#pragma unroll
        for (int c2 = 0; c2 < 2; ++c2) {
            const int tt = hh * 2 + c2;
#pragma unroll
            for (int nt = 0; nt < 2; ++nt) {
                alignas(8) unsigned short sh[4], sl[4];
#pragma unroll
                for (int r = 0; r < 4; ++r) {
                    const float v = fmaxf(acc1[tt][nt][r], 0.f);
                    split2(v, sh[r], sl[r]);
                }
                const int ci  = wv * 32 + c2 * 16 + rbase;
                const int col = cg * 32 + nt * 16 + l15;
                *(uint2*)&st_hi[col * 136 + ci] = *(uint2*)sh;
                *(uint2*)&st_lo[col * 136 + ci] = *(uint2*)sl;
            }
        }
        __syncthreads();

        for (int kc = 0; kc < 128; kc += 32) {
            v8s ah2[2], al2[2], bh2[2], bl2[2];
#pragma unroll
            for (int t = 0; t < 2; ++t) {
                const int row = (wv * 32 + t * 16 + l15) * 256 + hh * 128 + kc + q8;
                ah2[t] = *(const v8s*)&e1t_hi[row];
                al2[t] = *(const v8s*)&e1t_lo[row];
            }
#pragma unroll
            for (int t = 0; t < 2; ++t) {
                const int bo = ((cg * 2 + t) * 16 + l15) * 136 + kc + q8;
                bh2[t] = *(const v8s*)&st_hi[bo];
                bl2[t] = *(const v8s*)&st_lo[bo];
            }
#pragma unroll
            for (int ct = 0; ct < 2; ++ct)
#pragma unroll
                for (int nt = 0; nt < 2; ++nt) {
                    acc2[ct][nt] = __builtin_amdgcn_mfma_f32_16x16x32_bf16(ah2[ct], bh2[nt], acc2[ct][nt], 0, 0, 0);
                    acc2[ct][nt] = __builtin_amdgcn_mfma_f32_16x16x32_bf16(ah2[ct], bl2[nt], acc2[ct][nt], 0, 0, 0);
                    acc2[ct][nt] = __builtin_amdgcn_mfma_f32_16x16x32_bf16(al2[ct], bh2[nt], acc2[ct][nt], 0, 0, 0);
                }
        }
        if (hh == 0) __syncthreads();   // m2 half-0 reads done before st half-1 overwrite
    }

#pragma unroll
    for (int ct = 0; ct < 2; ++ct) {
        const int cobase = wv * 32 + ct * 16 + rbase;
        float bb[4];
#pragma unroll
        for (int r = 0; r < 4; ++r) bb[r] = b1[cobase + r];
#pragma unroll
        for (int nt = 0; nt < 2; ++nt) {
            const int col = m0 + cg * 32 + nt * 16 + l15;
#pragma unroll
            for (int r = 0; r < 4; ++r)
                y1[(size_t)(cobase + r) * gs + col] = fmaxf(acc2[ct][nt][r] + bb[r], 0.f);
        }
    }
}

// Fused maxpool3s2 + end2 (128->32) via split-bf16 MFMA. 64 pooled cols/block.
__global__ __launch_bounds__(256) void k_pe2_m(
    const float* __restrict__ y1c,
    const unsigned short* __restrict__ e2s_hi, const unsigned short* __restrict__ e2s_lo,
    const float* __restrict__ b2, float* __restrict__ e2c,
    const int gs, const int p1s)
{
    __shared__ unsigned short SP[2 * 64 * 136];
    unsigned short* sp_hi = SP;
    unsigned short* sp_lo = SP + 64 * 136;

    const int tid = threadIdx.x;
    const int m0 = blockIdx.x * 64;
    const int tp = m0 >> 8;
    const int nb = m0 & 255;

    {
        const int col = tid & 63;
        const int cig = tid >> 6;
        const int base = 2 * tp * 256 + nb + col;
#pragma unroll
        for (int u8 = 0; u8 < 4; ++u8) {
            alignas(16) unsigned short h8[8], l8[8];
#pragma unroll
            for (int u = 0; u < 8; ++u) {
                const int ci = cig * 32 + u8 * 8 + u;
                const float* yp = y1c + (size_t)ci * gs + base;
                const float v = fmaxf(fmaxf(yp[0], yp[256]), yp[512]);
                split2(v, h8[u], l8[u]);
            }
            *(uint4*)&sp_hi[col * 136 + cig * 32 + u8 * 8] = *(uint4*)h8;
            *(uint4*)&sp_lo[col * 136 + cig * 32 + u8 * 8] = *(uint4*)l8;
        }
    }
    __syncthreads();

    const int lane = tid & 63;
    const int w    = tid >> 6;
    const int mh   = w & 1;
    const int colh = w >> 1;
    const int l15  = lane & 15;
    const int quad = lane >> 4;
    const int q8   = quad * 8;

    v4f acc[2];
    acc[0] = (v4f)(0.f); acc[1] = (v4f)(0.f);

#pragma unroll
    for (int kc = 0; kc < 128; kc += 32) {
        const int row = (mh * 16 + l15) * 128 + kc + q8;
        const v8s ah = *(const v8s*)&e2s_hi[row];
        const v8s al = *(const v8s*)&e2s_lo[row];
#pragma unroll
        for (int nt = 0; nt < 2; ++nt) {
            const int col = colh * 32 + nt * 16 + l15;
            const v8s bh = *(const v8s*)&sp_hi[col * 136 + kc + q8];
            const v8s bl = *(const v8s*)&sp_lo[col * 136 + kc + q8];
            acc[nt] = __builtin_amdgcn_mfma_f32_16x16x32_bf16(ah, bh, acc[nt], 0, 0, 0);
            acc[nt] = __builtin_amdgcn_mfma_f32_16x16x32_bf16(ah, bl, acc[nt], 0, 0, 0);
            acc[nt] = __builtin_amdgcn_mfma_f32_16x16x32_bf16(al, bh, acc[nt], 0, 0, 0);
        }
    }

#pragma unroll
    for (int nt = 0; nt < 2; ++nt)
#pragma unroll
        for (int r = 0; r < 4; ++r) {
            const int co = mh * 16 + quad * 4 + r;
            const int col = m0 + colh * 32 + nt * 16 + l15;
            e2c[(size_t)co * p1s + col] = fmaxf(acc[nt][r] + b2[co], 0.f);
        }
}

// pool2 -> p2 stored packed-split u32 (consumed by k_fc1_m)
__global__ __launch_bounds__(256) void k_pool2p(const float* __restrict__ e2c,
                                                unsigned* __restrict__ p2,
                                                const int p1s, const int A) {
    const int n = threadIdx.x, tl2 = blockIdx.x, co = blockIdx.y;
    const int base = co * p1s + tl2 * 512 + n;
    float v = fmaxf(fmaxf(e2c[base], e2c[base + 256]), e2c[base + 512]);
    p2[co * 81152 + (A + tl2) * 256 + n] = packsplit(v);
}

// FC1 via split-bf16 MFMA: C[1024 x 256] += W1[1024 x 10144] @ P2[10144 x 256].
__global__ __launch_bounds__(256) void k_fc1_m(
    const unsigned short* __restrict__ w1s_hi, const unsigned short* __restrict__ w1s_lo,
    const unsigned* __restrict__ p2u, float* __restrict__ out)
{
    __shared__ unsigned short SB[2 * 64 * 40];
    unsigned short* sb_hi = SB;
    unsigned short* sb_lo = SB + 64 * 40;

    const int tid = threadIdx.x;
    const int o0 = blockIdx.x * 64;
    const int b0 = blockIdx.y * 64;
    const int k0 = blockIdx.z * 1280;
    const int kend = (k0 + 1280 < 10144) ? (k0 + 1280) : 10144;
    const int nch = (kend - k0) >> 5;

    const int lane = tid & 63;
    const int w    = tid >> 6;
    const int l15  = lane & 15;
    const int quad = lane >> 4;
    const int q8   = quad * 8;
    const int scol = tid & 63;
    const int kq   = tid >> 6;

    v4f acc[4];
#pragma unroll
    for (int nt = 0; nt < 4; ++nt) acc[nt] = (v4f)(0.f);

    for (int c = 0; c < nch; ++c) {
        const int kc = k0 + c * 32;
        alignas(16) unsigned short h8[8], l8[8];
#pragma unroll
        for (int j = 0; j < 8; ++j) {
            const unsigned v = p2u[(size_t)(kc + kq * 8 + j) * 256 + b0 + scol];
            h8[j] = (unsigned short)(v & 0xffffu);
            l8[j] = (unsigned short)(v >> 16);
        }
        __syncthreads();
        *(v8s*)&sb_hi[scol * 40 + kq * 8] = *(v8s*)h8;
        *(v8s*)&sb_lo[scol * 40 + kq * 8] = *(v8s*)l8;
        __syncthreads();

        const int arow = (o0 + w * 16 + l15) * 10144 + kc + q8;
        const v8s ah = *(const v8s*)&w1s_hi[arow];
        const v8s al = *(const v8s*)&w1s_lo[arow];
#pragma unroll
        for (int nt = 0; nt < 4; ++nt) {
            const v8s bh = *(const v8s*)&sb_hi[(nt * 16 + l15) * 40 + q8];
            const v8s bl = *(const v8s*)&sb_lo[(nt * 16 + l15) * 40 + q8];
            acc[nt] = __builtin_amdgcn_mfma_f32_16x16x32_bf16(ah, bh, acc[nt], 0, 0, 0);
            acc[nt] = __builtin_amdgcn_mfma_f32_16x16x32_bf16(ah, bl, acc[nt], 0, 0, 0);
            acc[nt] = __builtin_amdgcn_mfma_f32_16x16x32_bf16(al, bh, acc[nt], 0, 0, 0);
        }
    }

#pragma unroll
    for (int nt = 0; nt < 4; ++nt)
#pragma unroll
        for (int r = 0; r < 4; ++r)
            atomicAdd(&out[(size_t)(o0 + w * 16 + quad * 4 + r) * 256 + b0 + nt * 16 + l15],
                      acc[nt][r]);
}

// Tiled f32 GEMM (FC2 only).
__global__ __launch_bounds__(256) void k_gemm64(const float* __restrict__ A,
                                                const float* __restrict__ B,
                                                float* __restrict__ C,
                                                const int Ktot, const int KC) {
    __shared__ float sA[32 * 65];
    __shared__ float sB[32 * 68];

    const int tid = threadIdx.x;
    const int o0 = blockIdx.x * 64;
    const int b0 = blockIdx.y * 64;
    const int k0 = blockIdx.z * KC;

    float acc[4][4];
#pragma unroll
    for (int i = 0; i < 4; ++i)
#pragma unroll
        for (int jq = 0; jq < 4; ++jq) acc[i][jq] = 0.f;

    const int ao  = tid >> 2;
    const int ak8 = (tid & 3) * 8;
    const int bk  = tid >> 3;
    const int bb8 = (tid & 7) * 8;
    const int to4 = (tid & 15) * 4;
    const int tb4 = (tid >> 4) * 4;

    for (int kc = 0; kc < KC; kc += 32) {
        const int kcLen = (KC - kc < 32) ? (KC - kc) : 32;
        const float* ap = A + (size_t)(o0 + ao) * Ktot + k0 + kc + ak8;
#pragma unroll
        for (int i = 0; i < 8; ++i) {
            float v = (ak8 + i < kcLen) ? ap[i] : 0.f;
            sA[(ak8 + i) * 65 + ao] = v;
        }
        if (bk < kcLen) {
            const float* bp = B + (size_t)(k0 + kc + bk) * 256 + b0 + bb8;
            const float4 v0 = *(const float4*)bp;
            const float4 v1 = *(const float4*)(bp + 4);
            *(float4*)&sB[bk * 68 + bb8] = v0;
            *(float4*)&sB[bk * 68 + bb8 + 4] = v1;
        } else {
            float4 z; z.x = z.y = z.z = z.w = 0.f;
            *(float4*)&sB[bk * 68 + bb8] = z;
            *(float4*)&sB[bk * 68 + bb8 + 4] = z;
        }
        __syncthreads();

#pragma unroll 8
        for (int kk = 0; kk < 32; ++kk) {
            const float4 av = *(const float4*)&sA[kk * 65 + to4];
            const float4 bv = *(const float4*)&sB[kk * 68 + tb4];
            const float aa[4] = {av.x, av.y, av.z, av.w};
#pragma unroll
            for (int i = 0; i < 4; ++i) {
                acc[i][0] = fmaf(aa[i], bv.x, acc[i][0]);
                acc[i][1] = fmaf(aa[i], bv.y, acc[i][1]);
                acc[i][2] = fmaf(aa[i], bv.z, acc[i][2]);
                acc[i][3] = fmaf(aa[i], bv.w, acc[i][3]);
            }
        }
        __syncthreads();
    }

#pragma unroll
    for (int i = 0; i < 4; ++i)
#pragma unroll
        for (int jq = 0; jq < 4; ++jq)
            atomicAdd(&C[(size_t)(o0 + to4 + i) * 256 + b0 + tb4 + jq], acc[i][jq]);
}

__global__ __launch_bounds__(256) void k_actbias(const float* __restrict__ raw,
                                                 const float* __restrict__ bias,
                                                 float* __restrict__ out) {
    const int k = blockIdx.x, b = threadIdx.x;
    out[k * 256 + b] = fmaxf(raw[k * 256 + b] + bias[k], 0.f);
}

__global__ __launch_bounds__(256) void k_fc3(const float* __restrict__ fc2raw,
                                             const float* __restrict__ fb2,
                                             const float* __restrict__ w3,
                                             const float* __restrict__ b3,
                                             float* __restrict__ out) {
    const int b = threadIdx.x;
    float l0 = b3[0], l1 = b3[1];
    for (int k = 0; k < 256; ++k) {
        const float a = fmaxf(fc2raw[k * 256 + b] + fb2[k], 0.f);
        l0 = fmaf(w3[k], a, l0);
        l1 = fmaf(w3[256 + k], a, l1);
    }
    out[2 * b] = l0;
    out[2 * b + 1] = l1;
    const float mx = fmaxf(l0, l1);
    const float e0 = expf(l0 - mx), e1 = expf(l1 - mx);
    const float inv = 1.f / (e0 + e1);
    out[512 + 2 * b] = e0 * inv;
    out[513 + 2 * b] = e1 * inv;
    out[1024 + b] = (l1 > l0) ? 1.f : 0.f;
}

extern "C" void kernel_launch(void* const* d_in, const int* in_sizes, int n_in,
                              void* d_out, int out_size, void* d_ws, size_t ws_size,
                              hipStream_t stream) {
    const float* x        = (const float*)d_in[0];
    const float* start_w  = (const float*)d_in[1];
    const float* filter_w = (const float*)d_in[2];
    const float* gate_w   = (const float*)d_in[3];
    const float* res_w    = (const float*)d_in[4];
    const float* skip_w   = (const float*)d_in[5];
    const float* e1w      = (const float*)d_in[6];
    const float* e1b      = (const float*)d_in[7];
    const float* e2w      = (const float*)d_in[8];
    const float* e2b      = (const float*)d_in[9];
    const float* w1       = (const float*)d_in[10];
    const float* fb1      = (const float*)d_in[11];
    const float* w2       = (const float*)d_in[12];
    const float* fb2      = (const float*)d_in[13];
    const float* w3       = (const float*)d_in[14];
    const float* b3       = (const float*)d_in[15];

    float* ws = (float*)d_ws;

    const long o_h0   = 0;            // 10,485,760
    const long o_p2   = 10485760;     // 2,596,864
    const long o_fc1  = 13082624;     // 262,144
    const long o_fc2  = 13344768;     // 65,536
    const long o_wbf  = 13410304;     // 81,920
    const long o_wfg  = 13492224;     // 24,576
    const long o_wr   = 13516800;     // 12,288
    const long o_e2s  = 13529088;     // 4,096
    const long o_act1 = 13533184;     // 262,144
    const long o_w1s  = 13795328;     // 10,387,456 (w1 hi+lo u16)
    const long o_G    = 24182784;

    long budget = (long)((double)ws_size * 0.94 / 4.0);
    int dB = 1;
    for (int d = 317; d >= 1; --d) {
        long mch = 256L * (4L * d + 3), hs = mch + 4096;
        long tot = o_G + 192L * mch + lmax_(128L * mch, 64L * hs);
        if (tot <= budget) { dB = d; break; }
    }
    int K = (317 + dB - 1) / dB;
    dB = (317 + K - 1) / K;
    const long MchA  = 256L * (4L * dB + 3);
    const long HSPAN = MchA + 4096;
    const long o_X   = o_G + 192L * MchA;
    const long P1S   = 256L * (2L * dB + 1);

    unsigned* h0 = (unsigned*)(ws + o_h0);
    unsigned* p2 = (unsigned*)(ws + o_p2);
    float* fc1r = ws + o_fc1;
    float* fc2r = ws + o_fc2;
    unsigned short* swt_hi = (unsigned short*)(ws + o_wbf);
    unsigned short* swt_lo = swt_hi + 49152;
    unsigned short* e1t_hi = swt_lo + 49152;
    unsigned short* e1t_lo = e1t_hi + 32768;
    unsigned short* wfg_hi = (unsigned short*)(ws + o_wfg);
    unsigned short* wfg_lo = wfg_hi + 24576;
    unsigned short* wr_hi  = (unsigned short*)(ws + o_wr);
    unsigned short* wr_lo  = wr_hi + 12288;
    unsigned short* e2s_hi = (unsigned short*)(ws + o_e2s);
    unsigned short* e2s_lo = e2s_hi + 4096;
    unsigned short* w1s_hi = (unsigned short*)(ws + o_w1s);
    unsigned short* w1s_lo = w1s_hi + 10387456;
    float* act1 = ws + o_act1;
    unsigned* G  = (unsigned*)(ws + o_G);
    unsigned* hA = (unsigned*)(ws + o_X);
    unsigned* hB = (unsigned*)(ws + o_X) + 32L * HSPAN;
    float* y1c  = ws + o_X;                 // aliases hA/hB (dead by then)
    float* e2c  = ws + o_G;                 // aliases G (dead after skip_end1)

    k_zero<<<1280, 256, 0, stream>>>(fc1r, 327680);
    k_start<<<1280, 256, 0, stream>>>(x, start_w, h0);
    k_prep<<<192, 256, 0, stream>>>(skip_w, e1w, filter_w, gate_w, res_w, e2w,
                                    swt_hi, swt_lo, e1t_hi, e1t_lo,
                                    wfg_hi, wfg_lo, wr_hi, wr_lo,
                                    e2s_hi, e2s_lo);
    k_prep_w1<<<40576, 256, 0, stream>>>(w1, w1s_hi, w1s_lo);

    const int Mc[6]   = {327424, 327168, 326656, 326400, 326144, 325632};
    const int NpmP[6] = {256, 256, 512, 256, 256, 512};
    const int pN[6]   = {0, 256, 512, 0, 256, 512};
    const int so_[6]  = {1792, 1536, 1024, 768, 512, 0};
    const int JloO[6] = {-1536, -1280, -768, -768, -512, 0};

    for (int c = 0; c < K; ++c) {
        const int A = c * dB;
        int B = A + dB; if (B > 317) B = 317;
        const int dBc = B - A;
        const int M0 = 1024 * A;
        int tmax = 4 * B + 3; if (tmax > 1272) tmax = 1272;
        const int Tt = tmax - 4 * A;
        const int M1 = M0 + 256 * Tt;

        int Jlo[6], Jhi[6];
        for (int q = 0; q < 6; ++q) {
            int lo = M0 + JloO[q]; if (lo < 0) lo = 0;
            int hi = M1 + so_[q];  if (hi > Mc[q]) hi = Mc[q];
            Jlo[q] = lo; Jhi[q] = hi;
        }

        for (int q = 0; q < 6; ++q) {
            const unsigned* hin = (q == 0) ? h0 : ((q & 1) ? hA : hB);
            const int hinBase   = (q == 0) ? 0 : Jlo[q - 1];
            const int hinStride = (q == 0) ? MCAP : (int)HSPAN;
            unsigned* hout = (q & 1) ? hB : hA;
            const int Jcnt = Jhi[q] - Jlo[q];     // % 128 == 0
            k_layer_m<<<Jcnt / 128, 256, 0, stream>>>(
                hin, hinBase, hinStride, hout, Jlo[q], (int)HSPAN,
                G + (long)q * 32 * MchA, (int)MchA,
                wfg_hi + q * 4096, wfg_lo + q * 4096,
                wr_hi + q * 2048, wr_lo + q * 2048,
                Jlo[q], NpmP[q], pN[q], so_[q], M0, M1, (q < 5) ? 1 : 0);
        }

        const int Mchc = 256 * Tt;
        k_skip_end1_m<<<Mchc / 64, 512, 0, stream>>>(
            G, swt_hi, swt_lo, e1t_hi, e1t_lo, e1b, y1c, (int)MchA);
        const int T1c = 2 * dBc + 1;
        k_pe2_m<<<T1c * 4, 256, 0, stream>>>(
            y1c, e2s_hi, e2s_lo, e2b, e2c, (int)MchA, (int)P1S);
        k_pool2p<<<dim3(dBc, 32), 256, 0, stream>>>(e2c, p2, (int)P1S, A);
    }

    k_fc1_m<<<dim3(16, 4, 8), 256, 0, stream>>>(w1s_hi, w1s_lo, p2, fc1r);
    k_actbias<<<1024, 256, 0, stream>>>(fc1r, fb1, act1);
    k_gemm64<<<dim3(4, 4, 4), 256, 0, stream>>>(w2, act1, fc2r, 1024, 256);
    k_fc3<<<1, 256, 0, stream>>>(fc2r, fb2, w3, b3, (float*)d_out);
}

// Round 7
// 859.441 us; speedup vs baseline: 1.2163x; 1.2163x over previous
//
#include <hip/hip_runtime.h>
#include <math.h>

// ---------------------------------------------------------------------------
// WaveNet forward. Layers, skip/end1, end2(+fused pool1), FC1 all via
// split-bf16 MFMA (3-term hi*hi+hi*lo+lo*hi, rel err ~2^-16). Flat layout
// (channel, time, batch) => buf[c][t*256+n]; dilate() is a reinterpretation.
// R16: revert R15 (512-thr column-split: 1 blk/CU, 158us). Base = R12
// (best, 829.7us) with two overlap-only changes:
// (1) skip_end1: gt DOUBLE-BUFFER (gt0/gt1, LDS 34.8->53.2KB, still 3
//     blk/CU). ph1 loads+ds_writes issued right after barrier #1 -> hidden
//     under m1-ph0's 144 MFMAs; barriers 7->6; pre[] regs gone. Math
//     bit-identical.
// (2) k_fc1_m: sb double-buffer (10->20KB LDS): 1 barrier per k-chunk
//     instead of 2 (80->40 barriers/block), loads hidden under MFMA.
// ---------------------------------------------------------------------------

#define MCAP 327680

typedef short v8s __attribute__((ext_vector_type(8)));
typedef float v4f __attribute__((ext_vector_type(4)));

static inline long lmax_(long a, long b) { return a > b ? a : b; }

__device__ inline unsigned short rnbf(float x) {
    unsigned u = __float_as_uint(x);
    return (unsigned short)((u + 0x7FFFu + ((u >> 16) & 1u)) >> 16);
}
__device__ inline void split2(float v, unsigned short& h, unsigned short& l) {
    h = rnbf(v);
    const float hf = __uint_as_float(((unsigned)h) << 16);
    l = rnbf(v - hf);
}
__device__ inline unsigned packsplit(float v) {
    unsigned short h, l;
    split2(v, h, l);
    return ((unsigned)l << 16) | (unsigned)h;
}
__device__ inline float unpack2f(unsigned v) {
    return __uint_as_float(v << 16) + __uint_as_float(v & 0xffff0000u);
}

__global__ __launch_bounds__(256) void k_zero(float* __restrict__ p, int n) {
    int i = blockIdx.x * 256 + threadIdx.x;
    if (i < n) p[i] = 0.f;
}

// h0[o][t*256+n] = packsplit(sum_i start_w[o,i] * x[n,i,t])
__global__ __launch_bounds__(256) void k_start(const float* __restrict__ x,
                                               const float* __restrict__ sw,
                                               unsigned* __restrict__ h0) {
    int j = blockIdx.x * 256 + threadIdx.x;
    int t = j >> 8, n = j & 255;
    float xv[5];
#pragma unroll
    for (int i = 0; i < 5; ++i) xv[i] = x[n * 6400 + i * 1280 + t];
#pragma unroll
    for (int o = 0; o < 32; ++o) {
        float acc = 0.f;
#pragma unroll
        for (int i = 0; i < 5; ++i) acc = fmaf(sw[o * 5 + i], xv[i], acc);
        h0[o * MCAP + j] = packsplit(acc);
    }
}

// Prepack small weights (split bf16).
// e1t k-dim is PERMUTED for k_skip_end1_m's two-pass st consumption:
//   k_new = h*128 + w*32 + c*16 + r  <->  ch = w*64 + (2h+c)*16 + r
__global__ __launch_bounds__(256) void k_prep(const float* __restrict__ skw,
                                              const float* __restrict__ e1w,
                                              const float* __restrict__ fw,
                                              const float* __restrict__ gw,
                                              const float* __restrict__ rw,
                                              const float* __restrict__ e2w,
                                              unsigned short* __restrict__ swt_hi,
                                              unsigned short* __restrict__ swt_lo,
                                              unsigned short* __restrict__ e1t_hi,
                                              unsigned short* __restrict__ e1t_lo,
                                              unsigned short* __restrict__ wfg_hi,
                                              unsigned short* __restrict__ wfg_lo,
                                              unsigned short* __restrict__ wr_hi,
                                              unsigned short* __restrict__ wr_lo,
                                              unsigned short* __restrict__ e2s_hi,
                                              unsigned short* __restrict__ e2s_lo) {
    int idx = blockIdx.x * 256 + threadIdx.x;
    if (idx < 49152) {
        int ch = idx / 192, k = idx - ch * 192;
        int l = k >> 5, i = k & 31;
        unsigned short h, lo;
        split2(skw[l * 8192 + ch * 32 + i], h, lo);
        swt_hi[idx] = h; swt_lo[idx] = lo;
    }
    if (idx < 32768) {
        int co = idx >> 8, kn = idx & 255;
        int hf = kn >> 7, wv = (kn >> 5) & 3, c = (kn >> 4) & 1, r = kn & 15;
        int ch = wv * 64 + (hf * 2 + c) * 16 + r;
        unsigned short h, lo;
        split2(e1w[co * 256 + ch], h, lo);
        e1t_hi[idx] = h; e1t_lo[idx] = lo;
    }
    if (idx < 24576) {
        int l = idx >> 12, r = idx & 4095;
        int row = r >> 6, k = r & 63;
        int o = row & 31, i = k & 31, tap = k >> 5;
        const float* src = (row < 32) ? fw : gw;
        unsigned short h, lo;
        split2(src[l * 2048 + o * 64 + i * 2 + tap], h, lo);
        wfg_hi[idx] = h; wfg_lo[idx] = lo;
    }
    if (idx < 12288) {
        int l = idx >> 11, r = idx & 2047;
        int o = r >> 6, k = r & 63, i = k & 31;
        unsigned short h, lo;
        split2(rw[l * 1024 + o * 32 + i], h, lo);
        wr_hi[idx] = h; wr_lo[idx] = lo;
    }
    if (idx < 4096) {
        unsigned short h, lo;
        split2(e2w[idx], h, lo);
        e2s_hi[idx] = h; e2s_lo[idx] = lo;
    }
}

// Split fc1 weights (1024 x 10144, row-major, k-contiguous).
__global__ __launch_bounds__(256) void k_prep_w1(const float* __restrict__ w1,
                                                 unsigned short* __restrict__ hi,
                                                 unsigned short* __restrict__ lo) {
    int idx = blockIdx.x * 256 + threadIdx.x;
    if (idx < 10387456) {
        unsigned short h, l;
        split2(w1[idx], h, l);
        hi[idx] = h; lo[idx] = l;
    }
}

// One dilated gated layer via split-bf16 MFMA. 128-col tile, Jcnt % 128 == 0.
// hin/hout/gsl hold packed-split u32 activations. LDS: single 128x136 u16
// buffer; acts (AT) during stage A, gated k-ext (GT) after a barrier.
__global__ __launch_bounds__(256) void k_layer_m(
    const unsigned* __restrict__ hin, const int hinBase, const int hinStride,
    unsigned* __restrict__ hout, const int houtBase, const int houtStride,
    unsigned* __restrict__ gsl, const int gStride,
    const unsigned short* __restrict__ wfg_hi, const unsigned short* __restrict__ wfg_lo,
    const unsigned short* __restrict__ wr_hi, const unsigned short* __restrict__ wr_lo,
    const int Jlo, const int NpmP, const int padN,
    const int so_, const int M0, const int M1, const int doRes)
{
    __shared__ unsigned short U[128 * 136];
    unsigned short* AT = U;          // [col][k]: 0..63 hi, 64..127 lo (stage A)
    unsigned short* GT = U;          // [col][72]: 0..31 ghi, 32..63 glo (stage B)

    const int tid = threadIdx.x;
    const int j0 = Jlo + blockIdx.x * 128;

    {
        const int col = tid & 127;
        const int kg = tid >> 7;
        unsigned short* bh = &AT[col * 136 + kg * 32];
        unsigned short* bl = &AT[col * 136 + 64 + kg * 32];
        if (kg == 0 && j0 < padN) {
            uint4 z; z.x = z.y = z.z = z.w = 0u;
#pragma unroll
            for (int ch = 0; ch < 32; ch += 8) {
                *(uint4*)&bh[ch] = z;
                *(uint4*)&bl[ch] = z;
            }
        } else {
            const int off = (kg == 0) ? (j0 - padN) : (j0 + NpmP);
            const unsigned* p = hin + (off - hinBase) + col;
#pragma unroll
            for (int ch = 0; ch < 32; ch += 8) {
                alignas(16) unsigned short h8[8], l8[8];
#pragma unroll
                for (int u = 0; u < 8; ++u) {
                    const unsigned v = p[(size_t)(ch + u) * hinStride];
                    h8[u] = (unsigned short)(v & 0xffffu);
                    l8[u] = (unsigned short)(v >> 16);
                }
                *(uint4*)&bh[ch] = *(uint4*)h8;
                *(uint4*)&bl[ch] = *(uint4*)l8;
            }
        }
    }
    __syncthreads();

    const int lane = tid & 63;
    const int w    = tid >> 6;
    const int ch2  = w >> 1;
    const int mh   = w & 1;
    const int l15  = lane & 15;
    const int quad = lane >> 4;
    const int q8   = quad * 8;
    const int colb = ch2 * 64;

    v4f accf[4], accg[4];
#pragma unroll
    for (int nt = 0; nt < 4; ++nt) { accf[nt] = (v4f)(0.f); accg[nt] = (v4f)(0.f); }

#pragma unroll
    for (int kt = 0; kt < 2; ++kt) {
        const int frow = (mh * 16 + l15) * 64 + kt * 32 + q8;
        const int grow = (32 + mh * 16 + l15) * 64 + kt * 32 + q8;
        const v8s afh = *(const v8s*)&wfg_hi[frow];
        const v8s afl = *(const v8s*)&wfg_lo[frow];
        const v8s agh = *(const v8s*)&wfg_hi[grow];
        const v8s agl = *(const v8s*)&wfg_lo[grow];
#pragma unroll
        for (int nt = 0; nt < 4; ++nt) {
            const int col = colb + nt * 16 + l15;
            const v8s bh = *(const v8s*)&AT[col * 136 + kt * 32 + q8];
            const v8s bl = *(const v8s*)&AT[col * 136 + 64 + kt * 32 + q8];
            accf[nt] = __builtin_amdgcn_mfma_f32_16x16x32_bf16(afh, bh, accf[nt], 0, 0, 0);
            accf[nt] = __builtin_amdgcn_mfma_f32_16x16x32_bf16(afh, bl, accf[nt], 0, 0, 0);
            accf[nt] = __builtin_amdgcn_mfma_f32_16x16x32_bf16(afl, bh, accf[nt], 0, 0, 0);
            accg[nt] = __builtin_amdgcn_mfma_f32_16x16x32_bf16(agh, bh, accg[nt], 0, 0, 0);
            accg[nt] = __builtin_amdgcn_mfma_f32_16x16x32_bf16(agh, bl, accg[nt], 0, 0, 0);
            accg[nt] = __builtin_amdgcn_mfma_f32_16x16x32_bf16(agl, bh, accg[nt], 0, 0, 0);
        }
    }

    // gate + split (split reused for G store and GT staging)
    unsigned short gh[4][4], gl[4][4];
#pragma unroll
    for (int nt = 0; nt < 4; ++nt)
#pragma unroll
        for (int r = 0; r < 4; ++r) {
            const float f = accf[nt][r];
            const float g = accg[nt][r];
            const float th = 1.f - 2.f / (__expf(2.f * f) + 1.f);
            const float sg = 1.f / (1.f + __expf(-g));
            split2(th * sg, gh[nt][r], gl[nt][r]);
        }

    const int m0c = j0 - so_;
    if (m0c >= M0 && m0c < M1) {
#pragma unroll
        for (int nt = 0; nt < 4; ++nt)
#pragma unroll
            for (int r = 0; r < 4; ++r) {
                const int ch = mh * 16 + quad * 4 + r;
                const int m = (m0c - M0) + colb + nt * 16 + l15;
                gsl[(size_t)ch * gStride + m] =
                    ((unsigned)gl[nt][r] << 16) | (unsigned)gh[nt][r];
            }
    }

    if (doRes) {
        __syncthreads();   // all stage-A AT reads complete before GT overlays U
#pragma unroll
        for (int nt = 0; nt < 4; ++nt)
#pragma unroll
            for (int r = 0; r < 4; ++r) {
                const int ch = mh * 16 + quad * 4 + r;
                const int col = colb + nt * 16 + l15;
                GT[col * 72 + ch] = gh[nt][r];
                GT[col * 72 + 32 + ch] = gl[nt][r];
            }
        __syncthreads();

        v4f accr[4];
#pragma unroll
        for (int nt = 0; nt < 4; ++nt) accr[nt] = (v4f)(0.f);
#pragma unroll
        for (int kt = 0; kt < 2; ++kt) {
            const int row = (mh * 16 + l15) * 64 + kt * 32 + q8;
            const v8s arh = *(const v8s*)&wr_hi[row];
            const v8s arl = *(const v8s*)&wr_lo[row];
#pragma unroll
            for (int nt = 0; nt < 4; ++nt) {
                const int col = colb + nt * 16 + l15;
                const v8s b = *(const v8s*)&GT[col * 72 + kt * 32 + q8];
                accr[nt] = __builtin_amdgcn_mfma_f32_16x16x32_bf16(arh, b, accr[nt], 0, 0, 0);
                accr[nt] = __builtin_amdgcn_mfma_f32_16x16x32_bf16(arl, b, accr[nt], 0, 0, 0);
            }
        }

        // tap1 re-loaded from global (same packed value as the AT copy)
        const unsigned* tp = hin + (j0 + NpmP - hinBase);
#pragma unroll
        for (int nt = 0; nt < 4; ++nt)
#pragma unroll
            for (int r = 0; r < 4; ++r) {
                const int o = mh * 16 + quad * 4 + r;
                const int col = colb + nt * 16 + l15;
                const float tap1 = unpack2f(tp[(size_t)o * hinStride + col]);
                hout[(size_t)o * houtStride + (j0 - houtBase) + col] =
                    packsplit(accr[nt][r] + tap1);
            }
    }
}

// Fused skip -> relu -> end1 + bias -> relu -> y1 (split-bf16 MFMA).
// R16: gt double-buffer. gt0 = U[0..13312), gt1 = U[13312..26624); st
// (17408 u16) aliases the front. ph1 staging (loads + ds_writes to gt1)
// issued right after barrier #1 -> hidden under m1-ph0 MFMAs. 53248B LDS,
// 3 blk/CU (3 x 53248 = 159744 <= 163840). Math bit-identical to R12.
__global__ __launch_bounds__(256, 3) void k_skip_end1_m(
    const unsigned* __restrict__ g,
    const unsigned short* __restrict__ swt_hi, const unsigned short* __restrict__ swt_lo,
    const unsigned short* __restrict__ e1t_hi, const unsigned short* __restrict__ e1t_lo,
    const float* __restrict__ b1, float* __restrict__ y1, const int gs)
{
    __shared__ unsigned short U[26624];          // 53248 B
    unsigned short* gt0_hi = U;                  // 64 x 104
    unsigned short* gt0_lo = U + 6656;
    unsigned short* gt1_hi = U + 13312;          // 64 x 104
    unsigned short* gt1_lo = U + 19968;
    unsigned short* st_hi = U;                   // 64 x 136 (aliases gt0/gt1)
    unsigned short* st_lo = U + 8704;

    const int tid  = threadIdx.x;
    const int m0   = blockIdx.x * 64;
    const int lane = tid & 63;
    const int w    = tid >> 6;
    const int l15  = lane & 15;
    const int q8   = (lane >> 4) * 8;
    const int rbase = (lane >> 4) * 4;

    const int scol = tid & 63;
    const int ks0  = (tid >> 6) * 8;

    v4f acc1[4][4];
#pragma unroll
    for (int a = 0; a < 4; ++a)
#pragma unroll
        for (int b = 0; b < 4; ++b) acc1[a][b] = (v4f)(0.f);

    // ---- stage ph=0 (k 0..95) -> gt0 ----
#pragma unroll
    for (int kc = 0; kc < 96; kc += 32) {
        alignas(16) unsigned short h8[8], l8[8];
#pragma unroll
        for (int j = 0; j < 8; ++j) {
            const int k = kc + ks0 + j;
            const unsigned v = g[(size_t)(k >> 5) * 32 * gs + (size_t)(k & 31) * gs + m0 + scol];
            h8[j] = (unsigned short)(v & 0xffffu);
            l8[j] = (unsigned short)(v >> 16);
        }
        *(v8s*)&gt0_hi[scol * 104 + kc + ks0] = *(v8s*)h8;
        *(v8s*)&gt0_lo[scol * 104 + kc + ks0] = *(v8s*)l8;
    }
    __syncthreads();

    // ---- stage ph=1 (k 96..191) -> gt1: issued NOW, hidden under m1-ph0 ----
#pragma unroll
    for (int kc = 0; kc < 96; kc += 32) {
        alignas(16) unsigned short h8[8], l8[8];
#pragma unroll
        for (int j = 0; j < 8; ++j) {
            const int k = 96 + kc + ks0 + j;
            const unsigned v = g[(size_t)(k >> 5) * 32 * gs + (size_t)(k & 31) * gs + m0 + scol];
            h8[j] = (unsigned short)(v & 0xffffu);
            l8[j] = (unsigned short)(v >> 16);
        }
        *(v8s*)&gt1_hi[scol * 104 + kc + ks0] = *(v8s*)h8;
        *(v8s*)&gt1_lo[scol * 104 + kc + ks0] = *(v8s*)l8;
    }

    // ---- m1 over ph=0 (reads gt0; independent of gt1 writes above) ----
    for (int kc = 0; kc < 96; kc += 32) {
        v8s bh[4], bl[4];
#pragma unroll
        for (int t = 0; t < 4; ++t) {
            const int bo = (t * 16 + l15) * 104 + kc + q8;
            bh[t] = *(const v8s*)&gt0_hi[bo];
            bl[t] = *(const v8s*)&gt0_lo[bo];
        }
#pragma unroll
        for (int cp = 0; cp < 2; ++cp) {
            v8s ah[2], al[2];
#pragma unroll
            for (int u = 0; u < 2; ++u) {
                const int ct = cp * 2 + u;
                const int row = (w * 64 + ct * 16 + l15) * 192 + kc + q8;
                ah[u] = *(const v8s*)&swt_hi[row];
                al[u] = *(const v8s*)&swt_lo[row];
            }
#pragma unroll
            for (int u = 0; u < 2; ++u) {
                const int ct = cp * 2 + u;
#pragma unroll
                for (int nt = 0; nt < 4; ++nt) {
                    acc1[ct][nt] = __builtin_amdgcn_mfma_f32_16x16x32_bf16(ah[u], bh[nt], acc1[ct][nt], 0, 0, 0);
                    acc1[ct][nt] = __builtin_amdgcn_mfma_f32_16x16x32_bf16(ah[u], bl[nt], acc1[ct][nt], 0, 0, 0);
                    acc1[ct][nt] = __builtin_amdgcn_mfma_f32_16x16x32_bf16(al[u], bh[nt], acc1[ct][nt], 0, 0, 0);
                }
            }
        }
    }
    __syncthreads();   // publishes gt1 writes (and retires gt0 reads)

    // ---- m1 over ph=1 (reads gt1) ----
    for (int kc = 0; kc < 96; kc += 32) {
        v8s bh[4], bl[4];
#pragma unroll
        for (int t = 0; t < 4; ++t) {
            const int bo = (t * 16 + l15) * 104 + kc + q8;
            bh[t] = *(const v8s*)&gt1_hi[bo];
            bl[t] = *(const v8s*)&gt1_lo[bo];
        }
#pragma unroll
        for (int cp = 0; cp < 2; ++cp) {
            v8s ah[2], al[2];
#pragma unroll
            for (int u = 0; u < 2; ++u) {
                const int ct = cp * 2 + u;
                const int row = (w * 64 + ct * 16 + l15) * 192 + 96 + kc + q8;
                ah[u] = *(const v8s*)&swt_hi[row];
                al[u] = *(const v8s*)&swt_lo[row];
            }
#pragma unroll
            for (int u = 0; u < 2; ++u) {
                const int ct = cp * 2 + u;
#pragma unroll
                for (int nt = 0; nt < 4; ++nt) {
                    acc1[ct][nt] = __builtin_amdgcn_mfma_f32_16x16x32_bf16(ah[u], bh[nt], acc1[ct][nt], 0, 0, 0);
                    acc1[ct][nt] = __builtin_amdgcn_mfma_f32_16x16x32_bf16(ah[u], bl[nt], acc1[ct][nt], 0, 0, 0);
                    acc1[ct][nt] = __builtin_amdgcn_mfma_f32_16x16x32_bf16(al[u], bh[nt], acc1[ct][nt], 0, 0, 0);
                }
            }
        }
    }
    __syncthreads();   // gt reads done before st overlays U

    v4f acc2[2][4];
#pragma unroll
    for (int a = 0; a < 2; ++a)
#pragma unroll
        for (int b = 0; b < 4; ++b) acc2[a][b] = (v4f)(0.f);

#pragma unroll
    for (int hh = 0; hh < 2; ++hh) {
        // write st half hh: waves' ct{2hh, 2hh+1} tiles -> st rows [0,128)
#pragma unroll
        for (int c2 = 0; c2 < 2; ++c2) {
            const int ct = hh * 2 + c2;
#pragma unroll
            for (int nt = 0; nt < 4; ++nt) {
                alignas(8) unsigned short sh[4], sl[4];
#pragma unroll
                for (int r = 0; r < 4; ++r) {
                    const float v = fmaxf(acc1[ct][nt][r], 0.f);
                    split2(v, sh[r], sl[r]);
                }
                const int ci  = w * 32 + c2 * 16 + rbase;
                const int col = nt * 16 + l15;
                *(uint2*)&st_hi[col * 136 + ci] = *(uint2*)sh;
                *(uint2*)&st_lo[col * 136 + ci] = *(uint2*)sl;
            }
        }
        __syncthreads();

        for (int kc = 0; kc < 128; kc += 32) {
            v8s ah2[2], al2[2], bh2[4], bl2[4];
#pragma unroll
            for (int t = 0; t < 2; ++t) {
                const int row = (w * 32 + t * 16 + l15) * 256 + hh * 128 + kc + q8;
                ah2[t] = *(const v8s*)&e1t_hi[row];
                al2[t] = *(const v8s*)&e1t_lo[row];
            }
#pragma unroll
            for (int t = 0; t < 4; ++t) {
                const int bo = (t * 16 + l15) * 136 + kc + q8;
                bh2[t] = *(const v8s*)&st_hi[bo];
                bl2[t] = *(const v8s*)&st_lo[bo];
            }
#pragma unroll
            for (int ct = 0; ct < 2; ++ct)
#pragma unroll
                for (int nt = 0; nt < 4; ++nt) {
                    acc2[ct][nt] = __builtin_amdgcn_mfma_f32_16x16x32_bf16(ah2[ct], bh2[nt], acc2[ct][nt], 0, 0, 0);
                    acc2[ct][nt] = __builtin_amdgcn_mfma_f32_16x16x32_bf16(ah2[ct], bl2[nt], acc2[ct][nt], 0, 0, 0);
                    acc2[ct][nt] = __builtin_amdgcn_mfma_f32_16x16x32_bf16(al2[ct], bh2[nt], acc2[ct][nt], 0, 0, 0);
                }
        }
        if (hh == 0) __syncthreads();   // m2 half-0 reads done before st half-1 overwrite
    }

#pragma unroll
    for (int ct = 0; ct < 2; ++ct) {
        const int cobase = w * 32 + ct * 16 + rbase;
        float bb[4];
#pragma unroll
        for (int r = 0; r < 4; ++r) bb[r] = b1[cobase + r];
#pragma unroll
        for (int nt = 0; nt < 4; ++nt) {
            const int col = m0 + nt * 16 + l15;
#pragma unroll
            for (int r = 0; r < 4; ++r)
                y1[(size_t)(cobase + r) * gs + col] = fmaxf(acc2[ct][nt][r] + bb[r], 0.f);
        }
    }
}

// Fused maxpool3s2 + end2 (128->32) via split-bf16 MFMA. 64 pooled cols/block.
__global__ __launch_bounds__(256) void k_pe2_m(
    const float* __restrict__ y1c,
    const unsigned short* __restrict__ e2s_hi, const unsigned short* __restrict__ e2s_lo,
    const float* __restrict__ b2, float* __restrict__ e2c,
    const int gs, const int p1s)
{
    __shared__ unsigned short SP[2 * 64 * 136];
    unsigned short* sp_hi = SP;
    unsigned short* sp_lo = SP + 64 * 136;

    const int tid = threadIdx.x;
    const int m0 = blockIdx.x * 64;
    const int tp = m0 >> 8;
    const int nb = m0 & 255;

    {
        const int col = tid & 63;
        const int cig = tid >> 6;
        const int base = 2 * tp * 256 + nb + col;
#pragma unroll
        for (int u8 = 0; u8 < 4; ++u8) {
            alignas(16) unsigned short h8[8], l8[8];
#pragma unroll
            for (int u = 0; u < 8; ++u) {
                const int ci = cig * 32 + u8 * 8 + u;
                const float* yp = y1c + (size_t)ci * gs + base;
                const float v = fmaxf(fmaxf(yp[0], yp[256]), yp[512]);
                split2(v, h8[u], l8[u]);
            }
            *(uint4*)&sp_hi[col * 136 + cig * 32 + u8 * 8] = *(uint4*)h8;
            *(uint4*)&sp_lo[col * 136 + cig * 32 + u8 * 8] = *(uint4*)l8;
        }
    }
    __syncthreads();

    const int lane = tid & 63;
    const int w    = tid >> 6;
    const int mh   = w & 1;
    const int colh = w >> 1;
    const int l15  = lane & 15;
    const int quad = lane >> 4;
    const int q8   = quad * 8;

    v4f acc[2];
    acc[0] = (v4f)(0.f); acc[1] = (v4f)(0.f);

#pragma unroll
    for (int kc = 0; kc < 128; kc += 32) {
        const int row = (mh * 16 + l15) * 128 + kc + q8;
        const v8s ah = *(const v8s*)&e2s_hi[row];
        const v8s al = *(const v8s*)&e2s_lo[row];
#pragma unroll
        for (int nt = 0; nt < 2; ++nt) {
            const int col = colh * 32 + nt * 16 + l15;
            const v8s bh = *(const v8s*)&sp_hi[col * 136 + kc + q8];
            const v8s bl = *(const v8s*)&sp_lo[col * 136 + kc + q8];
            acc[nt] = __builtin_amdgcn_mfma_f32_16x16x32_bf16(ah, bh, acc[nt], 0, 0, 0);
            acc[nt] = __builtin_amdgcn_mfma_f32_16x16x32_bf16(ah, bl, acc[nt], 0, 0, 0);
            acc[nt] = __builtin_amdgcn_mfma_f32_16x16x32_bf16(al, bh, acc[nt], 0, 0, 0);
        }
    }

#pragma unroll
    for (int nt = 0; nt < 2; ++nt)
#pragma unroll
        for (int r = 0; r < 4; ++r) {
            const int co = mh * 16 + quad * 4 + r;
            const int col = m0 + colh * 32 + nt * 16 + l15;
            e2c[(size_t)co * p1s + col] = fmaxf(acc[nt][r] + b2[co], 0.f);
        }
}

// pool2 -> p2 stored packed-split u32 (consumed by k_fc1_m)
__global__ __launch_bounds__(256) void k_pool2p(const float* __restrict__ e2c,
                                                unsigned* __restrict__ p2,
                                                const int p1s, const int A) {
    const int n = threadIdx.x, tl2 = blockIdx.x, co = blockIdx.y;
    const int base = co * p1s + tl2 * 512 + n;
    float v = fmaxf(fmaxf(e2c[base], e2c[base + 256]), e2c[base + 512]);
    p2[co * 81152 + (A + tl2) * 256 + n] = packsplit(v);
}

// FC1 via split-bf16 MFMA: C[1024 x 256] += W1[1024 x 10144] @ P2[10144 x 256].
// R16: sb double-buffered -> 1 barrier per k-chunk (was 2), next-chunk
// loads issued before the MFMAs of the current chunk.
__global__ __launch_bounds__(256) void k_fc1_m(
    const unsigned short* __restrict__ w1s_hi, const unsigned short* __restrict__ w1s_lo,
    const unsigned* __restrict__ p2u, float* __restrict__ out)
{
    __shared__ unsigned short SB[2 * 2 * 64 * 40];   // 2 buffers x (hi+lo)

    const int tid = threadIdx.x;
    const int o0 = blockIdx.x * 64;
    const int b0 = blockIdx.y * 64;
    const int k0 = blockIdx.z * 1280;
    const int kend = (k0 + 1280 < 10144) ? (k0 + 1280) : 10144;
    const int nch = (kend - k0) >> 5;

    const int lane = tid & 63;
    const int w    = tid >> 6;
    const int l15  = lane & 15;
    const int quad = lane >> 4;
    const int q8   = quad * 8;
    const int scol = tid & 63;
    const int kq   = tid >> 6;

    v4f acc[4];
#pragma unroll
    for (int nt = 0; nt < 4; ++nt) acc[nt] = (v4f)(0.f);

    // prologue: stage chunk 0 into buffer 0
    {
        alignas(16) unsigned short h8[8], l8[8];
#pragma unroll
        for (int j = 0; j < 8; ++j) {
            const unsigned v = p2u[(size_t)(k0 + kq * 8 + j) * 256 + b0 + scol];
            h8[j] = (unsigned short)(v & 0xffffu);
            l8[j] = (unsigned short)(v >> 16);
        }
        *(v8s*)&SB[scol * 40 + kq * 8] = *(v8s*)h8;
        *(v8s*)&SB[2560 + scol * 40 + kq * 8] = *(v8s*)l8;
    }
    __syncthreads();

    int cur = 0;
    for (int c = 0; c < nch; ++c) {
        const int kc = k0 + c * 32;

        // issue next-chunk loads early (hidden under this chunk's MFMAs)
        unsigned nxt[8];
        if (c + 1 < nch) {
#pragma unroll
            for (int j = 0; j < 8; ++j)
                nxt[j] = p2u[(size_t)(kc + 32 + kq * 8 + j) * 256 + b0 + scol];
        }

        const unsigned short* sb_hi = SB + cur * 5120;
        const unsigned short* sb_lo = sb_hi + 2560;

        const int arow = (o0 + w * 16 + l15) * 10144 + kc + q8;
        const v8s ah = *(const v8s*)&w1s_hi[arow];
        const v8s al = *(const v8s*)&w1s_lo[arow];
#pragma unroll
        for (int nt = 0; nt < 4; ++nt) {
            const v8s bh = *(const v8s*)&sb_hi[(nt * 16 + l15) * 40 + q8];
            const v8s bl = *(const v8s*)&sb_lo[(nt * 16 + l15) * 40 + q8];
            acc[nt] = __builtin_amdgcn_mfma_f32_16x16x32_bf16(ah, bh, acc[nt], 0, 0, 0);
            acc[nt] = __builtin_amdgcn_mfma_f32_16x16x32_bf16(ah, bl, acc[nt], 0, 0, 0);
            acc[nt] = __builtin_amdgcn_mfma_f32_16x16x32_bf16(al, bh, acc[nt], 0, 0, 0);
        }

        if (c + 1 < nch) {
            unsigned short* nb_hi = SB + (cur ^ 1) * 5120;
            unsigned short* nb_lo = nb_hi + 2560;
            alignas(16) unsigned short h8[8], l8[8];
#pragma unroll
            for (int j = 0; j < 8; ++j) {
                h8[j] = (unsigned short)(nxt[j] & 0xffffu);
                l8[j] = (unsigned short)(nxt[j] >> 16);
            }
            *(v8s*)&nb_hi[scol * 40 + kq * 8] = *(v8s*)h8;
            *(v8s*)&nb_lo[scol * 40 + kq * 8] = *(v8s*)l8;
            __syncthreads();
            cur ^= 1;
        }
    }

#pragma unroll
    for (int nt = 0; nt < 4; ++nt)
#pragma unroll
        for (int r = 0; r < 4; ++r)
            atomicAdd(&out[(size_t)(o0 + w * 16 + quad * 4 + r) * 256 + b0 + nt * 16 + l15],
                      acc[nt][r]);
}

// Tiled f32 GEMM (FC2 only).
__global__ __launch_bounds__(256) void k_gemm64(const float* __restrict__ A,
                                                const float* __restrict__ B,
                                                float* __restrict__ C,
                                                const int Ktot, const int KC) {
    __shared__ float sA[32 * 65];
    __shared__ float sB[32 * 68];

    const int tid = threadIdx.x;
    const int o0 = blockIdx.x * 64;
    const int b0 = blockIdx.y * 64;
    const int k0 = blockIdx.z * KC;

    float acc[4][4];
#pragma unroll
    for (int i = 0; i < 4; ++i)
#pragma unroll
        for (int jq = 0; jq < 4; ++jq) acc[i][jq] = 0.f;

    const int ao  = tid >> 2;
    const int ak8 = (tid & 3) * 8;
    const int bk  = tid >> 3;
    const int bb8 = (tid & 7) * 8;
    const int to4 = (tid & 15) * 4;
    const int tb4 = (tid >> 4) * 4;

    for (int kc = 0; kc < KC; kc += 32) {
        const int kcLen = (KC - kc < 32) ? (KC - kc) : 32;
        const float* ap = A + (size_t)(o0 + ao) * Ktot + k0 + kc + ak8;
#pragma unroll
        for (int i = 0; i < 8; ++i) {
            float v = (ak8 + i < kcLen) ? ap[i] : 0.f;
            sA[(ak8 + i) * 65 + ao] = v;
        }
        if (bk < kcLen) {
            const float* bp = B + (size_t)(k0 + kc + bk) * 256 + b0 + bb8;
            const float4 v0 = *(const float4*)bp;
            const float4 v1 = *(const float4*)(bp + 4);
            *(float4*)&sB[bk * 68 + bb8] = v0;
            *(float4*)&sB[bk * 68 + bb8 + 4] = v1;
        } else {
            float4 z; z.x = z.y = z.z = z.w = 0.f;
            *(float4*)&sB[bk * 68 + bb8] = z;
            *(float4*)&sB[bk * 68 + bb8 + 4] = z;
        }
        __syncthreads();

#pragma unroll 8
        for (int kk = 0; kk < 32; ++kk) {
            const float4 av = *(const float4*)&sA[kk * 65 + to4];
            const float4 bv = *(const float4*)&sB[kk * 68 + tb4];
            const float aa[4] = {av.x, av.y, av.z, av.w};
#pragma unroll
            for (int i = 0; i < 4; ++i) {
                acc[i][0] = fmaf(aa[i], bv.x, acc[i][0]);
                acc[i][1] = fmaf(aa[i], bv.y, acc[i][1]);
                acc[i][2] = fmaf(aa[i], bv.z, acc[i][2]);
                acc[i][3] = fmaf(aa[i], bv.w, acc[i][3]);
            }
        }
        __syncthreads();
    }

#pragma unroll
    for (int i = 0; i < 4; ++i)
#pragma unroll
        for (int jq = 0; jq < 4; ++jq)
            atomicAdd(&C[(size_t)(o0 + to4 + i) * 256 + b0 + tb4 + jq], acc[i][jq]);
}

__global__ __launch_bounds__(256) void k_actbias(const float* __restrict__ raw,
                                                 const float* __restrict__ bias,
                                                 float* __restrict__ out) {
    const int k = blockIdx.x, b = threadIdx.x;
    out[k * 256 + b] = fmaxf(raw[k * 256 + b] + bias[k], 0.f);
}

__global__ __launch_bounds__(256) void k_fc3(const float* __restrict__ fc2raw,
                                             const float* __restrict__ fb2,
                                             const float* __restrict__ w3,
                                             const float* __restrict__ b3,
                                             float* __restrict__ out) {
    const int b = threadIdx.x;
    float l0 = b3[0], l1 = b3[1];
    for (int k = 0; k < 256; ++k) {
        const float a = fmaxf(fc2raw[k * 256 + b] + fb2[k], 0.f);
        l0 = fmaf(w3[k], a, l0);
        l1 = fmaf(w3[256 + k], a, l1);
    }
    out[2 * b] = l0;
    out[2 * b + 1] = l1;
    const float mx = fmaxf(l0, l1);
    const float e0 = expf(l0 - mx), e1 = expf(l1 - mx);
    const float inv = 1.f / (e0 + e1);
    out[512 + 2 * b] = e0 * inv;
    out[513 + 2 * b] = e1 * inv;
    out[1024 + b] = (l1 > l0) ? 1.f : 0.f;
}

extern "C" void kernel_launch(void* const* d_in, const int* in_sizes, int n_in,
                              void* d_out, int out_size, void* d_ws, size_t ws_size,
                              hipStream_t stream) {
    const float* x        = (const float*)d_in[0];
    const float* start_w  = (const float*)d_in[1];
    const float* filter_w = (const float*)d_in[2];
    const float* gate_w   = (const float*)d_in[3];
    const float* res_w    = (const float*)d_in[4];
    const float* skip_w   = (const float*)d_in[5];
    const float* e1w      = (const float*)d_in[6];
    const float* e1b      = (const float*)d_in[7];
    const float* e2w      = (const float*)d_in[8];
    const float* e2b      = (const float*)d_in[9];
    const float* w1       = (const float*)d_in[10];
    const float* fb1      = (const float*)d_in[11];
    const float* w2       = (const float*)d_in[12];
    const float* fb2      = (const float*)d_in[13];
    const float* w3       = (const float*)d_in[14];
    const float* b3       = (const float*)d_in[15];

    float* ws = (float*)d_ws;

    const long o_h0   = 0;            // 10,485,760
    const long o_p2   = 10485760;     // 2,596,864
    const long o_fc1  = 13082624;     // 262,144
    const long o_fc2  = 13344768;     // 65,536
    const long o_wbf  = 13410304;     // 81,920
    const long o_wfg  = 13492224;     // 24,576
    const long o_wr   = 13516800;     // 12,288
    const long o_e2s  = 13529088;     // 4,096
    const long o_act1 = 13533184;     // 262,144
    const long o_w1s  = 13795328;     // 10,387,456 (w1 hi+lo u16)
    const long o_G    = 24182784;

    long budget = (long)((double)ws_size * 0.94 / 4.0);
    int dB = 1;
    for (int d = 317; d >= 1; --d) {
        long mch = 256L * (4L * d + 3), hs = mch + 4096;
        long tot = o_G + 192L * mch + lmax_(128L * mch, 64L * hs);
        if (tot <= budget) { dB = d; break; }
    }
    int K = (317 + dB - 1) / dB;
    dB = (317 + K - 1) / K;
    const long MchA  = 256L * (4L * dB + 3);
    const long HSPAN = MchA + 4096;
    const long o_X   = o_G + 192L * MchA;
    const long P1S   = 256L * (2L * dB + 1);

    unsigned* h0 = (unsigned*)(ws + o_h0);
    unsigned* p2 = (unsigned*)(ws + o_p2);
    float* fc1r = ws + o_fc1;
    float* fc2r = ws + o_fc2;
    unsigned short* swt_hi = (unsigned short*)(ws + o_wbf);
    unsigned short* swt_lo = swt_hi + 49152;
    unsigned short* e1t_hi = swt_lo + 49152;
    unsigned short* e1t_lo = e1t_hi + 32768;
    unsigned short* wfg_hi = (unsigned short*)(ws + o_wfg);
    unsigned short* wfg_lo = wfg_hi + 24576;
    unsigned short* wr_hi  = (unsigned short*)(ws + o_wr);
    unsigned short* wr_lo  = wr_hi + 12288;
    unsigned short* e2s_hi = (unsigned short*)(ws + o_e2s);
    unsigned short* e2s_lo = e2s_hi + 4096;
    unsigned short* w1s_hi = (unsigned short*)(ws + o_w1s);
    unsigned short* w1s_lo = w1s_hi + 10387456;
    float* act1 = ws + o_act1;
    unsigned* G  = (unsigned*)(ws + o_G);
    unsigned* hA = (unsigned*)(ws + o_X);
    unsigned* hB = (unsigned*)(ws + o_X) + 32L * HSPAN;
    float* y1c  = ws + o_X;                 // aliases hA/hB (dead by then)
    float* e2c  = ws + o_G;                 // aliases G (dead after skip_end1)

    k_zero<<<1280, 256, 0, stream>>>(fc1r, 327680);
    k_start<<<1280, 256, 0, stream>>>(x, start_w, h0);
    k_prep<<<192, 256, 0, stream>>>(skip_w, e1w, filter_w, gate_w, res_w, e2w,
                                    swt_hi, swt_lo, e1t_hi, e1t_lo,
                                    wfg_hi, wfg_lo, wr_hi, wr_lo,
                                    e2s_hi, e2s_lo);
    k_prep_w1<<<40576, 256, 0, stream>>>(w1, w1s_hi, w1s_lo);

    const int Mc[6]   = {327424, 327168, 326656, 326400, 326144, 325632};
    const int NpmP[6] = {256, 256, 512, 256, 256, 512};
    const int pN[6]   = {0, 256, 512, 0, 256, 512};
    const int so_[6]  = {1792, 1536, 1024, 768, 512, 0};
    const int JloO[6] = {-1536, -1280, -768, -768, -512, 0};

    for (int c = 0; c < K; ++c) {
        const int A = c * dB;
        int B = A + dB; if (B > 317) B = 317;
        const int dBc = B - A;
        const int M0 = 1024 * A;
        int tmax = 4 * B + 3; if (tmax > 1272) tmax = 1272;
        const int Tt = tmax - 4 * A;
        const int M1 = M0 + 256 * Tt;

        int Jlo[6], Jhi[6];
        for (int q = 0; q < 6; ++q) {
            int lo = M0 + JloO[q]; if (lo < 0) lo = 0;
            int hi = M1 + so_[q];  if (hi > Mc[q]) hi = Mc[q];
            Jlo[q] = lo; Jhi[q] = hi;
        }

        for (int q = 0; q < 6; ++q) {
            const unsigned* hin = (q == 0) ? h0 : ((q & 1) ? hA : hB);
            const int hinBase   = (q == 0) ? 0 : Jlo[q - 1];
            const int hinStride = (q == 0) ? MCAP : (int)HSPAN;
            unsigned* hout = (q & 1) ? hB : hA;
            const int Jcnt = Jhi[q] - Jlo[q];     // % 128 == 0
            k_layer_m<<<Jcnt / 128, 256, 0, stream>>>(
                hin, hinBase, hinStride, hout, Jlo[q], (int)HSPAN,
                G + (long)q * 32 * MchA, (int)MchA,
                wfg_hi + q * 4096, wfg_lo + q * 4096,
                wr_hi + q * 2048, wr_lo + q * 2048,
                Jlo[q], NpmP[q], pN[q], so_[q], M0, M1, (q < 5) ? 1 : 0);
        }

        const int Mchc = 256 * Tt;
        k_skip_end1_m<<<Mchc / 64, 256, 0, stream>>>(
            G, swt_hi, swt_lo, e1t_hi, e1t_lo, e1b, y1c, (int)MchA);
        const int T1c = 2 * dBc + 1;
        k_pe2_m<<<T1c * 4, 256, 0, stream>>>(
            y1c, e2s_hi, e2s_lo, e2b, e2c, (int)MchA, (int)P1S);
        k_pool2p<<<dim3(dBc, 32), 256, 0, stream>>>(e2c, p2, (int)P1S, A);
    }

    k_fc1_m<<<dim3(16, 4, 8), 256, 0, stream>>>(w1s_hi, w1s_lo, p2, fc1r);
    k_actbias<<<1024, 256, 0, stream>>>(fc1r, fb1, act1);
    k_gemm64<<<dim3(4, 4, 4), 256, 0, stream>>>(w2, act1, fc2r, 1024, 256);
    k_fc3<<<1, 256, 0, stream>>>(fc2r, fb2, w3, b3, (float*)d_out);
}

// Round 8
// 822.084 us; speedup vs baseline: 1.2716x; 1.0454x over previous
//
#include <hip/hip_runtime.h>
#include <math.h>

// ---------------------------------------------------------------------------
// WaveNet forward. Layers, skip/end1, end2(+fused pool1), FC1 all via
// split-bf16 MFMA (3-term hi*hi+hi*lo+lo*hi, rel err ~2^-16). Flat layout
// (channel, time, batch) => buf[c][t*256+n]; dilate() is a reinterpretation.
// R17: revert to exact R12 (best, 829.7us) — R13..R16 skip_end1 restructures
// all regressed; that kernel is at its structural optimum. One new variable:
// k_layer_m gets an XCD-chunked bijective blockIdx swizzle (T1/m204). Layer
// blocks i and i +- NpmP/128 read the SAME hin lines (tap0/tap1 overlap, and
// doRes re-reads tap1); round-robin dispatch puts them on different XCDs ->
// HBM-latency misses in a latency-bound staging phase. Chunked mapping makes
// the overlap L2-local. Pure index remap; numerics untouched.
// ---------------------------------------------------------------------------

#define MCAP 327680

typedef short v8s __attribute__((ext_vector_type(8)));
typedef float v4f __attribute__((ext_vector_type(4)));

static inline long lmax_(long a, long b) { return a > b ? a : b; }

__device__ inline unsigned short rnbf(float x) {
    unsigned u = __float_as_uint(x);
    return (unsigned short)((u + 0x7FFFu + ((u >> 16) & 1u)) >> 16);
}
__device__ inline void split2(float v, unsigned short& h, unsigned short& l) {
    h = rnbf(v);
    const float hf = __uint_as_float(((unsigned)h) << 16);
    l = rnbf(v - hf);
}
__device__ inline unsigned packsplit(float v) {
    unsigned short h, l;
    split2(v, h, l);
    return ((unsigned)l << 16) | (unsigned)h;
}
__device__ inline float unpack2f(unsigned v) {
    return __uint_as_float(v << 16) + __uint_as_float(v & 0xffff0000u);
}

__global__ __launch_bounds__(256) void k_zero(float* __restrict__ p, int n) {
    int i = blockIdx.x * 256 + threadIdx.x;
    if (i < n) p[i] = 0.f;
}

// h0[o][t*256+n] = packsplit(sum_i start_w[o,i] * x[n,i,t])
__global__ __launch_bounds__(256) void k_start(const float* __restrict__ x,
                                               const float* __restrict__ sw,
                                               unsigned* __restrict__ h0) {
    int j = blockIdx.x * 256 + threadIdx.x;
    int t = j >> 8, n = j & 255;
    float xv[5];
#pragma unroll
    for (int i = 0; i < 5; ++i) xv[i] = x[n * 6400 + i * 1280 + t];
#pragma unroll
    for (int o = 0; o < 32; ++o) {
        float acc = 0.f;
#pragma unroll
        for (int i = 0; i < 5; ++i) acc = fmaf(sw[o * 5 + i], xv[i], acc);
        h0[o * MCAP + j] = packsplit(acc);
    }
}

// Prepack small weights (split bf16).
// e1t k-dim is PERMUTED for k_skip_end1_m's two-pass st consumption:
//   k_new = h*128 + w*32 + c*16 + r  <->  ch = w*64 + (2h+c)*16 + r
__global__ __launch_bounds__(256) void k_prep(const float* __restrict__ skw,
                                              const float* __restrict__ e1w,
                                              const float* __restrict__ fw,
                                              const float* __restrict__ gw,
                                              const float* __restrict__ rw,
                                              const float* __restrict__ e2w,
                                              unsigned short* __restrict__ swt_hi,
                                              unsigned short* __restrict__ swt_lo,
                                              unsigned short* __restrict__ e1t_hi,
                                              unsigned short* __restrict__ e1t_lo,
                                              unsigned short* __restrict__ wfg_hi,
                                              unsigned short* __restrict__ wfg_lo,
                                              unsigned short* __restrict__ wr_hi,
                                              unsigned short* __restrict__ wr_lo,
                                              unsigned short* __restrict__ e2s_hi,
                                              unsigned short* __restrict__ e2s_lo) {
    int idx = blockIdx.x * 256 + threadIdx.x;
    if (idx < 49152) {
        int ch = idx / 192, k = idx - ch * 192;
        int l = k >> 5, i = k & 31;
        unsigned short h, lo;
        split2(skw[l * 8192 + ch * 32 + i], h, lo);
        swt_hi[idx] = h; swt_lo[idx] = lo;
    }
    if (idx < 32768) {
        int co = idx >> 8, kn = idx & 255;
        int hf = kn >> 7, wv = (kn >> 5) & 3, c = (kn >> 4) & 1, r = kn & 15;
        int ch = wv * 64 + (hf * 2 + c) * 16 + r;
        unsigned short h, lo;
        split2(e1w[co * 256 + ch], h, lo);
        e1t_hi[idx] = h; e1t_lo[idx] = lo;
    }
    if (idx < 24576) {
        int l = idx >> 12, r = idx & 4095;
        int row = r >> 6, k = r & 63;
        int o = row & 31, i = k & 31, tap = k >> 5;
        const float* src = (row < 32) ? fw : gw;
        unsigned short h, lo;
        split2(src[l * 2048 + o * 64 + i * 2 + tap], h, lo);
        wfg_hi[idx] = h; wfg_lo[idx] = lo;
    }
    if (idx < 12288) {
        int l = idx >> 11, r = idx & 2047;
        int o = r >> 6, k = r & 63, i = k & 31;
        unsigned short h, lo;
        split2(rw[l * 1024 + o * 32 + i], h, lo);
        wr_hi[idx] = h; wr_lo[idx] = lo;
    }
    if (idx < 4096) {
        unsigned short h, lo;
        split2(e2w[idx], h, lo);
        e2s_hi[idx] = h; e2s_lo[idx] = lo;
    }
}

// Split fc1 weights (1024 x 10144, row-major, k-contiguous).
__global__ __launch_bounds__(256) void k_prep_w1(const float* __restrict__ w1,
                                                 unsigned short* __restrict__ hi,
                                                 unsigned short* __restrict__ lo) {
    int idx = blockIdx.x * 256 + threadIdx.x;
    if (idx < 10387456) {
        unsigned short h, l;
        split2(w1[idx], h, l);
        hi[idx] = h; lo[idx] = l;
    }
}

// One dilated gated layer via split-bf16 MFMA. 128-col tile, Jcnt % 128 == 0.
// hin/hout/gsl hold packed-split u32 activations. LDS: single 128x136 u16
// buffer; acts (AT) during stage A, gated k-ext (GT) after a barrier.
// R17: XCD-chunked bijective blockIdx swizzle (T1/m204) for hin L2 locality.
__global__ __launch_bounds__(256) void k_layer_m(
    const unsigned* __restrict__ hin, const int hinBase, const int hinStride,
    unsigned* __restrict__ hout, const int houtBase, const int houtStride,
    unsigned* __restrict__ gsl, const int gStride,
    const unsigned short* __restrict__ wfg_hi, const unsigned short* __restrict__ wfg_lo,
    const unsigned short* __restrict__ wr_hi, const unsigned short* __restrict__ wr_lo,
    const int Jlo, const int NpmP, const int padN,
    const int so_, const int M0, const int M1, const int doRes)
{
    __shared__ unsigned short U[128 * 136];
    unsigned short* AT = U;          // [col][k]: 0..63 hi, 64..127 lo (stage A)
    unsigned short* GT = U;          // [col][72]: 0..31 ghi, 32..63 glo (stage B)

    const int tid = threadIdx.x;
    // bijective XCD-chunked swizzle (m204): round-robin id -> chunked id
    int wg;
    {
        const int nwg = gridDim.x;
        const int q = nwg >> 3, r = nwg & 7;
        const int xcd = blockIdx.x & 7, off = blockIdx.x >> 3;
        wg = (xcd < r ? xcd * (q + 1) : r * (q + 1) + (xcd - r) * q) + off;
    }
    const int j0 = Jlo + wg * 128;

    {
        const int col = tid & 127;
        const int kg = tid >> 7;
        unsigned short* bh = &AT[col * 136 + kg * 32];
        unsigned short* bl = &AT[col * 136 + 64 + kg * 32];
        if (kg == 0 && j0 < padN) {
            uint4 z; z.x = z.y = z.z = z.w = 0u;
#pragma unroll
            for (int ch = 0; ch < 32; ch += 8) {
                *(uint4*)&bh[ch] = z;
                *(uint4*)&bl[ch] = z;
            }
        } else {
            const int off = (kg == 0) ? (j0 - padN) : (j0 + NpmP);
            const unsigned* p = hin + (off - hinBase) + col;
#pragma unroll
            for (int ch = 0; ch < 32; ch += 8) {
                alignas(16) unsigned short h8[8], l8[8];
#pragma unroll
                for (int u = 0; u < 8; ++u) {
                    const unsigned v = p[(size_t)(ch + u) * hinStride];
                    h8[u] = (unsigned short)(v & 0xffffu);
                    l8[u] = (unsigned short)(v >> 16);
                }
                *(uint4*)&bh[ch] = *(uint4*)h8;
                *(uint4*)&bl[ch] = *(uint4*)l8;
            }
        }
    }
    __syncthreads();

    const int lane = tid & 63;
    const int w    = tid >> 6;
    const int ch2  = w >> 1;
    const int mh   = w & 1;
    const int l15  = lane & 15;
    const int quad = lane >> 4;
    const int q8   = quad * 8;
    const int colb = ch2 * 64;

    v4f accf[4], accg[4];
#pragma unroll
    for (int nt = 0; nt < 4; ++nt) { accf[nt] = (v4f)(0.f); accg[nt] = (v4f)(0.f); }

#pragma unroll
    for (int kt = 0; kt < 2; ++kt) {
        const int frow = (mh * 16 + l15) * 64 + kt * 32 + q8;
        const int grow = (32 + mh * 16 + l15) * 64 + kt * 32 + q8;
        const v8s afh = *(const v8s*)&wfg_hi[frow];
        const v8s afl = *(const v8s*)&wfg_lo[frow];
        const v8s agh = *(const v8s*)&wfg_hi[grow];
        const v8s agl = *(const v8s*)&wfg_lo[grow];
#pragma unroll
        for (int nt = 0; nt < 4; ++nt) {
            const int col = colb + nt * 16 + l15;
            const v8s bh = *(const v8s*)&AT[col * 136 + kt * 32 + q8];
            const v8s bl = *(const v8s*)&AT[col * 136 + 64 + kt * 32 + q8];
            accf[nt] = __builtin_amdgcn_mfma_f32_16x16x32_bf16(afh, bh, accf[nt], 0, 0, 0);
            accf[nt] = __builtin_amdgcn_mfma_f32_16x16x32_bf16(afh, bl, accf[nt], 0, 0, 0);
            accf[nt] = __builtin_amdgcn_mfma_f32_16x16x32_bf16(afl, bh, accf[nt], 0, 0, 0);
            accg[nt] = __builtin_amdgcn_mfma_f32_16x16x32_bf16(agh, bh, accg[nt], 0, 0, 0);
            accg[nt] = __builtin_amdgcn_mfma_f32_16x16x32_bf16(agh, bl, accg[nt], 0, 0, 0);
            accg[nt] = __builtin_amdgcn_mfma_f32_16x16x32_bf16(agl, bh, accg[nt], 0, 0, 0);
        }
    }

    // gate + split (split reused for G store and GT staging)
    unsigned short gh[4][4], gl[4][4];
#pragma unroll
    for (int nt = 0; nt < 4; ++nt)
#pragma unroll
        for (int r = 0; r < 4; ++r) {
            const float f = accf[nt][r];
            const float g = accg[nt][r];
            const float th = 1.f - 2.f / (__expf(2.f * f) + 1.f);
            const float sg = 1.f / (1.f + __expf(-g));
            split2(th * sg, gh[nt][r], gl[nt][r]);
        }

    const int m0c = j0 - so_;
    if (m0c >= M0 && m0c < M1) {
#pragma unroll
        for (int nt = 0; nt < 4; ++nt)
#pragma unroll
            for (int r = 0; r < 4; ++r) {
                const int ch = mh * 16 + quad * 4 + r;
                const int m = (m0c - M0) + colb + nt * 16 + l15;
                gsl[(size_t)ch * gStride + m] =
                    ((unsigned)gl[nt][r] << 16) | (unsigned)gh[nt][r];
            }
    }

    if (doRes) {
        __syncthreads();   // all stage-A AT reads complete before GT overlays U
#pragma unroll
        for (int nt = 0; nt < 4; ++nt)
#pragma unroll
            for (int r = 0; r < 4; ++r) {
                const int ch = mh * 16 + quad * 4 + r;
                const int col = colb + nt * 16 + l15;
                GT[col * 72 + ch] = gh[nt][r];
                GT[col * 72 + 32 + ch] = gl[nt][r];
            }
        __syncthreads();

        v4f accr[4];
#pragma unroll
        for (int nt = 0; nt < 4; ++nt) accr[nt] = (v4f)(0.f);
#pragma unroll
        for (int kt = 0; kt < 2; ++kt) {
            const int row = (mh * 16 + l15) * 64 + kt * 32 + q8;
            const v8s arh = *(const v8s*)&wr_hi[row];
            const v8s arl = *(const v8s*)&wr_lo[row];
#pragma unroll
            for (int nt = 0; nt < 4; ++nt) {
                const int col = colb + nt * 16 + l15;
                const v8s b = *(const v8s*)&GT[col * 72 + kt * 32 + q8];
                accr[nt] = __builtin_amdgcn_mfma_f32_16x16x32_bf16(arh, b, accr[nt], 0, 0, 0);
                accr[nt] = __builtin_amdgcn_mfma_f32_16x16x32_bf16(arl, b, accr[nt], 0, 0, 0);
            }
        }

        // tap1 re-loaded from global (same packed value as the AT copy)
        const unsigned* tp = hin + (j0 + NpmP - hinBase);
#pragma unroll
        for (int nt = 0; nt < 4; ++nt)
#pragma unroll
            for (int r = 0; r < 4; ++r) {
                const int o = mh * 16 + quad * 4 + r;
                const int col = colb + nt * 16 + l15;
                const float tap1 = unpack2f(tp[(size_t)o * hinStride + col]);
                hout[(size_t)o * houtStride + (j0 - houtBase) + col] =
                    packsplit(accr[nt][r] + tap1);
            }
    }
}

// Fused skip -> relu -> end1 + bias -> relu -> y1 (split-bf16 MFMA).
// Exact R12: (256,3), pair-batched A-operands, T14 reg-prefetch of ph=1
// under m1-ph0 (write AFTER m1 in program order — the compiler-safe form).
// LDS 34.8 KB: gt 64x104, st 64x136 aliased; e1t k-permuted.
__global__ __launch_bounds__(256, 3) void k_skip_end1_m(
    const unsigned* __restrict__ g,
    const unsigned short* __restrict__ swt_hi, const unsigned short* __restrict__ swt_lo,
    const unsigned short* __restrict__ e1t_hi, const unsigned short* __restrict__ e1t_lo,
    const float* __restrict__ b1, float* __restrict__ y1, const int gs)
{
    __shared__ unsigned short U[17408];          // 34816 B
    unsigned short* gt_hi = U;                   // 64 x 104
    unsigned short* gt_lo = U + 6656;
    unsigned short* st_hi = U;                   // 64 x 136 (aliases gt)
    unsigned short* st_lo = U + 8704;

    const int tid  = threadIdx.x;
    const int m0   = blockIdx.x * 64;
    const int lane = tid & 63;
    const int w    = tid >> 6;
    const int l15  = lane & 15;
    const int q8   = (lane >> 4) * 8;
    const int rbase = (lane >> 4) * 4;

    const int scol = tid & 63;
    const int ks0  = (tid >> 6) * 8;

    v4f acc1[4][4];
#pragma unroll
    for (int a = 0; a < 4; ++a)
#pragma unroll
        for (int b = 0; b < 4; ++b) acc1[a][b] = (v4f)(0.f);

    // ---- stage ph=0 (k 0..95) directly to LDS ----
#pragma unroll
    for (int kc = 0; kc < 96; kc += 32) {
        alignas(16) unsigned short h8[8], l8[8];
#pragma unroll
        for (int j = 0; j < 8; ++j) {
            const int k = kc + ks0 + j;
            const unsigned v = g[(size_t)(k >> 5) * 32 * gs + (size_t)(k & 31) * gs + m0 + scol];
            h8[j] = (unsigned short)(v & 0xffffu);
            l8[j] = (unsigned short)(v >> 16);
        }
        *(v8s*)&gt_hi[scol * 104 + kc + ks0] = *(v8s*)h8;
        *(v8s*)&gt_lo[scol * 104 + kc + ks0] = *(v8s*)l8;
    }
    __syncthreads();

    // ---- T14: issue ph=1 (k 96..191) loads into regs; consumed after m1-ph0 ----
    unsigned pre[24];
#pragma unroll
    for (int c = 0; c < 3; ++c)
#pragma unroll
        for (int j = 0; j < 8; ++j) {
            const int k = 96 + c * 32 + ks0 + j;
            pre[c * 8 + j] = g[(size_t)(k >> 5) * 32 * gs + (size_t)(k & 31) * gs + m0 + scol];
        }

    // ---- m1 over ph=0 ----
    for (int kc = 0; kc < 96; kc += 32) {
        v8s bh[4], bl[4];
#pragma unroll
        for (int t = 0; t < 4; ++t) {
            const int bo = (t * 16 + l15) * 104 + kc + q8;
            bh[t] = *(const v8s*)&gt_hi[bo];
            bl[t] = *(const v8s*)&gt_lo[bo];
        }
#pragma unroll
        for (int cp = 0; cp < 2; ++cp) {
            v8s ah[2], al[2];
#pragma unroll
            for (int u = 0; u < 2; ++u) {
                const int ct = cp * 2 + u;
                const int row = (w * 64 + ct * 16 + l15) * 192 + kc + q8;
                ah[u] = *(const v8s*)&swt_hi[row];
                al[u] = *(const v8s*)&swt_lo[row];
            }
#pragma unroll
            for (int u = 0; u < 2; ++u) {
                const int ct = cp * 2 + u;
#pragma unroll
                for (int nt = 0; nt < 4; ++nt) {
                    acc1[ct][nt] = __builtin_amdgcn_mfma_f32_16x16x32_bf16(ah[u], bh[nt], acc1[ct][nt], 0, 0, 0);
                    acc1[ct][nt] = __builtin_amdgcn_mfma_f32_16x16x32_bf16(ah[u], bl[nt], acc1[ct][nt], 0, 0, 0);
                    acc1[ct][nt] = __builtin_amdgcn_mfma_f32_16x16x32_bf16(al[u], bh[nt], acc1[ct][nt], 0, 0, 0);
                }
            }
        }
    }
    __syncthreads();   // gt(ph0) reads done before overwrite

    // ---- write prefetched ph=1 to LDS ----
#pragma unroll
    for (int c = 0; c < 3; ++c) {
        alignas(16) unsigned short h8[8], l8[8];
#pragma unroll
        for (int j = 0; j < 8; ++j) {
            const unsigned v = pre[c * 8 + j];
            h8[j] = (unsigned short)(v & 0xffffu);
            l8[j] = (unsigned short)(v >> 16);
        }
        *(v8s*)&gt_hi[scol * 104 + c * 32 + ks0] = *(v8s*)h8;
        *(v8s*)&gt_lo[scol * 104 + c * 32 + ks0] = *(v8s*)l8;
    }
    __syncthreads();

    // ---- m1 over ph=1 ----
    for (int kc = 0; kc < 96; kc += 32) {
        v8s bh[4], bl[4];
#pragma unroll
        for (int t = 0; t < 4; ++t) {
            const int bo = (t * 16 + l15) * 104 + kc + q8;
            bh[t] = *(const v8s*)&gt_hi[bo];
            bl[t] = *(const v8s*)&gt_lo[bo];
        }
#pragma unroll
        for (int cp = 0; cp < 2; ++cp) {
            v8s ah[2], al[2];
#pragma unroll
            for (int u = 0; u < 2; ++u) {
                const int ct = cp * 2 + u;
                const int row = (w * 64 + ct * 16 + l15) * 192 + 96 + kc + q8;
                ah[u] = *(const v8s*)&swt_hi[row];
                al[u] = *(const v8s*)&swt_lo[row];
            }
#pragma unroll
            for (int u = 0; u < 2; ++u) {
                const int ct = cp * 2 + u;
#pragma unroll
                for (int nt = 0; nt < 4; ++nt) {
                    acc1[ct][nt] = __builtin_amdgcn_mfma_f32_16x16x32_bf16(ah[u], bh[nt], acc1[ct][nt], 0, 0, 0);
                    acc1[ct][nt] = __builtin_amdgcn_mfma_f32_16x16x32_bf16(ah[u], bl[nt], acc1[ct][nt], 0, 0, 0);
                    acc1[ct][nt] = __builtin_amdgcn_mfma_f32_16x16x32_bf16(al[u], bh[nt], acc1[ct][nt], 0, 0, 0);
                }
            }
        }
    }
    __syncthreads();   // gt reads done before st overlays U

    v4f acc2[2][4];
#pragma unroll
    for (int a = 0; a < 2; ++a)
#pragma unroll
        for (int b = 0; b < 4; ++b) acc2[a][b] = (v4f)(0.f);

#pragma unroll
    for (int hh = 0; hh < 2; ++hh) {
        // write st half hh: waves' ct{2hh, 2hh+1} tiles -> st rows [0,128)
#pragma unroll
        for (int c2 = 0; c2 < 2; ++c2) {
            const int ct = hh * 2 + c2;
#pragma unroll
            for (int nt = 0; nt < 4; ++nt) {
                alignas(8) unsigned short sh[4], sl[4];
#pragma unroll
                for (int r = 0; r < 4; ++r) {
                    const float v = fmaxf(acc1[ct][nt][r], 0.f);
                    split2(v, sh[r], sl[r]);
                }
                const int ci  = w * 32 + c2 * 16 + rbase;
                const int col = nt * 16 + l15;
                *(uint2*)&st_hi[col * 136 + ci] = *(uint2*)sh;
                *(uint2*)&st_lo[col * 136 + ci] = *(uint2*)sl;
            }
        }
        __syncthreads();

        for (int kc = 0; kc < 128; kc += 32) {
            v8s ah2[2], al2[2], bh2[4], bl2[4];
#pragma unroll
            for (int t = 0; t < 2; ++t) {
                const int row = (w * 32 + t * 16 + l15) * 256 + hh * 128 + kc + q8;
                ah2[t] = *(const v8s*)&e1t_hi[row];
                al2[t] = *(const v8s*)&e1t_lo[row];
            }
#pragma unroll
            for (int t = 0; t < 4; ++t) {
                const int bo = (t * 16 + l15) * 136 + kc + q8;
                bh2[t] = *(const v8s*)&st_hi[bo];
                bl2[t] = *(const v8s*)&st_lo[bo];
            }
#pragma unroll
            for (int ct = 0; ct < 2; ++ct)
#pragma unroll
                for (int nt = 0; nt < 4; ++nt) {
                    acc2[ct][nt] = __builtin_amdgcn_mfma_f32_16x16x32_bf16(ah2[ct], bh2[nt], acc2[ct][nt], 0, 0, 0);
                    acc2[ct][nt] = __builtin_amdgcn_mfma_f32_16x16x32_bf16(ah2[ct], bl2[nt], acc2[ct][nt], 0, 0, 0);
                    acc2[ct][nt] = __builtin_amdgcn_mfma_f32_16x16x32_bf16(al2[ct], bh2[nt], acc2[ct][nt], 0, 0, 0);
                }
        }
        if (hh == 0) __syncthreads();   // m2 half-0 reads done before st half-1 overwrite
    }

#pragma unroll
    for (int ct = 0; ct < 2; ++ct) {
        const int cobase = w * 32 + ct * 16 + rbase;
        float bb[4];
#pragma unroll
        for (int r = 0; r < 4; ++r) bb[r] = b1[cobase + r];
#pragma unroll
        for (int nt = 0; nt < 4; ++nt) {
            const int col = m0 + nt * 16 + l15;
#pragma unroll
            for (int r = 0; r < 4; ++r)
                y1[(size_t)(cobase + r) * gs + col] = fmaxf(acc2[ct][nt][r] + bb[r], 0.f);
        }
    }
}

// Fused maxpool3s2 + end2 (128->32) via split-bf16 MFMA. 64 pooled cols/block.
__global__ __launch_bounds__(256) void k_pe2_m(
    const float* __restrict__ y1c,
    const unsigned short* __restrict__ e2s_hi, const unsigned short* __restrict__ e2s_lo,
    const float* __restrict__ b2, float* __restrict__ e2c,
    const int gs, const int p1s)
{
    __shared__ unsigned short SP[2 * 64 * 136];
    unsigned short* sp_hi = SP;
    unsigned short* sp_lo = SP + 64 * 136;

    const int tid = threadIdx.x;
    const int m0 = blockIdx.x * 64;
    const int tp = m0 >> 8;
    const int nb = m0 & 255;

    {
        const int col = tid & 63;
        const int cig = tid >> 6;
        const int base = 2 * tp * 256 + nb + col;
#pragma unroll
        for (int u8 = 0; u8 < 4; ++u8) {
            alignas(16) unsigned short h8[8], l8[8];
#pragma unroll
            for (int u = 0; u < 8; ++u) {
                const int ci = cig * 32 + u8 * 8 + u;
                const float* yp = y1c + (size_t)ci * gs + base;
                const float v = fmaxf(fmaxf(yp[0], yp[256]), yp[512]);
                split2(v, h8[u], l8[u]);
            }
            *(uint4*)&sp_hi[col * 136 + cig * 32 + u8 * 8] = *(uint4*)h8;
            *(uint4*)&sp_lo[col * 136 + cig * 32 + u8 * 8] = *(uint4*)l8;
        }
    }
    __syncthreads();

    const int lane = tid & 63;
    const int w    = tid >> 6;
    const int mh   = w & 1;
    const int colh = w >> 1;
    const int l15  = lane & 15;
    const int quad = lane >> 4;
    const int q8   = quad * 8;

    v4f acc[2];
    acc[0] = (v4f)(0.f); acc[1] = (v4f)(0.f);

#pragma unroll
    for (int kc = 0; kc < 128; kc += 32) {
        const int row = (mh * 16 + l15) * 128 + kc + q8;
        const v8s ah = *(const v8s*)&e2s_hi[row];
        const v8s al = *(const v8s*)&e2s_lo[row];
#pragma unroll
        for (int nt = 0; nt < 2; ++nt) {
            const int col = colh * 32 + nt * 16 + l15;
            const v8s bh = *(const v8s*)&sp_hi[col * 136 + kc + q8];
            const v8s bl = *(const v8s*)&sp_lo[col * 136 + kc + q8];
            acc[nt] = __builtin_amdgcn_mfma_f32_16x16x32_bf16(ah, bh, acc[nt], 0, 0, 0);
            acc[nt] = __builtin_amdgcn_mfma_f32_16x16x32_bf16(ah, bl, acc[nt], 0, 0, 0);
            acc[nt] = __builtin_amdgcn_mfma_f32_16x16x32_bf16(al, bh, acc[nt], 0, 0, 0);
        }
    }

#pragma unroll
    for (int nt = 0; nt < 2; ++nt)
#pragma unroll
        for (int r = 0; r < 4; ++r) {
            const int co = mh * 16 + quad * 4 + r;
            const int col = m0 + colh * 32 + nt * 16 + l15;
            e2c[(size_t)co * p1s + col] = fmaxf(acc[nt][r] + b2[co], 0.f);
        }
}

// pool2 -> p2 stored packed-split u32 (consumed by k_fc1_m)
__global__ __launch_bounds__(256) void k_pool2p(const float* __restrict__ e2c,
                                                unsigned* __restrict__ p2,
                                                const int p1s, const int A) {
    const int n = threadIdx.x, tl2 = blockIdx.x, co = blockIdx.y;
    const int base = co * p1s + tl2 * 512 + n;
    float v = fmaxf(fmaxf(e2c[base], e2c[base + 256]), e2c[base + 512]);
    p2[co * 81152 + (A + tl2) * 256 + n] = packsplit(v);
}

// FC1 via split-bf16 MFMA: C[1024 x 256] += W1[1024 x 10144] @ P2[10144 x 256].
__global__ __launch_bounds__(256) void k_fc1_m(
    const unsigned short* __restrict__ w1s_hi, const unsigned short* __restrict__ w1s_lo,
    const unsigned* __restrict__ p2u, float* __restrict__ out)
{
    __shared__ unsigned short SB[2 * 64 * 40];
    unsigned short* sb_hi = SB;
    unsigned short* sb_lo = SB + 64 * 40;

    const int tid = threadIdx.x;
    const int o0 = blockIdx.x * 64;
    const int b0 = blockIdx.y * 64;
    const int k0 = blockIdx.z * 1280;
    const int kend = (k0 + 1280 < 10144) ? (k0 + 1280) : 10144;
    const int nch = (kend - k0) >> 5;

    const int lane = tid & 63;
    const int w    = tid >> 6;
    const int l15  = lane & 15;
    const int quad = lane >> 4;
    const int q8   = quad * 8;
    const int scol = tid & 63;
    const int kq   = tid >> 6;

    v4f acc[4];
#pragma unroll
    for (int nt = 0; nt < 4; ++nt) acc[nt] = (v4f)(0.f);

    for (int c = 0; c < nch; ++c) {
        const int kc = k0 + c * 32;
        alignas(16) unsigned short h8[8], l8[8];
#pragma unroll
        for (int j = 0; j < 8; ++j) {
            const unsigned v = p2u[(size_t)(kc + kq * 8 + j) * 256 + b0 + scol];
            h8[j] = (unsigned short)(v & 0xffffu);
            l8[j] = (unsigned short)(v >> 16);
        }
        __syncthreads();
        *(v8s*)&sb_hi[scol * 40 + kq * 8] = *(v8s*)h8;
        *(v8s*)&sb_lo[scol * 40 + kq * 8] = *(v8s*)l8;
        __syncthreads();

        const int arow = (o0 + w * 16 + l15) * 10144 + kc + q8;
        const v8s ah = *(const v8s*)&w1s_hi[arow];
        const v8s al = *(const v8s*)&w1s_lo[arow];
#pragma unroll
        for (int nt = 0; nt < 4; ++nt) {
            const v8s bh = *(const v8s*)&sb_hi[(nt * 16 + l15) * 40 + q8];
            const v8s bl = *(const v8s*)&sb_lo[(nt * 16 + l15) * 40 + q8];
            acc[nt] = __builtin_amdgcn_mfma_f32_16x16x32_bf16(ah, bh, acc[nt], 0, 0, 0);
            acc[nt] = __builtin_amdgcn_mfma_f32_16x16x32_bf16(ah, bl, acc[nt], 0, 0, 0);
            acc[nt] = __builtin_amdgcn_mfma_f32_16x16x32_bf16(al, bh, acc[nt], 0, 0, 0);
        }
    }

#pragma unroll
    for (int nt = 0; nt < 4; ++nt)
#pragma unroll
        for (int r = 0; r < 4; ++r)
            atomicAdd(&out[(size_t)(o0 + w * 16 + quad * 4 + r) * 256 + b0 + nt * 16 + l15],
                      acc[nt][r]);
}

// Tiled f32 GEMM (FC2 only).
__global__ __launch_bounds__(256) void k_gemm64(const float* __restrict__ A,
                                                const float* __restrict__ B,
                                                float* __restrict__ C,
                                                const int Ktot, const int KC) {
    __shared__ float sA[32 * 65];
    __shared__ float sB[32 * 68];

    const int tid = threadIdx.x;
    const int o0 = blockIdx.x * 64;
    const int b0 = blockIdx.y * 64;
    const int k0 = blockIdx.z * KC;

    float acc[4][4];
#pragma unroll
    for (int i = 0; i < 4; ++i)
#pragma unroll
        for (int jq = 0; jq < 4; ++jq) acc[i][jq] = 0.f;

    const int ao  = tid >> 2;
    const int ak8 = (tid & 3) * 8;
    const int bk  = tid >> 3;
    const int bb8 = (tid & 7) * 8;
    const int to4 = (tid & 15) * 4;
    const int tb4 = (tid >> 4) * 4;

    for (int kc = 0; kc < KC; kc += 32) {
        const int kcLen = (KC - kc < 32) ? (KC - kc) : 32;
        const float* ap = A + (size_t)(o0 + ao) * Ktot + k0 + kc + ak8;
#pragma unroll
        for (int i = 0; i < 8; ++i) {
            float v = (ak8 + i < kcLen) ? ap[i] : 0.f;
            sA[(ak8 + i) * 65 + ao] = v;
        }
        if (bk < kcLen) {
            const float* bp = B + (size_t)(k0 + kc + bk) * 256 + b0 + bb8;
            const float4 v0 = *(const float4*)bp;
            const float4 v1 = *(const float4*)(bp + 4);
            *(float4*)&sB[bk * 68 + bb8] = v0;
            *(float4*)&sB[bk * 68 + bb8 + 4] = v1;
        } else {
            float4 z; z.x = z.y = z.z = z.w = 0.f;
            *(float4*)&sB[bk * 68 + bb8] = z;
            *(float4*)&sB[bk * 68 + bb8 + 4] = z;
        }
        __syncthreads();

#pragma unroll 8
        for (int kk = 0; kk < 32; ++kk) {
            const float4 av = *(const float4*)&sA[kk * 65 + to4];
            const float4 bv = *(const float4*)&sB[kk * 68 + tb4];
            const float aa[4] = {av.x, av.y, av.z, av.w};
#pragma unroll
            for (int i = 0; i < 4; ++i) {
                acc[i][0] = fmaf(aa[i], bv.x, acc[i][0]);
                acc[i][1] = fmaf(aa[i], bv.y, acc[i][1]);
                acc[i][2] = fmaf(aa[i], bv.z, acc[i][2]);
                acc[i][3] = fmaf(aa[i], bv.w, acc[i][3]);
            }
        }
        __syncthreads();
    }

#pragma unroll
    for (int i = 0; i < 4; ++i)
#pragma unroll
        for (int jq = 0; jq < 4; ++jq)
            atomicAdd(&C[(size_t)(o0 + to4 + i) * 256 + b0 + tb4 + jq], acc[i][jq]);
}

__global__ __launch_bounds__(256) void k_actbias(const float* __restrict__ raw,
                                                 const float* __restrict__ bias,
                                                 float* __restrict__ out) {
    const int k = blockIdx.x, b = threadIdx.x;
    out[k * 256 + b] = fmaxf(raw[k * 256 + b] + bias[k], 0.f);
}

__global__ __launch_bounds__(256) void k_fc3(const float* __restrict__ fc2raw,
                                             const float* __restrict__ fb2,
                                             const float* __restrict__ w3,
                                             const float* __restrict__ b3,
                                             float* __restrict__ out) {
    const int b = threadIdx.x;
    float l0 = b3[0], l1 = b3[1];
    for (int k = 0; k < 256; ++k) {
        const float a = fmaxf(fc2raw[k * 256 + b] + fb2[k], 0.f);
        l0 = fmaf(w3[k], a, l0);
        l1 = fmaf(w3[256 + k], a, l1);
    }
    out[2 * b] = l0;
    out[2 * b + 1] = l1;
    const float mx = fmaxf(l0, l1);
    const float e0 = expf(l0 - mx), e1 = expf(l1 - mx);
    const float inv = 1.f / (e0 + e1);
    out[512 + 2 * b] = e0 * inv;
    out[513 + 2 * b] = e1 * inv;
    out[1024 + b] = (l1 > l0) ? 1.f : 0.f;
}

extern "C" void kernel_launch(void* const* d_in, const int* in_sizes, int n_in,
                              void* d_out, int out_size, void* d_ws, size_t ws_size,
                              hipStream_t stream) {
    const float* x        = (const float*)d_in[0];
    const float* start_w  = (const float*)d_in[1];
    const float* filter_w = (const float*)d_in[2];
    const float* gate_w   = (const float*)d_in[3];
    const float* res_w    = (const float*)d_in[4];
    const float* skip_w   = (const float*)d_in[5];
    const float* e1w      = (const float*)d_in[6];
    const float* e1b      = (const float*)d_in[7];
    const float* e2w      = (const float*)d_in[8];
    const float* e2b      = (const float*)d_in[9];
    const float* w1       = (const float*)d_in[10];
    const float* fb1      = (const float*)d_in[11];
    const float* w2       = (const float*)d_in[12];
    const float* fb2      = (const float*)d_in[13];
    const float* w3       = (const float*)d_in[14];
    const float* b3       = (const float*)d_in[15];

    float* ws = (float*)d_ws;

    const long o_h0   = 0;            // 10,485,760
    const long o_p2   = 10485760;     // 2,596,864
    const long o_fc1  = 13082624;     // 262,144
    const long o_fc2  = 13344768;     // 65,536
    const long o_wbf  = 13410304;     // 81,920
    const long o_wfg  = 13492224;     // 24,576
    const long o_wr   = 13516800;     // 12,288
    const long o_e2s  = 13529088;     // 4,096
    const long o_act1 = 13533184;     // 262,144
    const long o_w1s  = 13795328;     // 10,387,456 (w1 hi+lo u16)
    const long o_G    = 24182784;

    long budget = (long)((double)ws_size * 0.94 / 4.0);
    int dB = 1;
    for (int d = 317; d >= 1; --d) {
        long mch = 256L * (4L * d + 3), hs = mch + 4096;
        long tot = o_G + 192L * mch + lmax_(128L * mch, 64L * hs);
        if (tot <= budget) { dB = d; break; }
    }
    int K = (317 + dB - 1) / dB;
    dB = (317 + K - 1) / K;
    const long MchA  = 256L * (4L * dB + 3);
    const long HSPAN = MchA + 4096;
    const long o_X   = o_G + 192L * MchA;
    const long P1S   = 256L * (2L * dB + 1);

    unsigned* h0 = (unsigned*)(ws + o_h0);
    unsigned* p2 = (unsigned*)(ws + o_p2);
    float* fc1r = ws + o_fc1;
    float* fc2r = ws + o_fc2;
    unsigned short* swt_hi = (unsigned short*)(ws + o_wbf);
    unsigned short* swt_lo = swt_hi + 49152;
    unsigned short* e1t_hi = swt_lo + 49152;
    unsigned short* e1t_lo = e1t_hi + 32768;
    unsigned short* wfg_hi = (unsigned short*)(ws + o_wfg);
    unsigned short* wfg_lo = wfg_hi + 24576;
    unsigned short* wr_hi  = (unsigned short*)(ws + o_wr);
    unsigned short* wr_lo  = wr_hi + 12288;
    unsigned short* e2s_hi = (unsigned short*)(ws + o_e2s);
    unsigned short* e2s_lo = e2s_hi + 4096;
    unsigned short* w1s_hi = (unsigned short*)(ws + o_w1s);
    unsigned short* w1s_lo = w1s_hi + 10387456;
    float* act1 = ws + o_act1;
    unsigned* G  = (unsigned*)(ws + o_G);
    unsigned* hA = (unsigned*)(ws + o_X);
    unsigned* hB = (unsigned*)(ws + o_X) + 32L * HSPAN;
    float* y1c  = ws + o_X;                 // aliases hA/hB (dead by then)
    float* e2c  = ws + o_G;                 // aliases G (dead after skip_end1)

    k_zero<<<1280, 256, 0, stream>>>(fc1r, 327680);
    k_start<<<1280, 256, 0, stream>>>(x, start_w, h0);
    k_prep<<<192, 256, 0, stream>>>(skip_w, e1w, filter_w, gate_w, res_w, e2w,
                                    swt_hi, swt_lo, e1t_hi, e1t_lo,
                                    wfg_hi, wfg_lo, wr_hi, wr_lo,
                                    e2s_hi, e2s_lo);
    k_prep_w1<<<40576, 256, 0, stream>>>(w1, w1s_hi, w1s_lo);

    const int Mc[6]   = {327424, 327168, 326656, 326400, 326144, 325632};
    const int NpmP[6] = {256, 256, 512, 256, 256, 512};
    const int pN[6]   = {0, 256, 512, 0, 256, 512};
    const int so_[6]  = {1792, 1536, 1024, 768, 512, 0};
    const int JloO[6] = {-1536, -1280, -768, -768, -512, 0};

    for (int c = 0; c < K; ++c) {
        const int A = c * dB;
        int B = A + dB; if (B > 317) B = 317;
        const int dBc = B - A;
        const int M0 = 1024 * A;
        int tmax = 4 * B + 3; if (tmax > 1272) tmax = 1272;
        const int Tt = tmax - 4 * A;
        const int M1 = M0 + 256 * Tt;

        int Jlo[6], Jhi[6];
        for (int q = 0; q < 6; ++q) {
            int lo = M0 + JloO[q]; if (lo < 0) lo = 0;
            int hi = M1 + so_[q];  if (hi > Mc[q]) hi = Mc[q];
            Jlo[q] = lo; Jhi[q] = hi;
        }

        for (int q = 0; q < 6; ++q) {
            const unsigned* hin = (q == 0) ? h0 : ((q & 1) ? hA : hB);
            const int hinBase   = (q == 0) ? 0 : Jlo[q - 1];
            const int hinStride = (q == 0) ? MCAP : (int)HSPAN;
            unsigned* hout = (q & 1) ? hB : hA;
            const int Jcnt = Jhi[q] - Jlo[q];     // % 128 == 0
            k_layer_m<<<Jcnt / 128, 256, 0, stream>>>(
                hin, hinBase, hinStride, hout, Jlo[q], (int)HSPAN,
                G + (long)q * 32 * MchA, (int)MchA,
                wfg_hi + q * 4096, wfg_lo + q * 4096,
                wr_hi + q * 2048, wr_lo + q * 2048,
                Jlo[q], NpmP[q], pN[q], so_[q], M0, M1, (q < 5) ? 1 : 0);
        }

        const int Mchc = 256 * Tt;
        k_skip_end1_m<<<Mchc / 64, 256, 0, stream>>>(
            G, swt_hi, swt_lo, e1t_hi, e1t_lo, e1b, y1c, (int)MchA);
        const int T1c = 2 * dBc + 1;
        k_pe2_m<<<T1c * 4, 256, 0, stream>>>(
            y1c, e2s_hi, e2s_lo, e2b, e2c, (int)MchA, (int)P1S);
        k_pool2p<<<dim3(dBc, 32), 256, 0, stream>>>(e2c, p2, (int)P1S, A);
    }

    k_fc1_m<<<dim3(16, 4, 8), 256, 0, stream>>>(w1s_hi, w1s_lo, p2, fc1r);
    k_actbias<<<1024, 256, 0, stream>>>(fc1r, fb1, act1);
    k_gemm64<<<dim3(4, 4, 4), 256, 0, stream>>>(w2, act1, fc2r, 1024, 256);
    k_fc3<<<1, 256, 0, stream>>>(fc2r, fb2, w3, b3, (float*)d_out);
}

// Round 9
// 818.915 us; speedup vs baseline: 1.2765x; 1.0039x over previous
//
#include <hip/hip_runtime.h>
#include <math.h>

// ---------------------------------------------------------------------------
// WaveNet forward. Layers, skip/end1, end2(+fused pool1), FC1 all via
// split-bf16 MFMA (3-term hi*hi+hi*lo+lo*hi, rel err ~2^-16). Flat layout
// (channel, time, batch) => buf[c][t*256+n]; dilate() is a reinterpretation.
// R18: extend R17's XCD-chunked swizzle (T1/m204, +8us on layers) to
// k_skip_end1_m and k_pe2_m. Mechanism: producer->consumer XCD alignment.
// Layers (chunked) write G; a round-robin skip_end1 block for G cols b*64
// lands on XCD b%8 while the producer sits at XCD ~ 8*colfrac -> cross-XCD
// HBM misses for data still dirty in the producer's L2. Same seam between
// skip_end1 (y1c writer) and pe2 (pool-window reader, 33% t1-adjacent
// overlap). Identical chunked map on all three aligns the whole chunk
// pipeline. Pure index remap; numerics/structure/occupancy untouched.
// ---------------------------------------------------------------------------

#define MCAP 327680

typedef short v8s __attribute__((ext_vector_type(8)));
typedef float v4f __attribute__((ext_vector_type(4)));

static inline long lmax_(long a, long b) { return a > b ? a : b; }

__device__ inline unsigned short rnbf(float x) {
    unsigned u = __float_as_uint(x);
    return (unsigned short)((u + 0x7FFFu + ((u >> 16) & 1u)) >> 16);
}
__device__ inline void split2(float v, unsigned short& h, unsigned short& l) {
    h = rnbf(v);
    const float hf = __uint_as_float(((unsigned)h) << 16);
    l = rnbf(v - hf);
}
__device__ inline unsigned packsplit(float v) {
    unsigned short h, l;
    split2(v, h, l);
    return ((unsigned)l << 16) | (unsigned)h;
}
__device__ inline float unpack2f(unsigned v) {
    return __uint_as_float(v << 16) + __uint_as_float(v & 0xffff0000u);
}

// bijective XCD-chunked swizzle (m204): round-robin id -> chunked id
__device__ inline int xcd_chunk(int bid, int nwg) {
    const int q = nwg >> 3, r = nwg & 7;
    const int xcd = bid & 7, off = bid >> 3;
    return (xcd < r ? xcd * (q + 1) : r * (q + 1) + (xcd - r) * q) + off;
}

__global__ __launch_bounds__(256) void k_zero(float* __restrict__ p, int n) {
    int i = blockIdx.x * 256 + threadIdx.x;
    if (i < n) p[i] = 0.f;
}

// h0[o][t*256+n] = packsplit(sum_i start_w[o,i] * x[n,i,t])
__global__ __launch_bounds__(256) void k_start(const float* __restrict__ x,
                                               const float* __restrict__ sw,
                                               unsigned* __restrict__ h0) {
    int j = blockIdx.x * 256 + threadIdx.x;
    int t = j >> 8, n = j & 255;
    float xv[5];
#pragma unroll
    for (int i = 0; i < 5; ++i) xv[i] = x[n * 6400 + i * 1280 + t];
#pragma unroll
    for (int o = 0; o < 32; ++o) {
        float acc = 0.f;
#pragma unroll
        for (int i = 0; i < 5; ++i) acc = fmaf(sw[o * 5 + i], xv[i], acc);
        h0[o * MCAP + j] = packsplit(acc);
    }
}

// Prepack small weights (split bf16).
// e1t k-dim is PERMUTED for k_skip_end1_m's two-pass st consumption:
//   k_new = h*128 + w*32 + c*16 + r  <->  ch = w*64 + (2h+c)*16 + r
__global__ __launch_bounds__(256) void k_prep(const float* __restrict__ skw,
                                              const float* __restrict__ e1w,
                                              const float* __restrict__ fw,
                                              const float* __restrict__ gw,
                                              const float* __restrict__ rw,
                                              const float* __restrict__ e2w,
                                              unsigned short* __restrict__ swt_hi,
                                              unsigned short* __restrict__ swt_lo,
                                              unsigned short* __restrict__ e1t_hi,
                                              unsigned short* __restrict__ e1t_lo,
                                              unsigned short* __restrict__ wfg_hi,
                                              unsigned short* __restrict__ wfg_lo,
                                              unsigned short* __restrict__ wr_hi,
                                              unsigned short* __restrict__ wr_lo,
                                              unsigned short* __restrict__ e2s_hi,
                                              unsigned short* __restrict__ e2s_lo) {
    int idx = blockIdx.x * 256 + threadIdx.x;
    if (idx < 49152) {
        int ch = idx / 192, k = idx - ch * 192;
        int l = k >> 5, i = k & 31;
        unsigned short h, lo;
        split2(skw[l * 8192 + ch * 32 + i], h, lo);
        swt_hi[idx] = h; swt_lo[idx] = lo;
    }
    if (idx < 32768) {
        int co = idx >> 8, kn = idx & 255;
        int hf = kn >> 7, wv = (kn >> 5) & 3, c = (kn >> 4) & 1, r = kn & 15;
        int ch = wv * 64 + (hf * 2 + c) * 16 + r;
        unsigned short h, lo;
        split2(e1w[co * 256 + ch], h, lo);
        e1t_hi[idx] = h; e1t_lo[idx] = lo;
    }
    if (idx < 24576) {
        int l = idx >> 12, r = idx & 4095;
        int row = r >> 6, k = r & 63;
        int o = row & 31, i = k & 31, tap = k >> 5;
        const float* src = (row < 32) ? fw : gw;
        unsigned short h, lo;
        split2(src[l * 2048 + o * 64 + i * 2 + tap], h, lo);
        wfg_hi[idx] = h; wfg_lo[idx] = lo;
    }
    if (idx < 12288) {
        int l = idx >> 11, r = idx & 2047;
        int o = r >> 6, k = r & 63, i = k & 31;
        unsigned short h, lo;
        split2(rw[l * 1024 + o * 32 + i], h, lo);
        wr_hi[idx] = h; wr_lo[idx] = lo;
    }
    if (idx < 4096) {
        unsigned short h, lo;
        split2(e2w[idx], h, lo);
        e2s_hi[idx] = h; e2s_lo[idx] = lo;
    }
}

// Split fc1 weights (1024 x 10144, row-major, k-contiguous).
__global__ __launch_bounds__(256) void k_prep_w1(const float* __restrict__ w1,
                                                 unsigned short* __restrict__ hi,
                                                 unsigned short* __restrict__ lo) {
    int idx = blockIdx.x * 256 + threadIdx.x;
    if (idx < 10387456) {
        unsigned short h, l;
        split2(w1[idx], h, l);
        hi[idx] = h; lo[idx] = l;
    }
}

// One dilated gated layer via split-bf16 MFMA. 128-col tile, Jcnt % 128 == 0.
// hin/hout/gsl hold packed-split u32 activations. LDS: single 128x136 u16
// buffer; acts (AT) during stage A, gated k-ext (GT) after a barrier.
// XCD-chunked bijective blockIdx swizzle (T1/m204) for hin L2 locality.
__global__ __launch_bounds__(256) void k_layer_m(
    const unsigned* __restrict__ hin, const int hinBase, const int hinStride,
    unsigned* __restrict__ hout, const int houtBase, const int houtStride,
    unsigned* __restrict__ gsl, const int gStride,
    const unsigned short* __restrict__ wfg_hi, const unsigned short* __restrict__ wfg_lo,
    const unsigned short* __restrict__ wr_hi, const unsigned short* __restrict__ wr_lo,
    const int Jlo, const int NpmP, const int padN,
    const int so_, const int M0, const int M1, const int doRes)
{
    __shared__ unsigned short U[128 * 136];
    unsigned short* AT = U;          // [col][k]: 0..63 hi, 64..127 lo (stage A)
    unsigned short* GT = U;          // [col][72]: 0..31 ghi, 32..63 glo (stage B)

    const int tid = threadIdx.x;
    const int wg = xcd_chunk(blockIdx.x, gridDim.x);
    const int j0 = Jlo + wg * 128;

    {
        const int col = tid & 127;
        const int kg = tid >> 7;
        unsigned short* bh = &AT[col * 136 + kg * 32];
        unsigned short* bl = &AT[col * 136 + 64 + kg * 32];
        if (kg == 0 && j0 < padN) {
            uint4 z; z.x = z.y = z.z = z.w = 0u;
#pragma unroll
            for (int ch = 0; ch < 32; ch += 8) {
                *(uint4*)&bh[ch] = z;
                *(uint4*)&bl[ch] = z;
            }
        } else {
            const int off = (kg == 0) ? (j0 - padN) : (j0 + NpmP);
            const unsigned* p = hin + (off - hinBase) + col;
#pragma unroll
            for (int ch = 0; ch < 32; ch += 8) {
                alignas(16) unsigned short h8[8], l8[8];
#pragma unroll
                for (int u = 0; u < 8; ++u) {
                    const unsigned v = p[(size_t)(ch + u) * hinStride];
                    h8[u] = (unsigned short)(v & 0xffffu);
                    l8[u] = (unsigned short)(v >> 16);
                }
                *(uint4*)&bh[ch] = *(uint4*)h8;
                *(uint4*)&bl[ch] = *(uint4*)l8;
            }
        }
    }
    __syncthreads();

    const int lane = tid & 63;
    const int w    = tid >> 6;
    const int ch2  = w >> 1;
    const int mh   = w & 1;
    const int l15  = lane & 15;
    const int quad = lane >> 4;
    const int q8   = quad * 8;
    const int colb = ch2 * 64;

    v4f accf[4], accg[4];
#pragma unroll
    for (int nt = 0; nt < 4; ++nt) { accf[nt] = (v4f)(0.f); accg[nt] = (v4f)(0.f); }

#pragma unroll
    for (int kt = 0; kt < 2; ++kt) {
        const int frow = (mh * 16 + l15) * 64 + kt * 32 + q8;
        const int grow = (32 + mh * 16 + l15) * 64 + kt * 32 + q8;
        const v8s afh = *(const v8s*)&wfg_hi[frow];
        const v8s afl = *(const v8s*)&wfg_lo[frow];
        const v8s agh = *(const v8s*)&wfg_hi[grow];
        const v8s agl = *(const v8s*)&wfg_lo[grow];
#pragma unroll
        for (int nt = 0; nt < 4; ++nt) {
            const int col = colb + nt * 16 + l15;
            const v8s bh = *(const v8s*)&AT[col * 136 + kt * 32 + q8];
            const v8s bl = *(const v8s*)&AT[col * 136 + 64 + kt * 32 + q8];
            accf[nt] = __builtin_amdgcn_mfma_f32_16x16x32_bf16(afh, bh, accf[nt], 0, 0, 0);
            accf[nt] = __builtin_amdgcn_mfma_f32_16x16x32_bf16(afh, bl, accf[nt], 0, 0, 0);
            accf[nt] = __builtin_amdgcn_mfma_f32_16x16x32_bf16(afl, bh, accf[nt], 0, 0, 0);
            accg[nt] = __builtin_amdgcn_mfma_f32_16x16x32_bf16(agh, bh, accg[nt], 0, 0, 0);
            accg[nt] = __builtin_amdgcn_mfma_f32_16x16x32_bf16(agh, bl, accg[nt], 0, 0, 0);
            accg[nt] = __builtin_amdgcn_mfma_f32_16x16x32_bf16(agl, bh, accg[nt], 0, 0, 0);
        }
    }

    // gate + split (split reused for G store and GT staging)
    unsigned short gh[4][4], gl[4][4];
#pragma unroll
    for (int nt = 0; nt < 4; ++nt)
#pragma unroll
        for (int r = 0; r < 4; ++r) {
            const float f = accf[nt][r];
            const float g = accg[nt][r];
            const float th = 1.f - 2.f / (__expf(2.f * f) + 1.f);
            const float sg = 1.f / (1.f + __expf(-g));
            split2(th * sg, gh[nt][r], gl[nt][r]);
        }

    const int m0c = j0 - so_;
    if (m0c >= M0 && m0c < M1) {
#pragma unroll
        for (int nt = 0; nt < 4; ++nt)
#pragma unroll
            for (int r = 0; r < 4; ++r) {
                const int ch = mh * 16 + quad * 4 + r;
                const int m = (m0c - M0) + colb + nt * 16 + l15;
                gsl[(size_t)ch * gStride + m] =
                    ((unsigned)gl[nt][r] << 16) | (unsigned)gh[nt][r];
            }
    }

    if (doRes) {
        __syncthreads();   // all stage-A AT reads complete before GT overlays U
#pragma unroll
        for (int nt = 0; nt < 4; ++nt)
#pragma unroll
            for (int r = 0; r < 4; ++r) {
                const int ch = mh * 16 + quad * 4 + r;
                const int col = colb + nt * 16 + l15;
                GT[col * 72 + ch] = gh[nt][r];
                GT[col * 72 + 32 + ch] = gl[nt][r];
            }
        __syncthreads();

        v4f accr[4];
#pragma unroll
        for (int nt = 0; nt < 4; ++nt) accr[nt] = (v4f)(0.f);
#pragma unroll
        for (int kt = 0; kt < 2; ++kt) {
            const int row = (mh * 16 + l15) * 64 + kt * 32 + q8;
            const v8s arh = *(const v8s*)&wr_hi[row];
            const v8s arl = *(const v8s*)&wr_lo[row];
#pragma unroll
            for (int nt = 0; nt < 4; ++nt) {
                const int col = colb + nt * 16 + l15;
                const v8s b = *(const v8s*)&GT[col * 72 + kt * 32 + q8];
                accr[nt] = __builtin_amdgcn_mfma_f32_16x16x32_bf16(arh, b, accr[nt], 0, 0, 0);
                accr[nt] = __builtin_amdgcn_mfma_f32_16x16x32_bf16(arl, b, accr[nt], 0, 0, 0);
            }
        }

        // tap1 re-loaded from global (same packed value as the AT copy)
        const unsigned* tp = hin + (j0 + NpmP - hinBase);
#pragma unroll
        for (int nt = 0; nt < 4; ++nt)
#pragma unroll
            for (int r = 0; r < 4; ++r) {
                const int o = mh * 16 + quad * 4 + r;
                const int col = colb + nt * 16 + l15;
                const float tap1 = unpack2f(tp[(size_t)o * hinStride + col]);
                hout[(size_t)o * houtStride + (j0 - houtBase) + col] =
                    packsplit(accr[nt][r] + tap1);
            }
    }
}

// Fused skip -> relu -> end1 + bias -> relu -> y1 (split-bf16 MFMA).
// R12 structure + R18 chunked swizzle (aligns G reads with the layer
// kernels' producer XCDs; y1 writes with pe2's consumer blocks).
// LDS 34.8 KB: gt 64x104, st 64x136 aliased; e1t k-permuted.
__global__ __launch_bounds__(256, 3) void k_skip_end1_m(
    const unsigned* __restrict__ g,
    const unsigned short* __restrict__ swt_hi, const unsigned short* __restrict__ swt_lo,
    const unsigned short* __restrict__ e1t_hi, const unsigned short* __restrict__ e1t_lo,
    const float* __restrict__ b1, float* __restrict__ y1, const int gs)
{
    __shared__ unsigned short U[17408];          // 34816 B
    unsigned short* gt_hi = U;                   // 64 x 104
    unsigned short* gt_lo = U + 6656;
    unsigned short* st_hi = U;                   // 64 x 136 (aliases gt)
    unsigned short* st_lo = U + 8704;

    const int tid  = threadIdx.x;
    const int m0   = xcd_chunk(blockIdx.x, gridDim.x) * 64;
    const int lane = tid & 63;
    const int w    = tid >> 6;
    const int l15  = lane & 15;
    const int q8   = (lane >> 4) * 8;
    const int rbase = (lane >> 4) * 4;

    const int scol = tid & 63;
    const int ks0  = (tid >> 6) * 8;

    v4f acc1[4][4];
#pragma unroll
    for (int a = 0; a < 4; ++a)
#pragma unroll
        for (int b = 0; b < 4; ++b) acc1[a][b] = (v4f)(0.f);

    // ---- stage ph=0 (k 0..95) directly to LDS ----
#pragma unroll
    for (int kc = 0; kc < 96; kc += 32) {
        alignas(16) unsigned short h8[8], l8[8];
#pragma unroll
        for (int j = 0; j < 8; ++j) {
            const int k = kc + ks0 + j;
            const unsigned v = g[(size_t)(k >> 5) * 32 * gs + (size_t)(k & 31) * gs + m0 + scol];
            h8[j] = (unsigned short)(v & 0xffffu);
            l8[j] = (unsigned short)(v >> 16);
        }
        *(v8s*)&gt_hi[scol * 104 + kc + ks0] = *(v8s*)h8;
        *(v8s*)&gt_lo[scol * 104 + kc + ks0] = *(v8s*)l8;
    }
    __syncthreads();

    // ---- T14: issue ph=1 (k 96..191) loads into regs; consumed after m1-ph0 ----
    unsigned pre[24];
#pragma unroll
    for (int c = 0; c < 3; ++c)
#pragma unroll
        for (int j = 0; j < 8; ++j) {
            const int k = 96 + c * 32 + ks0 + j;
            pre[c * 8 + j] = g[(size_t)(k >> 5) * 32 * gs + (size_t)(k & 31) * gs + m0 + scol];
        }

    // ---- m1 over ph=0 ----
    for (int kc = 0; kc < 96; kc += 32) {
        v8s bh[4], bl[4];
#pragma unroll
        for (int t = 0; t < 4; ++t) {
            const int bo = (t * 16 + l15) * 104 + kc + q8;
            bh[t] = *(const v8s*)&gt_hi[bo];
            bl[t] = *(const v8s*)&gt_lo[bo];
        }
#pragma unroll
        for (int cp = 0; cp < 2; ++cp) {
            v8s ah[2], al[2];
#pragma unroll
            for (int u = 0; u < 2; ++u) {
                const int ct = cp * 2 + u;
                const int row = (w * 64 + ct * 16 + l15) * 192 + kc + q8;
                ah[u] = *(const v8s*)&swt_hi[row];
                al[u] = *(const v8s*)&swt_lo[row];
            }
#pragma unroll
            for (int u = 0; u < 2; ++u) {
                const int ct = cp * 2 + u;
#pragma unroll
                for (int nt = 0; nt < 4; ++nt) {
                    acc1[ct][nt] = __builtin_amdgcn_mfma_f32_16x16x32_bf16(ah[u], bh[nt], acc1[ct][nt], 0, 0, 0);
                    acc1[ct][nt] = __builtin_amdgcn_mfma_f32_16x16x32_bf16(ah[u], bl[nt], acc1[ct][nt], 0, 0, 0);
                    acc1[ct][nt] = __builtin_amdgcn_mfma_f32_16x16x32_bf16(al[u], bh[nt], acc1[ct][nt], 0, 0, 0);
                }
            }
        }
    }
    __syncthreads();   // gt(ph0) reads done before overwrite

    // ---- write prefetched ph=1 to LDS ----
#pragma unroll
    for (int c = 0; c < 3; ++c) {
        alignas(16) unsigned short h8[8], l8[8];
#pragma unroll
        for (int j = 0; j < 8; ++j) {
            const unsigned v = pre[c * 8 + j];
            h8[j] = (unsigned short)(v & 0xffffu);
            l8[j] = (unsigned short)(v >> 16);
        }
        *(v8s*)&gt_hi[scol * 104 + c * 32 + ks0] = *(v8s*)h8;
        *(v8s*)&gt_lo[scol * 104 + c * 32 + ks0] = *(v8s*)l8;
    }
    __syncthreads();

    // ---- m1 over ph=1 ----
    for (int kc = 0; kc < 96; kc += 32) {
        v8s bh[4], bl[4];
#pragma unroll
        for (int t = 0; t < 4; ++t) {
            const int bo = (t * 16 + l15) * 104 + kc + q8;
            bh[t] = *(const v8s*)&gt_hi[bo];
            bl[t] = *(const v8s*)&gt_lo[bo];
        }
#pragma unroll
        for (int cp = 0; cp < 2; ++cp) {
            v8s ah[2], al[2];
#pragma unroll
            for (int u = 0; u < 2; ++u) {
                const int ct = cp * 2 + u;
                const int row = (w * 64 + ct * 16 + l15) * 192 + 96 + kc + q8;
                ah[u] = *(const v8s*)&swt_hi[row];
                al[u] = *(const v8s*)&swt_lo[row];
            }
#pragma unroll
            for (int u = 0; u < 2; ++u) {
                const int ct = cp * 2 + u;
#pragma unroll
                for (int nt = 0; nt < 4; ++nt) {
                    acc1[ct][nt] = __builtin_amdgcn_mfma_f32_16x16x32_bf16(ah[u], bh[nt], acc1[ct][nt], 0, 0, 0);
                    acc1[ct][nt] = __builtin_amdgcn_mfma_f32_16x16x32_bf16(ah[u], bl[nt], acc1[ct][nt], 0, 0, 0);
                    acc1[ct][nt] = __builtin_amdgcn_mfma_f32_16x16x32_bf16(al[u], bh[nt], acc1[ct][nt], 0, 0, 0);
                }
            }
        }
    }
    __syncthreads();   // gt reads done before st overlays U

    v4f acc2[2][4];
#pragma unroll
    for (int a = 0; a < 2; ++a)
#pragma unroll
        for (int b = 0; b < 4; ++b) acc2[a][b] = (v4f)(0.f);

#pragma unroll
    for (int hh = 0; hh < 2; ++hh) {
        // write st half hh: waves' ct{2hh, 2hh+1} tiles -> st rows [0,128)
#pragma unroll
        for (int c2 = 0; c2 < 2; ++c2) {
            const int ct = hh * 2 + c2;
#pragma unroll
            for (int nt = 0; nt < 4; ++nt) {
                alignas(8) unsigned short sh[4], sl[4];
#pragma unroll
                for (int r = 0; r < 4; ++r) {
                    const float v = fmaxf(acc1[ct][nt][r], 0.f);
                    split2(v, sh[r], sl[r]);
                }
                const int ci  = w * 32 + c2 * 16 + rbase;
                const int col = nt * 16 + l15;
                *(uint2*)&st_hi[col * 136 + ci] = *(uint2*)sh;
                *(uint2*)&st_lo[col * 136 + ci] = *(uint2*)sl;
            }
        }
        __syncthreads();

        for (int kc = 0; kc < 128; kc += 32) {
            v8s ah2[2], al2[2], bh2[4], bl2[4];
#pragma unroll
            for (int t = 0; t < 2; ++t) {
                const int row = (w * 32 + t * 16 + l15) * 256 + hh * 128 + kc + q8;
                ah2[t] = *(const v8s*)&e1t_hi[row];
                al2[t] = *(const v8s*)&e1t_lo[row];
            }
#pragma unroll
            for (int t = 0; t < 4; ++t) {
                const int bo = (t * 16 + l15) * 136 + kc + q8;
                bh2[t] = *(const v8s*)&st_hi[bo];
                bl2[t] = *(const v8s*)&st_lo[bo];
            }
#pragma unroll
            for (int ct = 0; ct < 2; ++ct)
#pragma unroll
                for (int nt = 0; nt < 4; ++nt) {
                    acc2[ct][nt] = __builtin_amdgcn_mfma_f32_16x16x32_bf16(ah2[ct], bh2[nt], acc2[ct][nt], 0, 0, 0);
                    acc2[ct][nt] = __builtin_amdgcn_mfma_f32_16x16x32_bf16(ah2[ct], bl2[nt], acc2[ct][nt], 0, 0, 0);
                    acc2[ct][nt] = __builtin_amdgcn_mfma_f32_16x16x32_bf16(al2[ct], bh2[nt], acc2[ct][nt], 0, 0, 0);
                }
        }
        if (hh == 0) __syncthreads();   // m2 half-0 reads done before st half-1 overwrite
    }

#pragma unroll
    for (int ct = 0; ct < 2; ++ct) {
        const int cobase = w * 32 + ct * 16 + rbase;
        float bb[4];
#pragma unroll
        for (int r = 0; r < 4; ++r) bb[r] = b1[cobase + r];
#pragma unroll
        for (int nt = 0; nt < 4; ++nt) {
            const int col = m0 + nt * 16 + l15;
#pragma unroll
            for (int r = 0; r < 4; ++r)
                y1[(size_t)(cobase + r) * gs + col] = fmaxf(acc2[ct][nt][r] + bb[r], 0.f);
        }
    }
}

// Fused maxpool3s2 + end2 (128->32) via split-bf16 MFMA. 64 pooled cols/block.
// R18: chunked swizzle (y1c producer alignment + 33% pool-window overlap
// between t1-adjacent blocks becomes L2-local).
__global__ __launch_bounds__(256) void k_pe2_m(
    const float* __restrict__ y1c,
    const unsigned short* __restrict__ e2s_hi, const unsigned short* __restrict__ e2s_lo,
    const float* __restrict__ b2, float* __restrict__ e2c,
    const int gs, const int p1s)
{
    __shared__ unsigned short SP[2 * 64 * 136];
    unsigned short* sp_hi = SP;
    unsigned short* sp_lo = SP + 64 * 136;

    const int tid = threadIdx.x;
    const int m0 = xcd_chunk(blockIdx.x, gridDim.x) * 64;
    const int tp = m0 >> 8;
    const int nb = m0 & 255;

    {
        const int col = tid & 63;
        const int cig = tid >> 6;
        const int base = 2 * tp * 256 + nb + col;
#pragma unroll
        for (int u8 = 0; u8 < 4; ++u8) {
            alignas(16) unsigned short h8[8], l8[8];
#pragma unroll
            for (int u = 0; u < 8; ++u) {
                const int ci = cig * 32 + u8 * 8 + u;
                const float* yp = y1c + (size_t)ci * gs + base;
                const float v = fmaxf(fmaxf(yp[0], yp[256]), yp[512]);
                split2(v, h8[u], l8[u]);
            }
            *(uint4*)&sp_hi[col * 136 + cig * 32 + u8 * 8] = *(uint4*)h8;
            *(uint4*)&sp_lo[col * 136 + cig * 32 + u8 * 8] = *(uint4*)l8;
        }
    }
    __syncthreads();

    const int lane = tid & 63;
    const int w    = tid >> 6;
    const int mh   = w & 1;
    const int colh = w >> 1;
    const int l15  = lane & 15;
    const int quad = lane >> 4;
    const int q8   = quad * 8;

    v4f acc[2];
    acc[0] = (v4f)(0.f); acc[1] = (v4f)(0.f);

#pragma unroll
    for (int kc = 0; kc < 128; kc += 32) {
        const int row = (mh * 16 + l15) * 128 + kc + q8;
        const v8s ah = *(const v8s*)&e2s_hi[row];
        const v8s al = *(const v8s*)&e2s_lo[row];
#pragma unroll
        for (int nt = 0; nt < 2; ++nt) {
            const int col = colh * 32 + nt * 16 + l15;
            const v8s bh = *(const v8s*)&sp_hi[col * 136 + kc + q8];
            const v8s bl = *(const v8s*)&sp_lo[col * 136 + kc + q8];
            acc[nt] = __builtin_amdgcn_mfma_f32_16x16x32_bf16(ah, bh, acc[nt], 0, 0, 0);
            acc[nt] = __builtin_amdgcn_mfma_f32_16x16x32_bf16(ah, bl, acc[nt], 0, 0, 0);
            acc[nt] = __builtin_amdgcn_mfma_f32_16x16x32_bf16(al, bh, acc[nt], 0, 0, 0);
        }
    }

#pragma unroll
    for (int nt = 0; nt < 2; ++nt)
#pragma unroll
        for (int r = 0; r < 4; ++r) {
            const int co = mh * 16 + quad * 4 + r;
            const int col = m0 + colh * 32 + nt * 16 + l15;
            e2c[(size_t)co * p1s + col] = fmaxf(acc[nt][r] + b2[co], 0.f);
        }
}

// pool2 -> p2 stored packed-split u32 (consumed by k_fc1_m)
__global__ __launch_bounds__(256) void k_pool2p(const float* __restrict__ e2c,
                                                unsigned* __restrict__ p2,
                                                const int p1s, const int A) {
    const int n = threadIdx.x, tl2 = blockIdx.x, co = blockIdx.y;
    const int base = co * p1s + tl2 * 512 + n;
    float v = fmaxf(fmaxf(e2c[base], e2c[base + 256]), e2c[base + 512]);
    p2[co * 81152 + (A + tl2) * 256 + n] = packsplit(v);
}

// FC1 via split-bf16 MFMA: C[1024 x 256] += W1[1024 x 10144] @ P2[10144 x 256].
__global__ __launch_bounds__(256) void k_fc1_m(
    const unsigned short* __restrict__ w1s_hi, const unsigned short* __restrict__ w1s_lo,
    const unsigned* __restrict__ p2u, float* __restrict__ out)
{
    __shared__ unsigned short SB[2 * 64 * 40];
    unsigned short* sb_hi = SB;
    unsigned short* sb_lo = SB + 64 * 40;

    const int tid = threadIdx.x;
    const int o0 = blockIdx.x * 64;
    const int b0 = blockIdx.y * 64;
    const int k0 = blockIdx.z * 1280;
    const int kend = (k0 + 1280 < 10144) ? (k0 + 1280) : 10144;
    const int nch = (kend - k0) >> 5;

    const int lane = tid & 63;
    const int w    = tid >> 6;
    const int l15  = lane & 15;
    const int quad = lane >> 4;
    const int q8   = quad * 8;
    const int scol = tid & 63;
    const int kq   = tid >> 6;

    v4f acc[4];
#pragma unroll
    for (int nt = 0; nt < 4; ++nt) acc[nt] = (v4f)(0.f);

    for (int c = 0; c < nch; ++c) {
        const int kc = k0 + c * 32;
        alignas(16) unsigned short h8[8], l8[8];
#pragma unroll
        for (int j = 0; j < 8; ++j) {
            const unsigned v = p2u[(size_t)(kc + kq * 8 + j) * 256 + b0 + scol];
            h8[j] = (unsigned short)(v & 0xffffu);
            l8[j] = (unsigned short)(v >> 16);
        }
        __syncthreads();
        *(v8s*)&sb_hi[scol * 40 + kq * 8] = *(v8s*)h8;
        *(v8s*)&sb_lo[scol * 40 + kq * 8] = *(v8s*)l8;
        __syncthreads();

        const int arow = (o0 + w * 16 + l15) * 10144 + kc + q8;
        const v8s ah = *(const v8s*)&w1s_hi[arow];
        const v8s al = *(const v8s*)&w1s_lo[arow];
#pragma unroll
        for (int nt = 0; nt < 4; ++nt) {
            const v8s bh = *(const v8s*)&sb_hi[(nt * 16 + l15) * 40 + q8];
            const v8s bl = *(const v8s*)&sb_lo[(nt * 16 + l15) * 40 + q8];
            acc[nt] = __builtin_amdgcn_mfma_f32_16x16x32_bf16(ah, bh, acc[nt], 0, 0, 0);
            acc[nt] = __builtin_amdgcn_mfma_f32_16x16x32_bf16(ah, bl, acc[nt], 0, 0, 0);
            acc[nt] = __builtin_amdgcn_mfma_f32_16x16x32_bf16(al, bh, acc[nt], 0, 0, 0);
        }
    }

#pragma unroll
    for (int nt = 0; nt < 4; ++nt)
#pragma unroll
        for (int r = 0; r < 4; ++r)
            atomicAdd(&out[(size_t)(o0 + w * 16 + quad * 4 + r) * 256 + b0 + nt * 16 + l15],
                      acc[nt][r]);
}

// Tiled f32 GEMM (FC2 only).
__global__ __launch_bounds__(256) void k_gemm64(const float* __restrict__ A,
                                                const float* __restrict__ B,
                                                float* __restrict__ C,
                                                const int Ktot, const int KC) {
    __shared__ float sA[32 * 65];
    __shared__ float sB[32 * 68];

    const int tid = threadIdx.x;
    const int o0 = blockIdx.x * 64;
    const int b0 = blockIdx.y * 64;
    const int k0 = blockIdx.z * KC;

    float acc[4][4];
#pragma unroll
    for (int i = 0; i < 4; ++i)
#pragma unroll
        for (int jq = 0; jq < 4; ++jq) acc[i][jq] = 0.f;

    const int ao  = tid >> 2;
    const int ak8 = (tid & 3) * 8;
    const int bk  = tid >> 3;
    const int bb8 = (tid & 7) * 8;
    const int to4 = (tid & 15) * 4;
    const int tb4 = (tid >> 4) * 4;

    for (int kc = 0; kc < KC; kc += 32) {
        const int kcLen = (KC - kc < 32) ? (KC - kc) : 32;
        const float* ap = A + (size_t)(o0 + ao) * Ktot + k0 + kc + ak8;
#pragma unroll
        for (int i = 0; i < 8; ++i) {
            float v = (ak8 + i < kcLen) ? ap[i] : 0.f;
            sA[(ak8 + i) * 65 + ao] = v;
        }
        if (bk < kcLen) {
            const float* bp = B + (size_t)(k0 + kc + bk) * 256 + b0 + bb8;
            const float4 v0 = *(const float4*)bp;
            const float4 v1 = *(const float4*)(bp + 4);
            *(float4*)&sB[bk * 68 + bb8] = v0;
            *(float4*)&sB[bk * 68 + bb8 + 4] = v1;
        } else {
            float4 z; z.x = z.y = z.z = z.w = 0.f;
            *(float4*)&sB[bk * 68 + bb8] = z;
            *(float4*)&sB[bk * 68 + bb8 + 4] = z;
        }
        __syncthreads();

#pragma unroll 8
        for (int kk = 0; kk < 32; ++kk) {
            const float4 av = *(const float4*)&sA[kk * 65 + to4];
            const float4 bv = *(const float4*)&sB[kk * 68 + tb4];
            const float aa[4] = {av.x, av.y, av.z, av.w};
#pragma unroll
            for (int i = 0; i < 4; ++i) {
                acc[i][0] = fmaf(aa[i], bv.x, acc[i][0]);
                acc[i][1] = fmaf(aa[i], bv.y, acc[i][1]);
                acc[i][2] = fmaf(aa[i], bv.z, acc[i][2]);
                acc[i][3] = fmaf(aa[i], bv.w, acc[i][3]);
            }
        }
        __syncthreads();
    }

#pragma unroll
    for (int i = 0; i < 4; ++i)
#pragma unroll
        for (int jq = 0; jq < 4; ++jq)
            atomicAdd(&C[(size_t)(o0 + to4 + i) * 256 + b0 + tb4 + jq], acc[i][jq]);
}

__global__ __launch_bounds__(256) void k_actbias(const float* __restrict__ raw,
                                                 const float* __restrict__ bias,
                                                 float* __restrict__ out) {
    const int k = blockIdx.x, b = threadIdx.x;
    out[k * 256 + b] = fmaxf(raw[k * 256 + b] + bias[k], 0.f);
}

__global__ __launch_bounds__(256) void k_fc3(const float* __restrict__ fc2raw,
                                             const float* __restrict__ fb2,
                                             const float* __restrict__ w3,
                                             const float* __restrict__ b3,
                                             float* __restrict__ out) {
    const int b = threadIdx.x;
    float l0 = b3[0], l1 = b3[1];
    for (int k = 0; k < 256; ++k) {
        const float a = fmaxf(fc2raw[k * 256 + b] + fb2[k], 0.f);
        l0 = fmaf(w3[k], a, l0);
        l1 = fmaf(w3[256 + k], a, l1);
    }
    out[2 * b] = l0;
    out[2 * b + 1] = l1;
    const float mx = fmaxf(l0, l1);
    const float e0 = expf(l0 - mx), e1 = expf(l1 - mx);
    const float inv = 1.f / (e0 + e1);
    out[512 + 2 * b] = e0 * inv;
    out[513 + 2 * b] = e1 * inv;
    out[1024 + b] = (l1 > l0) ? 1.f : 0.f;
}

extern "C" void kernel_launch(void* const* d_in, const int* in_sizes, int n_in,
                              void* d_out, int out_size, void* d_ws, size_t ws_size,
                              hipStream_t stream) {
    const float* x        = (const float*)d_in[0];
    const float* start_w  = (const float*)d_in[1];
    const float* filter_w = (const float*)d_in[2];
    const float* gate_w   = (const float*)d_in[3];
    const float* res_w    = (const float*)d_in[4];
    const float* skip_w   = (const float*)d_in[5];
    const float* e1w      = (const float*)d_in[6];
    const float* e1b      = (const float*)d_in[7];
    const float* e2w      = (const float*)d_in[8];
    const float* e2b      = (const float*)d_in[9];
    const float* w1       = (const float*)d_in[10];
    const float* fb1      = (const float*)d_in[11];
    const float* w2       = (const float*)d_in[12];
    const float* fb2      = (const float*)d_in[13];
    const float* w3       = (const float*)d_in[14];
    const float* b3       = (const float*)d_in[15];

    float* ws = (float*)d_ws;

    const long o_h0   = 0;            // 10,485,760
    const long o_p2   = 10485760;     // 2,596,864
    const long o_fc1  = 13082624;     // 262,144
    const long o_fc2  = 13344768;     // 65,536
    const long o_wbf  = 13410304;     // 81,920
    const long o_wfg  = 13492224;     // 24,576
    const long o_wr   = 13516800;     // 12,288
    const long o_e2s  = 13529088;     // 4,096
    const long o_act1 = 13533184;     // 262,144
    const long o_w1s  = 13795328;     // 10,387,456 (w1 hi+lo u16)
    const long o_G    = 24182784;

    long budget = (long)((double)ws_size * 0.94 / 4.0);
    int dB = 1;
    for (int d = 317; d >= 1; --d) {
        long mch = 256L * (4L * d + 3), hs = mch + 4096;
        long tot = o_G + 192L * mch + lmax_(128L * mch, 64L * hs);
        if (tot <= budget) { dB = d; break; }
    }
    int K = (317 + dB - 1) / dB;
    dB = (317 + K - 1) / K;
    const long MchA  = 256L * (4L * dB + 3);
    const long HSPAN = MchA + 4096;
    const long o_X   = o_G + 192L * MchA;
    const long P1S   = 256L * (2L * dB + 1);

    unsigned* h0 = (unsigned*)(ws + o_h0);
    unsigned* p2 = (unsigned*)(ws + o_p2);
    float* fc1r = ws + o_fc1;
    float* fc2r = ws + o_fc2;
    unsigned short* swt_hi = (unsigned short*)(ws + o_wbf);
    unsigned short* swt_lo = swt_hi + 49152;
    unsigned short* e1t_hi = swt_lo + 49152;
    unsigned short* e1t_lo = e1t_hi + 32768;
    unsigned short* wfg_hi = (unsigned short*)(ws + o_wfg);
    unsigned short* wfg_lo = wfg_hi + 24576;
    unsigned short* wr_hi  = (unsigned short*)(ws + o_wr);
    unsigned short* wr_lo  = wr_hi + 12288;
    unsigned short* e2s_hi = (unsigned short*)(ws + o_e2s);
    unsigned short* e2s_lo = e2s_hi + 4096;
    unsigned short* w1s_hi = (unsigned short*)(ws + o_w1s);
    unsigned short* w1s_lo = w1s_hi + 10387456;
    float* act1 = ws + o_act1;
    unsigned* G  = (unsigned*)(ws + o_G);
    unsigned* hA = (unsigned*)(ws + o_X);
    unsigned* hB = (unsigned*)(ws + o_X) + 32L * HSPAN;
    float* y1c  = ws + o_X;                 // aliases hA/hB (dead by then)
    float* e2c  = ws + o_G;                 // aliases G (dead after skip_end1)

    k_zero<<<1280, 256, 0, stream>>>(fc1r, 327680);
    k_start<<<1280, 256, 0, stream>>>(x, start_w, h0);
    k_prep<<<192, 256, 0, stream>>>(skip_w, e1w, filter_w, gate_w, res_w, e2w,
                                    swt_hi, swt_lo, e1t_hi, e1t_lo,
                                    wfg_hi, wfg_lo, wr_hi, wr_lo,
                                    e2s_hi, e2s_lo);
    k_prep_w1<<<40576, 256, 0, stream>>>(w1, w1s_hi, w1s_lo);

    const int Mc[6]   = {327424, 327168, 326656, 326400, 326144, 325632};
    const int NpmP[6] = {256, 256, 512, 256, 256, 512};
    const int pN[6]   = {0, 256, 512, 0, 256, 512};
    const int so_[6]  = {1792, 1536, 1024, 768, 512, 0};
    const int JloO[6] = {-1536, -1280, -768, -768, -512, 0};

    for (int c = 0; c < K; ++c) {
        const int A = c * dB;
        int B = A + dB; if (B > 317) B = 317;
        const int dBc = B - A;
        const int M0 = 1024 * A;
        int tmax = 4 * B + 3; if (tmax > 1272) tmax = 1272;
        const int Tt = tmax - 4 * A;
        const int M1 = M0 + 256 * Tt;

        int Jlo[6], Jhi[6];
        for (int q = 0; q < 6; ++q) {
            int lo = M0 + JloO[q]; if (lo < 0) lo = 0;
            int hi = M1 + so_[q];  if (hi > Mc[q]) hi = Mc[q];
            Jlo[q] = lo; Jhi[q] = hi;
        }

        for (int q = 0; q < 6; ++q) {
            const unsigned* hin = (q == 0) ? h0 : ((q & 1) ? hA : hB);
            const int hinBase   = (q == 0) ? 0 : Jlo[q - 1];
            const int hinStride = (q == 0) ? MCAP : (int)HSPAN;
            unsigned* hout = (q & 1) ? hB : hA;
            const int Jcnt = Jhi[q] - Jlo[q];     // % 128 == 0
            k_layer_m<<<Jcnt / 128, 256, 0, stream>>>(
                hin, hinBase, hinStride, hout, Jlo[q], (int)HSPAN,
                G + (long)q * 32 * MchA, (int)MchA,
                wfg_hi + q * 4096, wfg_lo + q * 4096,
                wr_hi + q * 2048, wr_lo + q * 2048,
                Jlo[q], NpmP[q], pN[q], so_[q], M0, M1, (q < 5) ? 1 : 0);
        }

        const int Mchc = 256 * Tt;
        k_skip_end1_m<<<Mchc / 64, 256, 0, stream>>>(
            G, swt_hi, swt_lo, e1t_hi, e1t_lo, e1b, y1c, (int)MchA);
        const int T1c = 2 * dBc + 1;
        k_pe2_m<<<T1c * 4, 256, 0, stream>>>(
            y1c, e2s_hi, e2s_lo, e2b, e2c, (int)MchA, (int)P1S);
        k_pool2p<<<dim3(dBc, 32), 256, 0, stream>>>(e2c, p2, (int)P1S, A);
    }

    k_fc1_m<<<dim3(16, 4, 8), 256, 0, stream>>>(w1s_hi, w1s_lo, p2, fc1r);
    k_actbias<<<1024, 256, 0, stream>>>(fc1r, fb1, act1);
    k_gemm64<<<dim3(4, 4, 4), 256, 0, stream>>>(w2, act1, fc2r, 1024, 256);
    k_fc3<<<1, 256, 0, stream>>>(fc2r, fb2, w3, b3, (float*)d_out);
}

// Round 10
// 817.056 us; speedup vs baseline: 1.2794x; 1.0023x over previous
//
#include <hip/hip_runtime.h>
#include <math.h>

// ---------------------------------------------------------------------------
// WaveNet forward. Layers, skip/end1, end2(+fused pool1), FC1 all via
// split-bf16 MFMA (3-term hi*hi+hi*lo+lo*hi, rel err ~2^-16). Flat layout
// (channel, time, batch) => buf[c][t*256+n]; dilate() is a reinterpretation.
// R19: mixed swizzle config. R18 showed: chunked map on layers+pe2 gained
// ~50us (real neighbor sharing: tap overlap / pool-window overlap), but
// chunked skip_end1 LOST 12us/dispatch with FETCH unchanged — skip_end1 has
// ZERO inter-block G reuse (each block reads its own 64 cols once), so
// chunking bought no L2 hits and concentrated each XCD's reads on a narrow
// band -> worse HBM channel interleave (hbm_gbps 1090->970 on same bytes).
// Fix: skip_end1 back to round-robin; layers+pe2 stay chunked.
// ---------------------------------------------------------------------------

#define MCAP 327680

typedef short v8s __attribute__((ext_vector_type(8)));
typedef float v4f __attribute__((ext_vector_type(4)));

static inline long lmax_(long a, long b) { return a > b ? a : b; }

__device__ inline unsigned short rnbf(float x) {
    unsigned u = __float_as_uint(x);
    return (unsigned short)((u + 0x7FFFu + ((u >> 16) & 1u)) >> 16);
}
__device__ inline void split2(float v, unsigned short& h, unsigned short& l) {
    h = rnbf(v);
    const float hf = __uint_as_float(((unsigned)h) << 16);
    l = rnbf(v - hf);
}
__device__ inline unsigned packsplit(float v) {
    unsigned short h, l;
    split2(v, h, l);
    return ((unsigned)l << 16) | (unsigned)h;
}
__device__ inline float unpack2f(unsigned v) {
    return __uint_as_float(v << 16) + __uint_as_float(v & 0xffff0000u);
}

// bijective XCD-chunked swizzle (m204): round-robin id -> chunked id
__device__ inline int xcd_chunk(int bid, int nwg) {
    const int q = nwg >> 3, r = nwg & 7;
    const int xcd = bid & 7, off = bid >> 3;
    return (xcd < r ? xcd * (q + 1) : r * (q + 1) + (xcd - r) * q) + off;
}

__global__ __launch_bounds__(256) void k_zero(float* __restrict__ p, int n) {
    int i = blockIdx.x * 256 + threadIdx.x;
    if (i < n) p[i] = 0.f;
}

// h0[o][t*256+n] = packsplit(sum_i start_w[o,i] * x[n,i,t])
__global__ __launch_bounds__(256) void k_start(const float* __restrict__ x,
                                               const float* __restrict__ sw,
                                               unsigned* __restrict__ h0) {
    int j = blockIdx.x * 256 + threadIdx.x;
    int t = j >> 8, n = j & 255;
    float xv[5];
#pragma unroll
    for (int i = 0; i < 5; ++i) xv[i] = x[n * 6400 + i * 1280 + t];
#pragma unroll
    for (int o = 0; o < 32; ++o) {
        float acc = 0.f;
#pragma unroll
        for (int i = 0; i < 5; ++i) acc = fmaf(sw[o * 5 + i], xv[i], acc);
        h0[o * MCAP + j] = packsplit(acc);
    }
}

// Prepack small weights (split bf16).
// e1t k-dim is PERMUTED for k_skip_end1_m's two-pass st consumption:
//   k_new = h*128 + w*32 + c*16 + r  <->  ch = w*64 + (2h+c)*16 + r
__global__ __launch_bounds__(256) void k_prep(const float* __restrict__ skw,
                                              const float* __restrict__ e1w,
                                              const float* __restrict__ fw,
                                              const float* __restrict__ gw,
                                              const float* __restrict__ rw,
                                              const float* __restrict__ e2w,
                                              unsigned short* __restrict__ swt_hi,
                                              unsigned short* __restrict__ swt_lo,
                                              unsigned short* __restrict__ e1t_hi,
                                              unsigned short* __restrict__ e1t_lo,
                                              unsigned short* __restrict__ wfg_hi,
                                              unsigned short* __restrict__ wfg_lo,
                                              unsigned short* __restrict__ wr_hi,
                                              unsigned short* __restrict__ wr_lo,
                                              unsigned short* __restrict__ e2s_hi,
                                              unsigned short* __restrict__ e2s_lo) {
    int idx = blockIdx.x * 256 + threadIdx.x;
    if (idx < 49152) {
        int ch = idx / 192, k = idx - ch * 192;
        int l = k >> 5, i = k & 31;
        unsigned short h, lo;
        split2(skw[l * 8192 + ch * 32 + i], h, lo);
        swt_hi[idx] = h; swt_lo[idx] = lo;
    }
    if (idx < 32768) {
        int co = idx >> 8, kn = idx & 255;
        int hf = kn >> 7, wv = (kn >> 5) & 3, c = (kn >> 4) & 1, r = kn & 15;
        int ch = wv * 64 + (hf * 2 + c) * 16 + r;
        unsigned short h, lo;
        split2(e1w[co * 256 + ch], h, lo);
        e1t_hi[idx] = h; e1t_lo[idx] = lo;
    }
    if (idx < 24576) {
        int l = idx >> 12, r = idx & 4095;
        int row = r >> 6, k = r & 63;
        int o = row & 31, i = k & 31, tap = k >> 5;
        const float* src = (row < 32) ? fw : gw;
        unsigned short h, lo;
        split2(src[l * 2048 + o * 64 + i * 2 + tap], h, lo);
        wfg_hi[idx] = h; wfg_lo[idx] = lo;
    }
    if (idx < 12288) {
        int l = idx >> 11, r = idx & 2047;
        int o = r >> 6, k = r & 63, i = k & 31;
        unsigned short h, lo;
        split2(rw[l * 1024 + o * 32 + i], h, lo);
        wr_hi[idx] = h; wr_lo[idx] = lo;
    }
    if (idx < 4096) {
        unsigned short h, lo;
        split2(e2w[idx], h, lo);
        e2s_hi[idx] = h; e2s_lo[idx] = lo;
    }
}

// Split fc1 weights (1024 x 10144, row-major, k-contiguous).
__global__ __launch_bounds__(256) void k_prep_w1(const float* __restrict__ w1,
                                                 unsigned short* __restrict__ hi,
                                                 unsigned short* __restrict__ lo) {
    int idx = blockIdx.x * 256 + threadIdx.x;
    if (idx < 10387456) {
        unsigned short h, l;
        split2(w1[idx], h, l);
        hi[idx] = h; lo[idx] = l;
    }
}

// One dilated gated layer via split-bf16 MFMA. 128-col tile, Jcnt % 128 == 0.
// hin/hout/gsl hold packed-split u32 activations. LDS: single 128x136 u16
// buffer; acts (AT) during stage A, gated k-ext (GT) after a barrier.
// XCD-chunked bijective blockIdx swizzle (T1/m204) for hin L2 locality.
__global__ __launch_bounds__(256) void k_layer_m(
    const unsigned* __restrict__ hin, const int hinBase, const int hinStride,
    unsigned* __restrict__ hout, const int houtBase, const int houtStride,
    unsigned* __restrict__ gsl, const int gStride,
    const unsigned short* __restrict__ wfg_hi, const unsigned short* __restrict__ wfg_lo,
    const unsigned short* __restrict__ wr_hi, const unsigned short* __restrict__ wr_lo,
    const int Jlo, const int NpmP, const int padN,
    const int so_, const int M0, const int M1, const int doRes)
{
    __shared__ unsigned short U[128 * 136];
    unsigned short* AT = U;          // [col][k]: 0..63 hi, 64..127 lo (stage A)
    unsigned short* GT = U;          // [col][72]: 0..31 ghi, 32..63 glo (stage B)

    const int tid = threadIdx.x;
    const int wg = xcd_chunk(blockIdx.x, gridDim.x);
    const int j0 = Jlo + wg * 128;

    {
        const int col = tid & 127;
        const int kg = tid >> 7;
        unsigned short* bh = &AT[col * 136 + kg * 32];
        unsigned short* bl = &AT[col * 136 + 64 + kg * 32];
        if (kg == 0 && j0 < padN) {
            uint4 z; z.x = z.y = z.z = z.w = 0u;
#pragma unroll
            for (int ch = 0; ch < 32; ch += 8) {
                *(uint4*)&bh[ch] = z;
                *(uint4*)&bl[ch] = z;
            }
        } else {
            const int off = (kg == 0) ? (j0 - padN) : (j0 + NpmP);
            const unsigned* p = hin + (off - hinBase) + col;
#pragma unroll
            for (int ch = 0; ch < 32; ch += 8) {
                alignas(16) unsigned short h8[8], l8[8];
#pragma unroll
                for (int u = 0; u < 8; ++u) {
                    const unsigned v = p[(size_t)(ch + u) * hinStride];
                    h8[u] = (unsigned short)(v & 0xffffu);
                    l8[u] = (unsigned short)(v >> 16);
                }
                *(uint4*)&bh[ch] = *(uint4*)h8;
                *(uint4*)&bl[ch] = *(uint4*)l8;
            }
        }
    }
    __syncthreads();

    const int lane = tid & 63;
    const int w    = tid >> 6;
    const int ch2  = w >> 1;
    const int mh   = w & 1;
    const int l15  = lane & 15;
    const int quad = lane >> 4;
    const int q8   = quad * 8;
    const int colb = ch2 * 64;

    v4f accf[4], accg[4];
#pragma unroll
    for (int nt = 0; nt < 4; ++nt) { accf[nt] = (v4f)(0.f); accg[nt] = (v4f)(0.f); }

#pragma unroll
    for (int kt = 0; kt < 2; ++kt) {
        const int frow = (mh * 16 + l15) * 64 + kt * 32 + q8;
        const int grow = (32 + mh * 16 + l15) * 64 + kt * 32 + q8;
        const v8s afh = *(const v8s*)&wfg_hi[frow];
        const v8s afl = *(const v8s*)&wfg_lo[frow];
        const v8s agh = *(const v8s*)&wfg_hi[grow];
        const v8s agl = *(const v8s*)&wfg_lo[grow];
#pragma unroll
        for (int nt = 0; nt < 4; ++nt) {
            const int col = colb + nt * 16 + l15;
            const v8s bh = *(const v8s*)&AT[col * 136 + kt * 32 + q8];
            const v8s bl = *(const v8s*)&AT[col * 136 + 64 + kt * 32 + q8];
            accf[nt] = __builtin_amdgcn_mfma_f32_16x16x32_bf16(afh, bh, accf[nt], 0, 0, 0);
            accf[nt] = __builtin_amdgcn_mfma_f32_16x16x32_bf16(afh, bl, accf[nt], 0, 0, 0);
            accf[nt] = __builtin_amdgcn_mfma_f32_16x16x32_bf16(afl, bh, accf[nt], 0, 0, 0);
            accg[nt] = __builtin_amdgcn_mfma_f32_16x16x32_bf16(agh, bh, accg[nt], 0, 0, 0);
            accg[nt] = __builtin_amdgcn_mfma_f32_16x16x32_bf16(agh, bl, accg[nt], 0, 0, 0);
            accg[nt] = __builtin_amdgcn_mfma_f32_16x16x32_bf16(agl, bh, accg[nt], 0, 0, 0);
        }
    }

    // gate + split (split reused for G store and GT staging)
    unsigned short gh[4][4], gl[4][4];
#pragma unroll
    for (int nt = 0; nt < 4; ++nt)
#pragma unroll
        for (int r = 0; r < 4; ++r) {
            const float f = accf[nt][r];
            const float g = accg[nt][r];
            const float th = 1.f - 2.f / (__expf(2.f * f) + 1.f);
            const float sg = 1.f / (1.f + __expf(-g));
            split2(th * sg, gh[nt][r], gl[nt][r]);
        }

    const int m0c = j0 - so_;
    if (m0c >= M0 && m0c < M1) {
#pragma unroll
        for (int nt = 0; nt < 4; ++nt)
#pragma unroll
            for (int r = 0; r < 4; ++r) {
                const int ch = mh * 16 + quad * 4 + r;
                const int m = (m0c - M0) + colb + nt * 16 + l15;
                gsl[(size_t)ch * gStride + m] =
                    ((unsigned)gl[nt][r] << 16) | (unsigned)gh[nt][r];
            }
    }

    if (doRes) {
        __syncthreads();   // all stage-A AT reads complete before GT overlays U
#pragma unroll
        for (int nt = 0; nt < 4; ++nt)
#pragma unroll
            for (int r = 0; r < 4; ++r) {
                const int ch = mh * 16 + quad * 4 + r;
                const int col = colb + nt * 16 + l15;
                GT[col * 72 + ch] = gh[nt][r];
                GT[col * 72 + 32 + ch] = gl[nt][r];
            }
        __syncthreads();

        v4f accr[4];
#pragma unroll
        for (int nt = 0; nt < 4; ++nt) accr[nt] = (v4f)(0.f);
#pragma unroll
        for (int kt = 0; kt < 2; ++kt) {
            const int row = (mh * 16 + l15) * 64 + kt * 32 + q8;
            const v8s arh = *(const v8s*)&wr_hi[row];
            const v8s arl = *(const v8s*)&wr_lo[row];
#pragma unroll
            for (int nt = 0; nt < 4; ++nt) {
                const int col = colb + nt * 16 + l15;
                const v8s b = *(const v8s*)&GT[col * 72 + kt * 32 + q8];
                accr[nt] = __builtin_amdgcn_mfma_f32_16x16x32_bf16(arh, b, accr[nt], 0, 0, 0);
                accr[nt] = __builtin_amdgcn_mfma_f32_16x16x32_bf16(arl, b, accr[nt], 0, 0, 0);
            }
        }

        // tap1 re-loaded from global (same packed value as the AT copy)
        const unsigned* tp = hin + (j0 + NpmP - hinBase);
#pragma unroll
        for (int nt = 0; nt < 4; ++nt)
#pragma unroll
            for (int r = 0; r < 4; ++r) {
                const int o = mh * 16 + quad * 4 + r;
                const int col = colb + nt * 16 + l15;
                const float tap1 = unpack2f(tp[(size_t)o * hinStride + col]);
                hout[(size_t)o * houtStride + (j0 - houtBase) + col] =
                    packsplit(accr[nt][r] + tap1);
            }
    }
}

// Fused skip -> relu -> end1 + bias -> relu -> y1 (split-bf16 MFMA).
// R19: back to ROUND-ROBIN blocks (R12 exact). skip_end1 has no inter-block
// G reuse; chunking concentrated HBM reads (hbm_gbps 1090->970, +12us).
// LDS 34.8 KB: gt 64x104, st 64x136 aliased; e1t k-permuted.
__global__ __launch_bounds__(256, 3) void k_skip_end1_m(
    const unsigned* __restrict__ g,
    const unsigned short* __restrict__ swt_hi, const unsigned short* __restrict__ swt_lo,
    const unsigned short* __restrict__ e1t_hi, const unsigned short* __restrict__ e1t_lo,
    const float* __restrict__ b1, float* __restrict__ y1, const int gs)
{
    __shared__ unsigned short U[17408];          // 34816 B
    unsigned short* gt_hi = U;                   // 64 x 104
    unsigned short* gt_lo = U + 6656;
    unsigned short* st_hi = U;                   // 64 x 136 (aliases gt)
    unsigned short* st_lo = U + 8704;

    const int tid  = threadIdx.x;
    const int m0   = blockIdx.x * 64;
    const int lane = tid & 63;
    const int w    = tid >> 6;
    const int l15  = lane & 15;
    const int q8   = (lane >> 4) * 8;
    const int rbase = (lane >> 4) * 4;

    const int scol = tid & 63;
    const int ks0  = (tid >> 6) * 8;

    v4f acc1[4][4];
#pragma unroll
    for (int a = 0; a < 4; ++a)
#pragma unroll
        for (int b = 0; b < 4; ++b) acc1[a][b] = (v4f)(0.f);

    // ---- stage ph=0 (k 0..95) directly to LDS ----
#pragma unroll
    for (int kc = 0; kc < 96; kc += 32) {
        alignas(16) unsigned short h8[8], l8[8];
#pragma unroll
        for (int j = 0; j < 8; ++j) {
            const int k = kc + ks0 + j;
            const unsigned v = g[(size_t)(k >> 5) * 32 * gs + (size_t)(k & 31) * gs + m0 + scol];
            h8[j] = (unsigned short)(v & 0xffffu);
            l8[j] = (unsigned short)(v >> 16);
        }
        *(v8s*)&gt_hi[scol * 104 + kc + ks0] = *(v8s*)h8;
        *(v8s*)&gt_lo[scol * 104 + kc + ks0] = *(v8s*)l8;
    }
    __syncthreads();

    // ---- T14: issue ph=1 (k 96..191) loads into regs; consumed after m1-ph0 ----
    unsigned pre[24];
#pragma unroll
    for (int c = 0; c < 3; ++c)
#pragma unroll
        for (int j = 0; j < 8; ++j) {
            const int k = 96 + c * 32 + ks0 + j;
            pre[c * 8 + j] = g[(size_t)(k >> 5) * 32 * gs + (size_t)(k & 31) * gs + m0 + scol];
        }

    // ---- m1 over ph=0 ----
    for (int kc = 0; kc < 96; kc += 32) {
        v8s bh[4], bl[4];
#pragma unroll
        for (int t = 0; t < 4; ++t) {
            const int bo = (t * 16 + l15) * 104 + kc + q8;
            bh[t] = *(const v8s*)&gt_hi[bo];
            bl[t] = *(const v8s*)&gt_lo[bo];
        }
#pragma unroll
        for (int cp = 0; cp < 2; ++cp) {
            v8s ah[2], al[2];
#pragma unroll
            for (int u = 0; u < 2; ++u) {
                const int ct = cp * 2 + u;
                const int row = (w * 64 + ct * 16 + l15) * 192 + kc + q8;
                ah[u] = *(const v8s*)&swt_hi[row];
                al[u] = *(const v8s*)&swt_lo[row];
            }
#pragma unroll
            for (int u = 0; u < 2; ++u) {
                const int ct = cp * 2 + u;
#pragma unroll
                for (int nt = 0; nt < 4; ++nt) {
                    acc1[ct][nt] = __builtin_amdgcn_mfma_f32_16x16x32_bf16(ah[u], bh[nt], acc1[ct][nt], 0, 0, 0);
                    acc1[ct][nt] = __builtin_amdgcn_mfma_f32_16x16x32_bf16(ah[u], bl[nt], acc1[ct][nt], 0, 0, 0);
                    acc1[ct][nt] = __builtin_amdgcn_mfma_f32_16x16x32_bf16(al[u], bh[nt], acc1[ct][nt], 0, 0, 0);
                }
            }
        }
    }
    __syncthreads();   // gt(ph0) reads done before overwrite

    // ---- write prefetched ph=1 to LDS ----
#pragma unroll
    for (int c = 0; c < 3; ++c) {
        alignas(16) unsigned short h8[8], l8[8];
#pragma unroll
        for (int j = 0; j < 8; ++j) {
            const unsigned v = pre[c * 8 + j];
            h8[j] = (unsigned short)(v & 0xffffu);
            l8[j] = (unsigned short)(v >> 16);
        }
        *(v8s*)&gt_hi[scol * 104 + c * 32 + ks0] = *(v8s*)h8;
        *(v8s*)&gt_lo[scol * 104 + c * 32 + ks0] = *(v8s*)l8;
    }
    __syncthreads();

    // ---- m1 over ph=1 ----
    for (int kc = 0; kc < 96; kc += 32) {
        v8s bh[4], bl[4];
#pragma unroll
        for (int t = 0; t < 4; ++t) {
            const int bo = (t * 16 + l15) * 104 + kc + q8;
            bh[t] = *(const v8s*)&gt_hi[bo];
            bl[t] = *(const v8s*)&gt_lo[bo];
        }
#pragma unroll
        for (int cp = 0; cp < 2; ++cp) {
            v8s ah[2], al[2];
#pragma unroll
            for (int u = 0; u < 2; ++u) {
                const int ct = cp * 2 + u;
                const int row = (w * 64 + ct * 16 + l15) * 192 + 96 + kc + q8;
                ah[u] = *(const v8s*)&swt_hi[row];
                al[u] = *(const v8s*)&swt_lo[row];
            }
#pragma unroll
            for (int u = 0; u < 2; ++u) {
                const int ct = cp * 2 + u;
#pragma unroll
                for (int nt = 0; nt < 4; ++nt) {
                    acc1[ct][nt] = __builtin_amdgcn_mfma_f32_16x16x32_bf16(ah[u], bh[nt], acc1[ct][nt], 0, 0, 0);
                    acc1[ct][nt] = __builtin_amdgcn_mfma_f32_16x16x32_bf16(ah[u], bl[nt], acc1[ct][nt], 0, 0, 0);
                    acc1[ct][nt] = __builtin_amdgcn_mfma_f32_16x16x32_bf16(al[u], bh[nt], acc1[ct][nt], 0, 0, 0);
                }
            }
        }
    }
    __syncthreads();   // gt reads done before st overlays U

    v4f acc2[2][4];
#pragma unroll
    for (int a = 0; a < 2; ++a)
#pragma unroll
        for (int b = 0; b < 4; ++b) acc2[a][b] = (v4f)(0.f);

#pragma unroll
    for (int hh = 0; hh < 2; ++hh) {
        // write st half hh: waves' ct{2hh, 2hh+1} tiles -> st rows [0,128)
#pragma unroll
        for (int c2 = 0; c2 < 2; ++c2) {
            const int ct = hh * 2 + c2;
#pragma unroll
            for (int nt = 0; nt < 4; ++nt) {
                alignas(8) unsigned short sh[4], sl[4];
#pragma unroll
                for (int r = 0; r < 4; ++r) {
                    const float v = fmaxf(acc1[ct][nt][r], 0.f);
                    split2(v, sh[r], sl[r]);
                }
                const int ci  = w * 32 + c2 * 16 + rbase;
                const int col = nt * 16 + l15;
                *(uint2*)&st_hi[col * 136 + ci] = *(uint2*)sh;
                *(uint2*)&st_lo[col * 136 + ci] = *(uint2*)sl;
            }
        }
        __syncthreads();

        for (int kc = 0; kc < 128; kc += 32) {
            v8s ah2[2], al2[2], bh2[4], bl2[4];
#pragma unroll
            for (int t = 0; t < 2; ++t) {
                const int row = (w * 32 + t * 16 + l15) * 256 + hh * 128 + kc + q8;
                ah2[t] = *(const v8s*)&e1t_hi[row];
                al2[t] = *(const v8s*)&e1t_lo[row];
            }
#pragma unroll
            for (int t = 0; t < 4; ++t) {
                const int bo = (t * 16 + l15) * 136 + kc + q8;
                bh2[t] = *(const v8s*)&st_hi[bo];
                bl2[t] = *(const v8s*)&st_lo[bo];
            }
#pragma unroll
            for (int ct = 0; ct < 2; ++ct)
#pragma unroll
                for (int nt = 0; nt < 4; ++nt) {
                    acc2[ct][nt] = __builtin_amdgcn_mfma_f32_16x16x32_bf16(ah2[ct], bh2[nt], acc2[ct][nt], 0, 0, 0);
                    acc2[ct][nt] = __builtin_amdgcn_mfma_f32_16x16x32_bf16(ah2[ct], bl2[nt], acc2[ct][nt], 0, 0, 0);
                    acc2[ct][nt] = __builtin_amdgcn_mfma_f32_16x16x32_bf16(al2[ct], bh2[nt], acc2[ct][nt], 0, 0, 0);
                }
        }
        if (hh == 0) __syncthreads();   // m2 half-0 reads done before st half-1 overwrite
    }

#pragma unroll
    for (int ct = 0; ct < 2; ++ct) {
        const int cobase = w * 32 + ct * 16 + rbase;
        float bb[4];
#pragma unroll
        for (int r = 0; r < 4; ++r) bb[r] = b1[cobase + r];
#pragma unroll
        for (int nt = 0; nt < 4; ++nt) {
            const int col = m0 + nt * 16 + l15;
#pragma unroll
            for (int r = 0; r < 4; ++r)
                y1[(size_t)(cobase + r) * gs + col] = fmaxf(acc2[ct][nt][r] + bb[r], 0.f);
        }
    }
}

// Fused maxpool3s2 + end2 (128->32) via split-bf16 MFMA. 64 pooled cols/block.
// Chunked swizzle kept (33% pool-window overlap between t1-adjacent blocks
// becomes L2-local).
__global__ __launch_bounds__(256) void k_pe2_m(
    const float* __restrict__ y1c,
    const unsigned short* __restrict__ e2s_hi, const unsigned short* __restrict__ e2s_lo,
    const float* __restrict__ b2, float* __restrict__ e2c,
    const int gs, const int p1s)
{
    __shared__ unsigned short SP[2 * 64 * 136];
    unsigned short* sp_hi = SP;
    unsigned short* sp_lo = SP + 64 * 136;

    const int tid = threadIdx.x;
    const int m0 = xcd_chunk(blockIdx.x, gridDim.x) * 64;
    const int tp = m0 >> 8;
    const int nb = m0 & 255;

    {
        const int col = tid & 63;
        const int cig = tid >> 6;
        const int base = 2 * tp * 256 + nb + col;
#pragma unroll
        for (int u8 = 0; u8 < 4; ++u8) {
            alignas(16) unsigned short h8[8], l8[8];
#pragma unroll
            for (int u = 0; u < 8; ++u) {
                const int ci = cig * 32 + u8 * 8 + u;
                const float* yp = y1c + (size_t)ci * gs + base;
                const float v = fmaxf(fmaxf(yp[0], yp[256]), yp[512]);
                split2(v, h8[u], l8[u]);
            }
            *(uint4*)&sp_hi[col * 136 + cig * 32 + u8 * 8] = *(uint4*)h8;
            *(uint4*)&sp_lo[col * 136 + cig * 32 + u8 * 8] = *(uint4*)l8;
        }
    }
    __syncthreads();

    const int lane = tid & 63;
    const int w    = tid >> 6;
    const int mh   = w & 1;
    const int colh = w >> 1;
    const int l15  = lane & 15;
    const int quad = lane >> 4;
    const int q8   = quad * 8;

    v4f acc[2];
    acc[0] = (v4f)(0.f); acc[1] = (v4f)(0.f);

#pragma unroll
    for (int kc = 0; kc < 128; kc += 32) {
        const int row = (mh * 16 + l15) * 128 + kc + q8;
        const v8s ah = *(const v8s*)&e2s_hi[row];
        const v8s al = *(const v8s*)&e2s_lo[row];
#pragma unroll
        for (int nt = 0; nt < 2; ++nt) {
            const int col = colh * 32 + nt * 16 + l15;
            const v8s bh = *(const v8s*)&sp_hi[col * 136 + kc + q8];
            const v8s bl = *(const v8s*)&sp_lo[col * 136 + kc + q8];
            acc[nt] = __builtin_amdgcn_mfma_f32_16x16x32_bf16(ah, bh, acc[nt], 0, 0, 0);
            acc[nt] = __builtin_amdgcn_mfma_f32_16x16x32_bf16(ah, bl, acc[nt], 0, 0, 0);
            acc[nt] = __builtin_amdgcn_mfma_f32_16x16x32_bf16(al, bh, acc[nt], 0, 0, 0);
        }
    }

#pragma unroll
    for (int nt = 0; nt < 2; ++nt)
#pragma unroll
        for (int r = 0; r < 4; ++r) {
            const int co = mh * 16 + quad * 4 + r;
            const int col = m0 + colh * 32 + nt * 16 + l15;
            e2c[(size_t)co * p1s + col] = fmaxf(acc[nt][r] + b2[co], 0.f);
        }
}

// pool2 -> p2 stored packed-split u32 (consumed by k_fc1_m)
__global__ __launch_bounds__(256) void k_pool2p(const float* __restrict__ e2c,
                                                unsigned* __restrict__ p2,
                                                const int p1s, const int A) {
    const int n = threadIdx.x, tl2 = blockIdx.x, co = blockIdx.y;
    const int base = co * p1s + tl2 * 512 + n;
    float v = fmaxf(fmaxf(e2c[base], e2c[base + 256]), e2c[base + 512]);
    p2[co * 81152 + (A + tl2) * 256 + n] = packsplit(v);
}

// FC1 via split-bf16 MFMA: C[1024 x 256] += W1[1024 x 10144] @ P2[10144 x 256].
__global__ __launch_bounds__(256) void k_fc1_m(
    const unsigned short* __restrict__ w1s_hi, const unsigned short* __restrict__ w1s_lo,
    const unsigned* __restrict__ p2u, float* __restrict__ out)
{
    __shared__ unsigned short SB[2 * 64 * 40];
    unsigned short* sb_hi = SB;
    unsigned short* sb_lo = SB + 64 * 40;

    const int tid = threadIdx.x;
    const int o0 = blockIdx.x * 64;
    const int b0 = blockIdx.y * 64;
    const int k0 = blockIdx.z * 1280;
    const int kend = (k0 + 1280 < 10144) ? (k0 + 1280) : 10144;
    const int nch = (kend - k0) >> 5;

    const int lane = tid & 63;
    const int w    = tid >> 6;
    const int l15  = lane & 15;
    const int quad = lane >> 4;
    const int q8   = quad * 8;
    const int scol = tid & 63;
    const int kq   = tid >> 6;

    v4f acc[4];
#pragma unroll
    for (int nt = 0; nt < 4; ++nt) acc[nt] = (v4f)(0.f);

    for (int c = 0; c < nch; ++c) {
        const int kc = k0 + c * 32;
        alignas(16) unsigned short h8[8], l8[8];
#pragma unroll
        for (int j = 0; j < 8; ++j) {
            const unsigned v = p2u[(size_t)(kc + kq * 8 + j) * 256 + b0 + scol];
            h8[j] = (unsigned short)(v & 0xffffu);
            l8[j] = (unsigned short)(v >> 16);
        }
        __syncthreads();
        *(v8s*)&sb_hi[scol * 40 + kq * 8] = *(v8s*)h8;
        *(v8s*)&sb_lo[scol * 40 + kq * 8] = *(v8s*)l8;
        __syncthreads();

        const int arow = (o0 + w * 16 + l15) * 10144 + kc + q8;
        const v8s ah = *(const v8s*)&w1s_hi[arow];
        const v8s al = *(const v8s*)&w1s_lo[arow];
#pragma unroll
        for (int nt = 0; nt < 4; ++nt) {
            const v8s bh = *(const v8s*)&sb_hi[(nt * 16 + l15) * 40 + q8];
            const v8s bl = *(const v8s*)&sb_lo[(nt * 16 + l15) * 40 + q8];
            acc[nt] = __builtin_amdgcn_mfma_f32_16x16x32_bf16(ah, bh, acc[nt], 0, 0, 0);
            acc[nt] = __builtin_amdgcn_mfma_f32_16x16x32_bf16(ah, bl, acc[nt], 0, 0, 0);
            acc[nt] = __builtin_amdgcn_mfma_f32_16x16x32_bf16(al, bh, acc[nt], 0, 0, 0);
        }
    }

#pragma unroll
    for (int nt = 0; nt < 4; ++nt)
#pragma unroll
        for (int r = 0; r < 4; ++r)
            atomicAdd(&out[(size_t)(o0 + w * 16 + quad * 4 + r) * 256 + b0 + nt * 16 + l15],
                      acc[nt][r]);
}

// Tiled f32 GEMM (FC2 only).
__global__ __launch_bounds__(256) void k_gemm64(const float* __restrict__ A,
                                                const float* __restrict__ B,
                                                float* __restrict__ C,
                                                const int Ktot, const int KC) {
    __shared__ float sA[32 * 65];
    __shared__ float sB[32 * 68];

    const int tid = threadIdx.x;
    const int o0 = blockIdx.x * 64;
    const int b0 = blockIdx.y * 64;
    const int k0 = blockIdx.z * KC;

    float acc[4][4];
#pragma unroll
    for (int i = 0; i < 4; ++i)
#pragma unroll
        for (int jq = 0; jq < 4; ++jq) acc[i][jq] = 0.f;

    const int ao  = tid >> 2;
    const int ak8 = (tid & 3) * 8;
    const int bk  = tid >> 3;
    const int bb8 = (tid & 7) * 8;
    const int to4 = (tid & 15) * 4;
    const int tb4 = (tid >> 4) * 4;

    for (int kc = 0; kc < KC; kc += 32) {
        const int kcLen = (KC - kc < 32) ? (KC - kc) : 32;
        const float* ap = A + (size_t)(o0 + ao) * Ktot + k0 + kc + ak8;
#pragma unroll
        for (int i = 0; i < 8; ++i) {
            float v = (ak8 + i < kcLen) ? ap[i] : 0.f;
            sA[(ak8 + i) * 65 + ao] = v;
        }
        if (bk < kcLen) {
            const float* bp = B + (size_t)(k0 + kc + bk) * 256 + b0 + bb8;
            const float4 v0 = *(const float4*)bp;
            const float4 v1 = *(const float4*)(bp + 4);
            *(float4*)&sB[bk * 68 + bb8] = v0;
            *(float4*)&sB[bk * 68 + bb8 + 4] = v1;
        } else {
            float4 z; z.x = z.y = z.z = z.w = 0.f;
            *(float4*)&sB[bk * 68 + bb8] = z;
            *(float4*)&sB[bk * 68 + bb8 + 4] = z;
        }
        __syncthreads();

#pragma unroll 8
        for (int kk = 0; kk < 32; ++kk) {
            const float4 av = *(const float4*)&sA[kk * 65 + to4];
            const float4 bv = *(const float4*)&sB[kk * 68 + tb4];
            const float aa[4] = {av.x, av.y, av.z, av.w};
#pragma unroll
            for (int i = 0; i < 4; ++i) {
                acc[i][0] = fmaf(aa[i], bv.x, acc[i][0]);
                acc[i][1] = fmaf(aa[i], bv.y, acc[i][1]);
                acc[i][2] = fmaf(aa[i], bv.z, acc[i][2]);
                acc[i][3] = fmaf(aa[i], bv.w, acc[i][3]);
            }
        }
        __syncthreads();
    }

#pragma unroll
    for (int i = 0; i < 4; ++i)
#pragma unroll
        for (int jq = 0; jq < 4; ++jq)
            atomicAdd(&C[(size_t)(o0 + to4 + i) * 256 + b0 + tb4 + jq], acc[i][jq]);
}

__global__ __launch_bounds__(256) void k_actbias(const float* __restrict__ raw,
                                                 const float* __restrict__ bias,
                                                 float* __restrict__ out) {
    const int k = blockIdx.x, b = threadIdx.x;
    out[k * 256 + b] = fmaxf(raw[k * 256 + b] + bias[k], 0.f);
}

__global__ __launch_bounds__(256) void k_fc3(const float* __restrict__ fc2raw,
                                             const float* __restrict__ fb2,
                                             const float* __restrict__ w3,
                                             const float* __restrict__ b3,
                                             float* __restrict__ out) {
    const int b = threadIdx.x;
    float l0 = b3[0], l1 = b3[1];
    for (int k = 0; k < 256; ++k) {
        const float a = fmaxf(fc2raw[k * 256 + b] + fb2[k], 0.f);
        l0 = fmaf(w3[k], a, l0);
        l1 = fmaf(w3[256 + k], a, l1);
    }
    out[2 * b] = l0;
    out[2 * b + 1] = l1;
    const float mx = fmaxf(l0, l1);
    const float e0 = expf(l0 - mx), e1 = expf(l1 - mx);
    const float inv = 1.f / (e0 + e1);
    out[512 + 2 * b] = e0 * inv;
    out[513 + 2 * b] = e1 * inv;
    out[1024 + b] = (l1 > l0) ? 1.f : 0.f;
}

extern "C" void kernel_launch(void* const* d_in, const int* in_sizes, int n_in,
                              void* d_out, int out_size, void* d_ws, size_t ws_size,
                              hipStream_t stream) {
    const float* x        = (const float*)d_in[0];
    const float* start_w  = (const float*)d_in[1];
    const float* filter_w = (const float*)d_in[2];
    const float* gate_w   = (const float*)d_in[3];
    const float* res_w    = (const float*)d_in[4];
    const float* skip_w   = (const float*)d_in[5];
    const float* e1w      = (const float*)d_in[6];
    const float* e1b      = (const float*)d_in[7];
    const float* e2w      = (const float*)d_in[8];
    const float* e2b      = (const float*)d_in[9];
    const float* w1       = (const float*)d_in[10];
    const float* fb1      = (const float*)d_in[11];
    const float* w2       = (const float*)d_in[12];
    const float* fb2      = (const float*)d_in[13];
    const float* w3       = (const float*)d_in[14];
    const float* b3       = (const float*)d_in[15];

    float* ws = (float*)d_ws;

    const long o_h0   = 0;            // 10,485,760
    const long o_p2   = 10485760;     // 2,596,864
    const long o_fc1  = 13082624;     // 262,144
    const long o_fc2  = 13344768;     // 65,536
    const long o_wbf  = 13410304;     // 81,920
    const long o_wfg  = 13492224;     // 24,576
    const long o_wr   = 13516800;     // 12,288
    const long o_e2s  = 13529088;     // 4,096
    const long o_act1 = 13533184;     // 262,144
    const long o_w1s  = 13795328;     // 10,387,456 (w1 hi+lo u16)
    const long o_G    = 24182784;

    long budget = (long)((double)ws_size * 0.94 / 4.0);
    int dB = 1;
    for (int d = 317; d >= 1; --d) {
        long mch = 256L * (4L * d + 3), hs = mch + 4096;
        long tot = o_G + 192L * mch + lmax_(128L * mch, 64L * hs);
        if (tot <= budget) { dB = d; break; }
    }
    int K = (317 + dB - 1) / dB;
    dB = (317 + K - 1) / K;
    const long MchA  = 256L * (4L * dB + 3);
    const long HSPAN = MchA + 4096;
    const long o_X   = o_G + 192L * MchA;
    const long P1S   = 256L * (2L * dB + 1);

    unsigned* h0 = (unsigned*)(ws + o_h0);
    unsigned* p2 = (unsigned*)(ws + o_p2);
    float* fc1r = ws + o_fc1;
    float* fc2r = ws + o_fc2;
    unsigned short* swt_hi = (unsigned short*)(ws + o_wbf);
    unsigned short* swt_lo = swt_hi + 49152;
    unsigned short* e1t_hi = swt_lo + 49152;
    unsigned short* e1t_lo = e1t_hi + 32768;
    unsigned short* wfg_hi = (unsigned short*)(ws + o_wfg);
    unsigned short* wfg_lo = wfg_hi + 24576;
    unsigned short* wr_hi  = (unsigned short*)(ws + o_wr);
    unsigned short* wr_lo  = wr_hi + 12288;
    unsigned short* e2s_hi = (unsigned short*)(ws + o_e2s);
    unsigned short* e2s_lo = e2s_hi + 4096;
    unsigned short* w1s_hi = (unsigned short*)(ws + o_w1s);
    unsigned short* w1s_lo = w1s_hi + 10387456;
    float* act1 = ws + o_act1;
    unsigned* G  = (unsigned*)(ws + o_G);
    unsigned* hA = (unsigned*)(ws + o_X);
    unsigned* hB = (unsigned*)(ws + o_X) + 32L * HSPAN;
    float* y1c  = ws + o_X;                 // aliases hA/hB (dead by then)
    float* e2c  = ws + o_G;                 // aliases G (dead after skip_end1)

    k_zero<<<1280, 256, 0, stream>>>(fc1r, 327680);
    k_start<<<1280, 256, 0, stream>>>(x, start_w, h0);
    k_prep<<<192, 256, 0, stream>>>(skip_w, e1w, filter_w, gate_w, res_w, e2w,
                                    swt_hi, swt_lo, e1t_hi, e1t_lo,
                                    wfg_hi, wfg_lo, wr_hi, wr_lo,
                                    e2s_hi, e2s_lo);
    k_prep_w1<<<40576, 256, 0, stream>>>(w1, w1s_hi, w1s_lo);

    const int Mc[6]   = {327424, 327168, 326656, 326400, 326144, 325632};
    const int NpmP[6] = {256, 256, 512, 256, 256, 512};
    const int pN[6]   = {0, 256, 512, 0, 256, 512};
    const int so_[6]  = {1792, 1536, 1024, 768, 512, 0};
    const int JloO[6] = {-1536, -1280, -768, -768, -512, 0};

    for (int c = 0; c < K; ++c) {
        const int A = c * dB;
        int B = A + dB; if (B > 317) B = 317;
        const int dBc = B - A;
        const int M0 = 1024 * A;
        int tmax = 4 * B + 3; if (tmax > 1272) tmax = 1272;
        const int Tt = tmax - 4 * A;
        const int M1 = M0 + 256 * Tt;

        int Jlo[6], Jhi[6];
        for (int q = 0; q < 6; ++q) {
            int lo = M0 + JloO[q]; if (lo < 0) lo = 0;
            int hi = M1 + so_[q];  if (hi > Mc[q]) hi = Mc[q];
            Jlo[q] = lo; Jhi[q] = hi;
        }

        for (int q = 0; q < 6; ++q) {
            const unsigned* hin = (q == 0) ? h0 : ((q & 1) ? hA : hB);
            const int hinBase   = (q == 0) ? 0 : Jlo[q - 1];
            const int hinStride = (q == 0) ? MCAP : (int)HSPAN;
            unsigned* hout = (q & 1) ? hB : hA;
            const int Jcnt = Jhi[q] - Jlo[q];     // % 128 == 0
            k_layer_m<<<Jcnt / 128, 256, 0, stream>>>(
                hin, hinBase, hinStride, hout, Jlo[q], (int)HSPAN,
                G + (long)q * 32 * MchA, (int)MchA,
                wfg_hi + q * 4096, wfg_lo + q * 4096,
                wr_hi + q * 2048, wr_lo + q * 2048,
                Jlo[q], NpmP[q], pN[q], so_[q], M0, M1, (q < 5) ? 1 : 0);
        }

        const int Mchc = 256 * Tt;
        k_skip_end1_m<<<Mchc / 64, 256, 0, stream>>>(
            G, swt_hi, swt_lo, e1t_hi, e1t_lo, e1b, y1c, (int)MchA);
        const int T1c = 2 * dBc + 1;
        k_pe2_m<<<T1c * 4, 256, 0, stream>>>(
            y1c, e2s_hi, e2s_lo, e2b, e2c, (int)MchA, (int)P1S);
        k_pool2p<<<dim3(dBc, 32), 256, 0, stream>>>(e2c, p2, (int)P1S, A);
    }

    k_fc1_m<<<dim3(16, 4, 8), 256, 0, stream>>>(w1s_hi, w1s_lo, p2, fc1r);
    k_actbias<<<1024, 256, 0, stream>>>(fc1r, fb1, act1);
    k_gemm64<<<dim3(4, 4, 4), 256, 0, stream>>>(w2, act1, fc2r, 1024, 256);
    k_fc3<<<1, 256, 0, stream>>>(fc2r, fb2, w3, b3, (float*)d_out);
}